// Round 11
// baseline (424.162 us; speedup 1.0000x reference)
//
#include <hip/hip_runtime.h>
#include <stdint.h>

typedef unsigned short ushort_t;
typedef short bf16x4 __attribute__((ext_vector_type(4)));
typedef short bf16x8 __attribute__((ext_vector_type(8)));
typedef float f32x4 __attribute__((ext_vector_type(4)));
typedef float f32x16 __attribute__((ext_vector_type(16)));
typedef float f32x4v __attribute__((ext_vector_type(4)));

// ---------- helpers ----------
__device__ __forceinline__ ushort_t f2bf(float f) {
  unsigned int u = __builtin_bit_cast(unsigned int, f);
  u += 0x7fffu + ((u >> 16) & 1u);
  return (ushort_t)(u >> 16);
}
__device__ __forceinline__ float bf2f(ushort_t h) {
  unsigned int u = ((unsigned int)h) << 16;
  return __builtin_bit_cast(float, u);
}
__device__ __forceinline__ float exp2_hw(float x) {
  return __builtin_amdgcn_exp2f(x);  // v_exp_f32: D = 2^S0
}
__device__ __forceinline__ void load_lds16(const void* g, void* l) {
  __builtin_amdgcn_global_load_lds(
      (const __attribute__((address_space(1))) void*)g,
      (__attribute__((address_space(3))) void*)l, 16, 0, 0);
}

// ---------- x fp32 -> bf16 ----------
__global__ __launch_bounds__(256) void cvt_x_kernel(const float* __restrict__ x,
                                                    ushort_t* __restrict__ xb) {
  int i = blockIdx.x * 256 + threadIdx.x;  // each thread: 8 elems
  const f32x4v* xv = (const f32x4v*)x;
  f32x4v a = xv[2 * i], b = xv[2 * i + 1];
  bf16x8 o;
  o[0] = (short)f2bf(a[0]); o[1] = (short)f2bf(a[1]);
  o[2] = (short)f2bf(a[2]); o[3] = (short)f2bf(a[3]);
  o[4] = (short)f2bf(b[0]); o[5] = (short)f2bf(b[1]);
  o[6] = (short)f2bf(b[2]); o[7] = (short)f2bf(b[3]);
  ((bf16x8*)xb)[i] = o;
}

// ---------- weight fp32 [R][C] -> bf16 transposed [C][R] ----------
__global__ __launch_bounds__(256) void tr_cvt_kernel(const float* __restrict__ src,
                                                     ushort_t* __restrict__ dst,
                                                     int R, int C) {
  __shared__ float tile[64][65];
  int r0 = blockIdx.y * 64, c0 = blockIdx.x * 64;
  int t = threadIdx.x;
#pragma unroll
  for (int i = 0; i < 16; i++) {
    int idx = t + i * 256;
    int r = idx >> 6, c = idx & 63;
    tile[r][c] = src[(size_t)(r0 + r) * C + c0 + c];
  }
  __syncthreads();
#pragma unroll
  for (int i = 0; i < 16; i++) {
    int idx = t + i * 256;
    int cr = idx >> 6, cc = idx & 63;
    dst[(size_t)(c0 + cr) * R + r0 + cc] = f2bf(tile[cc][cr]);
  }
}

// ---------- RoPE in-place on C1 (Q cols 0..4095 pre-scaled by scale*log2e) ----------
__global__ __launch_bounds__(256) void rope_kernel(ushort_t* __restrict__ C1,
                                                   const float* __restrict__ cosb,
                                                   const float* __restrict__ sinb) {
  int idx = blockIdx.x * 256 + threadIdx.x;  // 2048 * 640
  int s = idx / 640;
  int col0 = (idx % 640) * 8;
  int i0 = (col0 & 127) >> 1;
  const float qs = (col0 < 4096) ? 0.12753055296570565f : 1.0f;  // scale*log2e
  ushort_t* p = C1 + (size_t)s * 6144 + col0;
  bf16x8 v = *(const bf16x8*)p;
  bf16x8 o;
  const float* cr = cosb + s * 64 + i0;
  const float* sr = sinb + s * 64 + i0;
#pragma unroll
  for (int j = 0; j < 4; j++) {
    float tr = bf2f((ushort_t)v[2 * j]);
    float ti = bf2f((ushort_t)v[2 * j + 1]);
    float c = cr[j], sn = sr[j];
    o[2 * j] = (short)f2bf((tr * c - ti * sn) * qs);
    o[2 * j + 1] = (short)f2bf((tr * sn + ti * c) * qs);
  }
  *(bf16x8*)p = o;
}

// ---------- V part of C1 -> VT [1024][2048] (row = hk*128+d, col = s) ----------
__global__ __launch_bounds__(256) void trv_kernel(const ushort_t* __restrict__ C1,
                                                  ushort_t* __restrict__ VT) {
  __shared__ ushort_t tile[64][65];
  int c0 = blockIdx.x * 64;  // within 1024
  int r0 = blockIdx.y * 64;  // within 2048
  int t = threadIdx.x;
#pragma unroll
  for (int i = 0; i < 16; i++) {
    int idx = t + i * 256;
    int r = idx >> 6, c = idx & 63;
    tile[r][c] = C1[(size_t)(r0 + r) * 6144 + 5120 + c0 + c];
  }
  __syncthreads();
#pragma unroll
  for (int i = 0; i < 16; i++) {
    int idx = t + i * 256;
    int cr = idx >> 6, cc = idx & 63;
    VT[(size_t)(c0 + cr) * 2048 + r0 + cc] = tile[cc][cr];
  }
}

// ---------- GEMM 256x256 8-phase (m201 port: T1+T2+T3/T4+T5) ----------
// C[M][ldc] = A[M][K]*BT[N][K]^T. M%256==0, N%256==0, K%64==0, K/64>=2,
// grid 1D = (M/256)*(N/256), grid%8==0. 512 thr = 8 waves (2Mr x 4Nc),
// per-wave 128x64 out (acc[8][4]). LDS 128KB = 2 dbuf x (A 32KB + B 32KB).
// Per K-tile: 4 phases {ds_read subtile + 2 stage-issues -> s_barrier ->
// lgkmcnt(0)+sched_barrier -> setprio(1) 16 MFMA setprio(0) -> [vmcnt] ->
// s_barrier}. Quarter staging (1 load/thr): order [Aq0,Aq2][Bq0,Bq1]
// [Bq2,Bq3][Aq1,Aq3]; vmcnt(4)@ph1-end guards A-odd quarters (read ph2),
// vmcnt(2)@ph3-end guards next tile ph0. vmcnt->barrier pairs make other
// waves' load arrival visible. Swizzle: LDS chunk L holds global chunk
// (L&7)^(row&7); ds_read XORs back (R9/R10: 0 bank conflicts).
template <typename OutT>
__global__ __launch_bounds__(512) void gemm256p8_kernel(const ushort_t* __restrict__ A,
                                                        const ushort_t* __restrict__ BT,
                                                        OutT* __restrict__ C,
                                                        int M, int N, int K, int ldc) {
  __shared__ ushort_t As[2][256 * 64];  // 64KB
  __shared__ ushort_t Bs[2][256 * 64];  // 64KB
  const int nbx = N >> 8;
  const int nwg = gridDim.x;
  const int id = blockIdx.x;
  const int wg = (id & 7) * (nwg >> 3) + (id >> 3);  // XCD-contiguous (nwg%8==0)
  const int brow = (wg / nbx) << 8, bcol = (wg % nbx) << 8;
  const int tid = threadIdx.x, w = tid >> 6, lane = tid & 63;
  const int wr = w >> 2, wc = w & 3;
  const int lr = lane & 15, lk = lane >> 4;

  const ushort_t* Ab = A + (size_t)brow * K;
  const ushort_t* Bb = BT + (size_t)bcol * K;

  // stage quarter q (64 rows x 64 cols) of tile t: 1 load/thread.
  auto stageQ = [&](const ushort_t* gbase, char* lds, int t, int q) {
    int L = q * 512 + tid;
    int r = L >> 3, sc = L & 7;
    load_lds16(gbase + (size_t)r * K + (t << 6) + ((sc ^ (r & 7)) << 3), lds + L * 16);
  };

  f32x4 acc[8][4] = {};
  const int NT = K >> 6;

  // prologue: tile 0 fully staged, drained once
#pragma unroll
  for (int q = 0; q < 4; ++q) stageQ(Ab, (char*)&As[0][0], 0, q);
#pragma unroll
  for (int q = 0; q < 4; ++q) stageQ(Bb, (char*)&Bs[0][0], 0, q);
  asm volatile("s_waitcnt vmcnt(0)" ::: "memory");
  __builtin_amdgcn_s_barrier();

  for (int t = 0; t < NT; ++t) {
    const int c = t & 1;
    const char* Ac = (const char*)&As[c][0];
    const char* Bc = (const char*)&Bs[c][0];
    char* An = (char*)&As[c ^ 1][0];
    char* Bn = (char*)&Bs[c ^ 1][0];
    const bool pf = (t + 1 < NT);

    bf16x8 af[4][2], bfr[4][2];
    // ======== phase 0: A mh0 (8 reads) + B n0,n1 (4) ; stage Aq0,Aq2 ========
#pragma unroll
    for (int mm = 0; mm < 4; ++mm)
#pragma unroll
      for (int ks = 0; ks < 2; ++ks) {
        int rA = wr * 128 + mm * 16 + lr;
        af[mm][ks] = *(const bf16x8*)(Ac + rA * 128 + (((ks * 4 + lk) ^ (rA & 7)) << 4));
      }
#pragma unroll
    for (int n = 0; n < 2; ++n)
#pragma unroll
      for (int ks = 0; ks < 2; ++ks) {
        int rB = wc * 64 + n * 16 + lr;
        bfr[n][ks] = *(const bf16x8*)(Bc + rB * 128 + (((ks * 4 + lk) ^ (rB & 7)) << 4));
      }
    if (pf) { stageQ(Ab, An, t + 1, 0); stageQ(Ab, An, t + 1, 2); }
    __builtin_amdgcn_s_barrier();
    asm volatile("s_waitcnt lgkmcnt(0)" ::: "memory");
    __builtin_amdgcn_sched_barrier(0);
    __builtin_amdgcn_s_setprio(1);
#pragma unroll
    for (int mm = 0; mm < 4; ++mm)
#pragma unroll
      for (int n = 0; n < 2; ++n)
#pragma unroll
        for (int ks = 0; ks < 2; ++ks)
          acc[mm][n] = __builtin_amdgcn_mfma_f32_16x16x32_bf16(af[mm][ks], bfr[n][ks],
                                                               acc[mm][n], 0, 0, 0);
    __builtin_amdgcn_s_setprio(0);
    __builtin_amdgcn_s_barrier();

    // ======== phase 1: B n2,n3 (4 reads) ; stage Bq0,Bq1 ; vmcnt(4) ========
#pragma unroll
    for (int n = 2; n < 4; ++n)
#pragma unroll
      for (int ks = 0; ks < 2; ++ks) {
        int rB = wc * 64 + n * 16 + lr;
        bfr[n][ks] = *(const bf16x8*)(Bc + rB * 128 + (((ks * 4 + lk) ^ (rB & 7)) << 4));
      }
    if (pf) { stageQ(Bb, Bn, t + 1, 0); stageQ(Bb, Bn, t + 1, 1); }
    __builtin_amdgcn_s_barrier();
    asm volatile("s_waitcnt lgkmcnt(0)" ::: "memory");
    __builtin_amdgcn_sched_barrier(0);
    __builtin_amdgcn_s_setprio(1);
#pragma unroll
    for (int mm = 0; mm < 4; ++mm)
#pragma unroll
      for (int n = 2; n < 4; ++n)
#pragma unroll
        for (int ks = 0; ks < 2; ++ks)
          acc[mm][n] = __builtin_amdgcn_mfma_f32_16x16x32_bf16(af[mm][ks], bfr[n][ks],
                                                               acc[mm][n], 0, 0, 0);
    __builtin_amdgcn_s_setprio(0);
    asm volatile("s_waitcnt vmcnt(4)" ::: "memory");  // A-odd quarters of tile t landed
    __builtin_amdgcn_s_barrier();

    // ======== phase 2: A mh1 (8 reads) ; stage Bq2,Bq3 ========
#pragma unroll
    for (int mm = 0; mm < 4; ++mm)
#pragma unroll
      for (int ks = 0; ks < 2; ++ks) {
        int rA = wr * 128 + 64 + mm * 16 + lr;
        af[mm][ks] = *(const bf16x8*)(Ac + rA * 128 + (((ks * 4 + lk) ^ (rA & 7)) << 4));
      }
    if (pf) { stageQ(Bb, Bn, t + 1, 2); stageQ(Bb, Bn, t + 1, 3); }
    __builtin_amdgcn_s_barrier();
    asm volatile("s_waitcnt lgkmcnt(0)" ::: "memory");
    __builtin_amdgcn_sched_barrier(0);
    __builtin_amdgcn_s_setprio(1);
#pragma unroll
    for (int mm = 0; mm < 4; ++mm)
#pragma unroll
      for (int n = 0; n < 2; ++n)
#pragma unroll
        for (int ks = 0; ks < 2; ++ks)
          acc[4 + mm][n] = __builtin_amdgcn_mfma_f32_16x16x32_bf16(af[mm][ks], bfr[n][ks],
                                                                   acc[4 + mm][n], 0, 0, 0);
    __builtin_amdgcn_s_setprio(0);
    __builtin_amdgcn_s_barrier();

    // ======== phase 3: no reads ; stage Aq1,Aq3 ; MFMA ; vmcnt(2) boundary ========
    if (pf) { stageQ(Ab, An, t + 1, 1); stageQ(Ab, An, t + 1, 3); }
    __builtin_amdgcn_s_setprio(1);
#pragma unroll
    for (int mm = 0; mm < 4; ++mm)
#pragma unroll
      for (int n = 2; n < 4; ++n)
#pragma unroll
        for (int ks = 0; ks < 2; ++ks)
          acc[4 + mm][n] = __builtin_amdgcn_mfma_f32_16x16x32_bf16(af[mm][ks], bfr[n][ks],
                                                                   acc[4 + mm][n], 0, 0, 0);
    __builtin_amdgcn_s_setprio(0);
    asm volatile("s_waitcnt vmcnt(2)" ::: "memory");  // all but Aq1,Aq3(t+1) landed
    __builtin_amdgcn_s_barrier();
  }
  // epilogue
#pragma unroll
  for (int m = 0; m < 8; ++m)
#pragma unroll
    for (int n = 0; n < 4; ++n) {
      int row = brow + wr * 128 + m * 16 + lk * 4;
      int col = bcol + wc * 64 + n * 16 + lr;
#pragma unroll
      for (int j = 0; j < 4; ++j) {
        float v = acc[m][n][j];
        if constexpr (sizeof(OutT) == 2)
          C[(size_t)(row + j) * ldc + col] = (OutT)f2bf(v);
        else
          C[(size_t)(row + j) * ldc + col] = v;
      }
    }
}

// ---------- GEMM: C[M][ldc] = A[M][K] * BT[N][K]^T  (m97 structure, fallback) ----------
template <typename OutT>
__global__ __launch_bounds__(256) void gemm128_kernel(const ushort_t* __restrict__ A,
                                                      const ushort_t* __restrict__ BT,
                                                      OutT* __restrict__ C,
                                                      int M, int N, int K, int ldc) {
  __shared__ ushort_t As[128 * 32];
  __shared__ ushort_t Bs[128 * 32];
  int brow = blockIdx.y * 128, bcol = blockIdx.x * 128;
  int tid = threadIdx.x, w = tid >> 6, lane = tid & 63;
  int wr = w >> 1, wc = w & 1;
  int lr = lane & 15, lk = lane >> 4;
  f32x4 acc[4][4] = {};

  int srow = lane >> 2;
  int scol = (lane & 3) * 8;
  const ushort_t* Ab = A + (size_t)brow * K + scol;
  const ushort_t* Bb = BT + (size_t)bcol * K + scol;

  for (int kt = 0; kt < K; kt += 32) {
#pragma unroll
    for (int i = 0; i < 2; i++) {
      int seg = w * 2 + i;
      int row = seg * 16 + srow;
      load_lds16(Ab + (size_t)row * K + kt, (char*)As + seg * 1024);
      load_lds16(Bb + (size_t)row * K + kt, (char*)Bs + seg * 1024);
    }
    __syncthreads();
    bf16x8 af[4], bfr[4];
#pragma unroll
    for (int m = 0; m < 4; m++)
      af[m] = *(const bf16x8*)&As[(wr * 64 + m * 16 + lr) * 32 + lk * 8];
#pragma unroll
    for (int n = 0; n < 4; n++)
      bfr[n] = *(const bf16x8*)&Bs[(wc * 64 + n * 16 + lr) * 32 + lk * 8];
#pragma unroll
    for (int m = 0; m < 4; m++)
#pragma unroll
      for (int n = 0; n < 4; n++)
        acc[m][n] = __builtin_amdgcn_mfma_f32_16x16x32_bf16(af[m], bfr[n], acc[m][n], 0, 0, 0);
    __syncthreads();
  }
#pragma unroll
  for (int m = 0; m < 4; m++)
#pragma unroll
    for (int n = 0; n < 4; n++) {
      int row = brow + wr * 64 + m * 16 + lk * 4;
      int col = bcol + wc * 64 + n * 16 + lr;
#pragma unroll
      for (int j = 0; j < 4; j++) {
        float v = acc[m][n][j];
        if constexpr (sizeof(OutT) == 2)
          C[(size_t)(row + j) * ldc + col] = (OutT)f2bf(v);
        else
          C[(size_t)(row + j) * ldc + col] = v;
      }
    }
}

// ---------- gemmS: P[tile] = exp2(Q K^T) causal, materialized bf16 ----------
__global__ __launch_bounds__(256) void gemmS_kernel(const ushort_t* __restrict__ C1,
                                                    ushort_t* __restrict__ P) {
  int rem = blockIdx.x, rt = 0;
  while (rem > rt) { rem -= (rt + 1); rt++; }
  const int ct = rem;
  const int h = blockIdx.y, hk = h >> 2;

  __shared__ ushort_t As[128 * 32];
  __shared__ ushort_t Bs[128 * 32];
  int tid = threadIdx.x, w = tid >> 6, lane = tid & 63;
  int wr = w >> 1, wc = w & 1;
  int lr = lane & 15, lk = lane >> 4;
  f32x4 acc[4][4] = {};
  int srow = lane >> 2;
  int scol = (lane & 3) * 8;
  const ushort_t* Ab = C1 + (size_t)(rt * 128) * 6144 + h * 128 + scol;         // Q
  const ushort_t* Bb = C1 + (size_t)(ct * 128) * 6144 + 4096 + hk * 128 + scol; // K

  for (int kt = 0; kt < 128; kt += 32) {
#pragma unroll
    for (int i = 0; i < 2; i++) {
      int seg = w * 2 + i;
      int row = seg * 16 + srow;
      load_lds16(Ab + (size_t)row * 6144 + kt, (char*)As + seg * 1024);
      load_lds16(Bb + (size_t)row * 6144 + kt, (char*)Bs + seg * 1024);
    }
    __syncthreads();
    bf16x8 af[4], bfr[4];
#pragma unroll
    for (int m = 0; m < 4; m++)
      af[m] = *(const bf16x8*)&As[(wr * 64 + m * 16 + lr) * 32 + lk * 8];
#pragma unroll
    for (int n = 0; n < 4; n++)
      bfr[n] = *(const bf16x8*)&Bs[(wc * 64 + n * 16 + lr) * 32 + lk * 8];
#pragma unroll
    for (int m = 0; m < 4; m++)
#pragma unroll
      for (int n = 0; n < 4; n++)
        acc[m][n] = __builtin_amdgcn_mfma_f32_16x16x32_bf16(af[m], bfr[n], acc[m][n], 0, 0, 0);
    __syncthreads();
  }
  ushort_t* Pt = P + ((size_t)h * 136 + (size_t)(rt * (rt + 1) / 2) + ct) * 16384;
  const bool diag = (rt == ct);
#pragma unroll
  for (int m = 0; m < 4; m++)
#pragma unroll
    for (int n = 0; n < 4; n++) {
      int row = wr * 64 + m * 16 + lk * 4;
      int col = wc * 64 + n * 16 + lr;
#pragma unroll
      for (int j = 0; j < 4; j++) {
        float v = exp2_hw(acc[m][n][j]);
        if (diag && col > row + j) v = 0.f;
        Pt[(row + j) * 128 + col] = f2bf(v);
      }
    }
}

// ---------- rowsum: inv[h][r] = 1 / sum_k P[h][r][k] ----------
__global__ __launch_bounds__(256) void rowsum_kernel(const ushort_t* __restrict__ P,
                                                     float* __restrict__ inv) {
  int row = blockIdx.x * 4 + (threadIdx.x >> 6);  // 0..65535
  int lane = threadIdx.x & 63;
  int h = row >> 11, r = row & 2047;
  int rt = r >> 7, rr = r & 127;
  const ushort_t* Ph = P + ((size_t)h * 136 + (size_t)(rt * (rt + 1) / 2)) * 16384 + rr * 128;
  float s = 0.f;
  for (int ct0 = 0; ct0 <= rt; ct0 += 4) {
    int ct = ct0 + (lane >> 4);
    if (ct <= rt) {
      bf16x8 v = *(const bf16x8*)(Ph + (size_t)ct * 16384 + (lane & 15) * 8);
#pragma unroll
      for (int j = 0; j < 8; j++) s += bf2f((ushort_t)v[j]);
    }
  }
#pragma unroll
  for (int off = 1; off < 64; off <<= 1) s += __shfl_xor(s, off, 64);
  if (lane == 0) inv[row] = 1.0f / s;
}

// ---------- gemmPV: AO[rt-tile] = (P * V) * inv ----------
__global__ __launch_bounds__(256) void gemmPV_kernel(const ushort_t* __restrict__ P,
                                                     const ushort_t* __restrict__ VT,
                                                     const float* __restrict__ inv,
                                                     ushort_t* __restrict__ AO) {
  const int h = blockIdx.x, hk = h >> 2;
  const int rt = 15 - (int)blockIdx.y;

  __shared__ ushort_t As[128 * 32];
  __shared__ ushort_t Bs[128 * 32];
  int tid = threadIdx.x, w = tid >> 6, lane = tid & 63;
  int wr = w >> 1, wc = w & 1;
  int lr = lane & 15, lk = lane >> 4;
  f32x4 acc[4][4] = {};
  int srow = lane >> 2;
  int scol = (lane & 3) * 8;
  const ushort_t* Ph = P + ((size_t)h * 136 + (size_t)(rt * (rt + 1) / 2)) * 16384;
  const ushort_t* Vh = VT + (size_t)hk * 128 * 2048;

  const int nks = (rt + 1) * 4;
  for (int ks = 0; ks < nks; ks++) {
    int k0 = ks * 32;
    int ctk = k0 >> 7, kin = k0 & 127;
#pragma unroll
    for (int i = 0; i < 2; i++) {
      int seg = w * 2 + i;
      int row = seg * 16 + srow;
      load_lds16(Ph + (size_t)ctk * 16384 + (size_t)row * 128 + kin + scol,
                 (char*)As + seg * 1024);
      load_lds16(Vh + (size_t)row * 2048 + k0 + scol, (char*)Bs + seg * 1024);
    }
    __syncthreads();
    bf16x8 af[4], bfr[4];
#pragma unroll
    for (int m = 0; m < 4; m++)
      af[m] = *(const bf16x8*)&As[(wr * 64 + m * 16 + lr) * 32 + lk * 8];
#pragma unroll
    for (int n = 0; n < 4; n++)
      bfr[n] = *(const bf16x8*)&Bs[(wc * 64 + n * 16 + lr) * 32 + lk * 8];
#pragma unroll
    for (int m = 0; m < 4; m++)
#pragma unroll
      for (int n = 0; n < 4; n++)
        acc[m][n] = __builtin_amdgcn_mfma_f32_16x16x32_bf16(af[m], bfr[n], acc[m][n], 0, 0, 0);
    __syncthreads();
  }
  const int q0 = rt * 128;
#pragma unroll
  for (int m = 0; m < 4; m++)
#pragma unroll
    for (int n = 0; n < 4; n++) {
      int row = wr * 64 + m * 16 + lk * 4;
      int col = wc * 64 + n * 16 + lr;
#pragma unroll
      for (int j = 0; j < 4; j++) {
        float v = acc[m][n][j] * inv[h * 2048 + q0 + row + j];
        AO[(size_t)(q0 + row + j) * 4096 + h * 128 + col] = f2bf(v);
      }
    }
}

// ---------- flash attention (fallback when workspace too small) ----------
__global__ __launch_bounds__(256) void fattn_kernel(const ushort_t* __restrict__ C1,
                                                    const ushort_t* __restrict__ VT,
                                                    ushort_t* __restrict__ AO) {
  __shared__ ushort_t Pl[4][32][72];
  const int h = blockIdx.x, hk = h >> 2;
  const int qt = gridDim.y - 1 - blockIdx.y;
  const int tid = threadIdx.x, w = tid >> 6, lane = tid & 63;
  const int lq = lane & 31, hi = lane >> 5;
  const int qw0 = qt * 128 + w * 32;
  const int qabs = qw0 + lq;

  const ushort_t* Kb = C1 + 4096 + (size_t)hk * 128;
  const ushort_t* Vb = VT + (size_t)hk * 128 * 2048;

  bf16x8 qf[8];
  {
    const ushort_t* qrow = C1 + (size_t)qabs * 6144 + h * 128;
#pragma unroll
    for (int s = 0; s < 8; s++) qf[s] = *(const bf16x8*)(qrow + s * 16 + hi * 8);
  }
  f32x16 ot[4] = {};
  float mrow = -1e30f, ssum = 0.f;

  const int ktmax = (qw0 + 31) >> 6;
  for (int kt = 0; kt <= ktmax; kt++) {
    f32x16 sg[2] = {};
#pragma unroll
    for (int g = 0; g < 2; g++) {
      bf16x8 kfa[8];
      const ushort_t* krow = Kb + (size_t)(kt * 64 + g * 32 + lq) * 6144 + hi * 8;
#pragma unroll
      for (int s = 0; s < 8; s++) kfa[s] = *(const bf16x8*)(krow + s * 16);
#pragma unroll
      for (int s = 0; s < 8; s++)
        sg[g] = __builtin_amdgcn_mfma_f32_32x32x16_bf16(kfa[s], qf[s], sg[g], 0, 0, 0);
    }
    if (kt * 64 + 63 > qw0) {
#pragma unroll
      for (int g = 0; g < 2; g++)
#pragma unroll
        for (int r = 0; r < 16; r++) {
          int key = kt * 64 + g * 32 + (r & 3) + 8 * (r >> 2) + 4 * hi;
          if (key > qabs) sg[g][r] = -1e30f;
        }
    }
    float pm = -1e30f;
#pragma unroll
    for (int g = 0; g < 2; g++)
#pragma unroll
      for (int r = 0; r < 16; r++) pm = fmaxf(pm, sg[g][r]);
    pm = fmaxf(pm, __shfl_xor(pm, 32));
    float mnew = fmaxf(mrow, pm);
    float corr = exp2_hw(mrow - mnew);
    mrow = mnew;
    float ps = 0.f;
#pragma unroll
    for (int g = 0; g < 2; g++)
#pragma unroll
      for (int r = 0; r < 16; r++) {
        float e = exp2_hw(sg[g][r] - mnew);
        sg[g][r] = e;
        ps += e;
      }
    ps += __shfl_xor(ps, 32);
    ssum = ssum * corr + ps;
    if (!__all(corr == 1.f)) {
#pragma unroll
      for (int d = 0; d < 4; d++)
#pragma unroll
        for (int r = 0; r < 16; r++) ot[d][r] *= corr;
    }
#pragma unroll
    for (int g = 0; g < 2; g++)
#pragma unroll
      for (int rq = 0; rq < 4; rq++) {
        bf16x4 pk;
#pragma unroll
        for (int j = 0; j < 4; j++) pk[j] = (short)f2bf(sg[g][rq * 4 + j]);
        *(bf16x4*)&Pl[w][lq][g * 32 + rq * 8 + hi * 4] = pk;
      }
    asm volatile("s_waitcnt lgkmcnt(0)" ::: "memory");
    bf16x8 pf[4];
#pragma unroll
    for (int s = 0; s < 4; s++) pf[s] = *(const bf16x8*)&Pl[w][lq][s * 16 + hi * 8];
#pragma unroll
    for (int d = 0; d < 4; d++) {
      bf16x8 vfa[4];
      const ushort_t* vrow = Vb + (size_t)(d * 32 + lq) * 2048 + kt * 64 + hi * 8;
#pragma unroll
      for (int s = 0; s < 4; s++) vfa[s] = *(const bf16x8*)(vrow + s * 16);
#pragma unroll
      for (int s = 0; s < 4; s++)
        ot[d] = __builtin_amdgcn_mfma_f32_32x32x16_bf16(vfa[s], pf[s], ot[d], 0, 0, 0);
    }
  }
  const float inv = 1.0f / ssum;
  ushort_t* orow = AO + (size_t)qabs * 4096 + h * 128;
#pragma unroll
  for (int d = 0; d < 4; d++)
#pragma unroll
    for (int rq = 0; rq < 4; rq++) {
      bf16x4 ok;
#pragma unroll
      for (int j = 0; j < 4; j++) ok[j] = (short)f2bf(ot[d][rq * 4 + j] * inv);
      *(bf16x4*)(orow + d * 32 + rq * 8 + hi * 4) = ok;
    }
}

// ---------- launch ----------
extern "C" void kernel_launch(void* const* d_in, const int* in_sizes, int n_in,
                              void* d_out, int out_size, void* d_ws, size_t ws_size,
                              hipStream_t stream) {
  (void)in_sizes; (void)n_in; (void)out_size;
  const float* x    = (const float*)d_in[0];
  const float* wq   = (const float*)d_in[1];
  const float* wk   = (const float*)d_in[2];
  const float* wv   = (const float*)d_in[3];
  const float* wo   = (const float*)d_in[4];
  const float* cosb = (const float*)d_in[5];
  const float* sinb = (const float*)d_in[6];

  char* ws = (char*)d_ws;
  const bool fast = ws_size >= (215ull << 20);

  if (fast) {
    // layout (MiB): C1[0,24) VT[24,28) woT[28,60) xb[60,76) wT[76,124)
    //               P[60,196) (xb+wT dead after gemm1)  AO[196,212) inv[212,213)
    ushort_t* C1  = (ushort_t*)(ws);
    ushort_t* VT  = (ushort_t*)(ws + ((size_t)24 << 20));
    ushort_t* woT = (ushort_t*)(ws + ((size_t)28 << 20));
    ushort_t* xb  = (ushort_t*)(ws + ((size_t)60 << 20));
    ushort_t* wT  = (ushort_t*)(ws + ((size_t)76 << 20));
    ushort_t* P   = (ushort_t*)(ws + ((size_t)60 << 20));
    ushort_t* AO  = (ushort_t*)(ws + ((size_t)196 << 20));
    float*    inv = (float*)(ws + ((size_t)212 << 20));

    cvt_x_kernel<<<4096, 256, 0, stream>>>(x, xb);
    tr_cvt_kernel<<<dim3(64, 64), 256, 0, stream>>>(wq, wT, 4096, 4096);
    tr_cvt_kernel<<<dim3(16, 64), 256, 0, stream>>>(wk, wT + (size_t)4096 * 4096, 4096, 1024);
    tr_cvt_kernel<<<dim3(16, 64), 256, 0, stream>>>(wv, wT + (size_t)5120 * 4096, 4096, 1024);
    tr_cvt_kernel<<<dim3(64, 64), 256, 0, stream>>>(wo, woT, 4096, 4096);

    // QKV projection: 256^2 8-phase GEMM, grid 8x24 = 192 (192%8==0)
    gemm256p8_kernel<ushort_t><<<192, 512, 0, stream>>>(xb, wT, C1, 2048, 6144, 4096, 6144);
    rope_kernel<<<5120, 256, 0, stream>>>(C1, cosb, sinb);
    trv_kernel<<<dim3(16, 32), 256, 0, stream>>>(C1, VT);

    gemmS_kernel<<<dim3(136, 32), 256, 0, stream>>>(C1, P);
    rowsum_kernel<<<16384, 256, 0, stream>>>(P, inv);
    gemmPV_kernel<<<dim3(32, 16), 256, 0, stream>>>(P, VT, inv, AO);

    // output projection: grid 8x16 = 128 (128%8==0)
    gemm256p8_kernel<float><<<128, 512, 0, stream>>>(AO, woT, (float*)d_out, 2048, 4096, 4096, 4096);
  } else {
    // proven 92MiB layout + R7 fattn
    ushort_t* xb  = (ushort_t*)(ws);
    ushort_t* wT  = (ushort_t*)(ws + ((size_t)16 << 20));
    ushort_t* C1  = (ushort_t*)(ws + ((size_t)64 << 20));
    ushort_t* VT  = (ushort_t*)(ws + ((size_t)88 << 20));
    ushort_t* AO  = xb;
    ushort_t* woT = wT;

    cvt_x_kernel<<<4096, 256, 0, stream>>>(x, xb);
    tr_cvt_kernel<<<dim3(64, 64), 256, 0, stream>>>(wq, wT, 4096, 4096);
    tr_cvt_kernel<<<dim3(16, 64), 256, 0, stream>>>(wk, wT + (size_t)4096 * 4096, 4096, 1024);
    tr_cvt_kernel<<<dim3(16, 64), 256, 0, stream>>>(wv, wT + (size_t)5120 * 4096, 4096, 1024);
    gemm128_kernel<ushort_t><<<dim3(48, 16), 256, 0, stream>>>(xb, wT, C1, 2048, 6144, 4096, 6144);
    rope_kernel<<<5120, 256, 0, stream>>>(C1, cosb, sinb);
    trv_kernel<<<dim3(16, 32), 256, 0, stream>>>(C1, VT);
    tr_cvt_kernel<<<dim3(64, 64), 256, 0, stream>>>(wo, woT, 4096, 4096);
    fattn_kernel<<<dim3(32, 16), 256, 0, stream>>>(C1, VT, AO);
    gemm128_kernel<float><<<dim3(32, 16), 256, 0, stream>>>(AO, woT, (float*)d_out, 2048, 4096, 4096, 4096);
  }
}

// Round 12
// 409.535 us; speedup vs baseline: 1.0357x; 1.0357x over previous
//
#include <hip/hip_runtime.h>
#include <stdint.h>

typedef unsigned short ushort_t;
typedef short bf16x4 __attribute__((ext_vector_type(4)));
typedef short bf16x8 __attribute__((ext_vector_type(8)));
typedef float f32x4 __attribute__((ext_vector_type(4)));
typedef float f32x16 __attribute__((ext_vector_type(16)));
typedef float f32x4v __attribute__((ext_vector_type(4)));

// ---------- helpers ----------
__device__ __forceinline__ ushort_t f2bf(float f) {
  unsigned int u = __builtin_bit_cast(unsigned int, f);
  u += 0x7fffu + ((u >> 16) & 1u);
  return (ushort_t)(u >> 16);
}
__device__ __forceinline__ float bf2f(ushort_t h) {
  unsigned int u = ((unsigned int)h) << 16;
  return __builtin_bit_cast(float, u);
}
__device__ __forceinline__ float exp2_hw(float x) {
  return __builtin_amdgcn_exp2f(x);  // v_exp_f32: D = 2^S0
}
__device__ __forceinline__ void load_lds16(const void* g, void* l) {
  __builtin_amdgcn_global_load_lds(
      (const __attribute__((address_space(1))) void*)g,
      (__attribute__((address_space(3))) void*)l, 16, 0, 0);
}

// ---------- x fp32 -> bf16 ----------
__global__ __launch_bounds__(256) void cvt_x_kernel(const float* __restrict__ x,
                                                    ushort_t* __restrict__ xb) {
  int i = blockIdx.x * 256 + threadIdx.x;  // each thread: 8 elems
  const f32x4v* xv = (const f32x4v*)x;
  f32x4v a = xv[2 * i], b = xv[2 * i + 1];
  bf16x8 o;
  o[0] = (short)f2bf(a[0]); o[1] = (short)f2bf(a[1]);
  o[2] = (short)f2bf(a[2]); o[3] = (short)f2bf(a[3]);
  o[4] = (short)f2bf(b[0]); o[5] = (short)f2bf(b[1]);
  o[6] = (short)f2bf(b[2]); o[7] = (short)f2bf(b[3]);
  ((bf16x8*)xb)[i] = o;
}

// ---------- weight fp32 [R][C] -> bf16 transposed [C][R] ----------
__global__ __launch_bounds__(256) void tr_cvt_kernel(const float* __restrict__ src,
                                                     ushort_t* __restrict__ dst,
                                                     int R, int C) {
  __shared__ float tile[64][65];
  int r0 = blockIdx.y * 64, c0 = blockIdx.x * 64;
  int t = threadIdx.x;
#pragma unroll
  for (int i = 0; i < 16; i++) {
    int idx = t + i * 256;
    int r = idx >> 6, c = idx & 63;
    tile[r][c] = src[(size_t)(r0 + r) * C + c0 + c];
  }
  __syncthreads();
#pragma unroll
  for (int i = 0; i < 16; i++) {
    int idx = t + i * 256;
    int cr = idx >> 6, cc = idx & 63;
    dst[(size_t)(c0 + cr) * R + r0 + cc] = f2bf(tile[cc][cr]);
  }
}

// ---------- RoPE in-place on C1 (Q cols 0..4095 pre-scaled by scale*log2e) ----------
__global__ __launch_bounds__(256) void rope_kernel(ushort_t* __restrict__ C1,
                                                   const float* __restrict__ cosb,
                                                   const float* __restrict__ sinb) {
  int idx = blockIdx.x * 256 + threadIdx.x;  // 2048 * 640
  int s = idx / 640;
  int col0 = (idx % 640) * 8;
  int i0 = (col0 & 127) >> 1;
  const float qs = (col0 < 4096) ? 0.12753055296570565f : 1.0f;  // scale*log2e
  ushort_t* p = C1 + (size_t)s * 6144 + col0;
  bf16x8 v = *(const bf16x8*)p;
  bf16x8 o;
  const float* cr = cosb + s * 64 + i0;
  const float* sr = sinb + s * 64 + i0;
#pragma unroll
  for (int j = 0; j < 4; j++) {
    float tr = bf2f((ushort_t)v[2 * j]);
    float ti = bf2f((ushort_t)v[2 * j + 1]);
    float c = cr[j], sn = sr[j];
    o[2 * j] = (short)f2bf((tr * c - ti * sn) * qs);
    o[2 * j + 1] = (short)f2bf((tr * sn + ti * c) * qs);
  }
  *(bf16x8*)p = o;
}

// ---------- V part of C1 -> VT [1024][2048] (row = hk*128+d, col = s) ----------
__global__ __launch_bounds__(256) void trv_kernel(const ushort_t* __restrict__ C1,
                                                  ushort_t* __restrict__ VT) {
  __shared__ ushort_t tile[64][65];
  int c0 = blockIdx.x * 64;  // within 1024
  int r0 = blockIdx.y * 64;  // within 2048
  int t = threadIdx.x;
#pragma unroll
  for (int i = 0; i < 16; i++) {
    int idx = t + i * 256;
    int r = idx >> 6, c = idx & 63;
    tile[r][c] = C1[(size_t)(r0 + r) * 6144 + 5120 + c0 + c];
  }
  __syncthreads();
#pragma unroll
  for (int i = 0; i < 16; i++) {
    int idx = t + i * 256;
    int cr = idx >> 6, cc = idx & 63;
    VT[(size_t)(c0 + cr) * 2048 + r0 + cc] = tile[cc][cr];
  }
}

// ---------- GEMM 256x256 8-phase (m201 port: T1+T2+T3/T4+T5) ----------
// (unchanged from R11 — verified; used for gemm1 where grid 192 fits 75% of CUs)
template <typename OutT>
__global__ __launch_bounds__(512) void gemm256p8_kernel(const ushort_t* __restrict__ A,
                                                        const ushort_t* __restrict__ BT,
                                                        OutT* __restrict__ C,
                                                        int M, int N, int K, int ldc) {
  __shared__ ushort_t As[2][256 * 64];  // 64KB
  __shared__ ushort_t Bs[2][256 * 64];  // 64KB
  const int nbx = N >> 8;
  const int nwg = gridDim.x;
  const int id = blockIdx.x;
  const int wg = (id & 7) * (nwg >> 3) + (id >> 3);  // XCD-contiguous (nwg%8==0)
  const int brow = (wg / nbx) << 8, bcol = (wg % nbx) << 8;
  const int tid = threadIdx.x, w = tid >> 6, lane = tid & 63;
  const int wr = w >> 2, wc = w & 3;
  const int lr = lane & 15, lk = lane >> 4;

  const ushort_t* Ab = A + (size_t)brow * K;
  const ushort_t* Bb = BT + (size_t)bcol * K;

  auto stageQ = [&](const ushort_t* gbase, char* lds, int t, int q) {
    int L = q * 512 + tid;
    int r = L >> 3, sc = L & 7;
    load_lds16(gbase + (size_t)r * K + (t << 6) + ((sc ^ (r & 7)) << 3), lds + L * 16);
  };

  f32x4 acc[8][4] = {};
  const int NT = K >> 6;

#pragma unroll
  for (int q = 0; q < 4; ++q) stageQ(Ab, (char*)&As[0][0], 0, q);
#pragma unroll
  for (int q = 0; q < 4; ++q) stageQ(Bb, (char*)&Bs[0][0], 0, q);
  asm volatile("s_waitcnt vmcnt(0)" ::: "memory");
  __builtin_amdgcn_s_barrier();

  for (int t = 0; t < NT; ++t) {
    const int c = t & 1;
    const char* Ac = (const char*)&As[c][0];
    const char* Bc = (const char*)&Bs[c][0];
    char* An = (char*)&As[c ^ 1][0];
    char* Bn = (char*)&Bs[c ^ 1][0];
    const bool pf = (t + 1 < NT);

    bf16x8 af[4][2], bfr[4][2];
    // ======== phase 0: A mh0 (8 reads) + B n0,n1 (4) ; stage Aq0,Aq2 ========
#pragma unroll
    for (int mm = 0; mm < 4; ++mm)
#pragma unroll
      for (int ks = 0; ks < 2; ++ks) {
        int rA = wr * 128 + mm * 16 + lr;
        af[mm][ks] = *(const bf16x8*)(Ac + rA * 128 + (((ks * 4 + lk) ^ (rA & 7)) << 4));
      }
#pragma unroll
    for (int n = 0; n < 2; ++n)
#pragma unroll
      for (int ks = 0; ks < 2; ++ks) {
        int rB = wc * 64 + n * 16 + lr;
        bfr[n][ks] = *(const bf16x8*)(Bc + rB * 128 + (((ks * 4 + lk) ^ (rB & 7)) << 4));
      }
    if (pf) { stageQ(Ab, An, t + 1, 0); stageQ(Ab, An, t + 1, 2); }
    __builtin_amdgcn_s_barrier();
    asm volatile("s_waitcnt lgkmcnt(0)" ::: "memory");
    __builtin_amdgcn_sched_barrier(0);
    __builtin_amdgcn_s_setprio(1);
#pragma unroll
    for (int mm = 0; mm < 4; ++mm)
#pragma unroll
      for (int n = 0; n < 2; ++n)
#pragma unroll
        for (int ks = 0; ks < 2; ++ks)
          acc[mm][n] = __builtin_amdgcn_mfma_f32_16x16x32_bf16(af[mm][ks], bfr[n][ks],
                                                               acc[mm][n], 0, 0, 0);
    __builtin_amdgcn_s_setprio(0);
    __builtin_amdgcn_s_barrier();

    // ======== phase 1: B n2,n3 (4 reads) ; stage Bq0,Bq1 ; vmcnt(4) ========
#pragma unroll
    for (int n = 2; n < 4; ++n)
#pragma unroll
      for (int ks = 0; ks < 2; ++ks) {
        int rB = wc * 64 + n * 16 + lr;
        bfr[n][ks] = *(const bf16x8*)(Bc + rB * 128 + (((ks * 4 + lk) ^ (rB & 7)) << 4));
      }
    if (pf) { stageQ(Bb, Bn, t + 1, 0); stageQ(Bb, Bn, t + 1, 1); }
    __builtin_amdgcn_s_barrier();
    asm volatile("s_waitcnt lgkmcnt(0)" ::: "memory");
    __builtin_amdgcn_sched_barrier(0);
    __builtin_amdgcn_s_setprio(1);
#pragma unroll
    for (int mm = 0; mm < 4; ++mm)
#pragma unroll
      for (int n = 2; n < 4; ++n)
#pragma unroll
        for (int ks = 0; ks < 2; ++ks)
          acc[mm][n] = __builtin_amdgcn_mfma_f32_16x16x32_bf16(af[mm][ks], bfr[n][ks],
                                                               acc[mm][n], 0, 0, 0);
    __builtin_amdgcn_s_setprio(0);
    asm volatile("s_waitcnt vmcnt(4)" ::: "memory");  // A-odd quarters of tile t landed
    __builtin_amdgcn_s_barrier();

    // ======== phase 2: A mh1 (8 reads) ; stage Bq2,Bq3 ========
#pragma unroll
    for (int mm = 0; mm < 4; ++mm)
#pragma unroll
      for (int ks = 0; ks < 2; ++ks) {
        int rA = wr * 128 + 64 + mm * 16 + lr;
        af[mm][ks] = *(const bf16x8*)(Ac + rA * 128 + (((ks * 4 + lk) ^ (rA & 7)) << 4));
      }
    if (pf) { stageQ(Bb, Bn, t + 1, 2); stageQ(Bb, Bn, t + 1, 3); }
    __builtin_amdgcn_s_barrier();
    asm volatile("s_waitcnt lgkmcnt(0)" ::: "memory");
    __builtin_amdgcn_sched_barrier(0);
    __builtin_amdgcn_s_setprio(1);
#pragma unroll
    for (int mm = 0; mm < 4; ++mm)
#pragma unroll
      for (int n = 0; n < 2; ++n)
#pragma unroll
        for (int ks = 0; ks < 2; ++ks)
          acc[4 + mm][n] = __builtin_amdgcn_mfma_f32_16x16x32_bf16(af[mm][ks], bfr[n][ks],
                                                                   acc[4 + mm][n], 0, 0, 0);
    __builtin_amdgcn_s_setprio(0);
    __builtin_amdgcn_s_barrier();

    // ======== phase 3: no reads ; stage Aq1,Aq3 ; MFMA ; vmcnt(2) boundary ========
    if (pf) { stageQ(Ab, An, t + 1, 1); stageQ(Ab, An, t + 1, 3); }
    __builtin_amdgcn_s_setprio(1);
#pragma unroll
    for (int mm = 0; mm < 4; ++mm)
#pragma unroll
      for (int n = 2; n < 4; ++n)
#pragma unroll
        for (int ks = 0; ks < 2; ++ks)
          acc[4 + mm][n] = __builtin_amdgcn_mfma_f32_16x16x32_bf16(af[mm][ks], bfr[n][ks],
                                                                   acc[4 + mm][n], 0, 0, 0);
    __builtin_amdgcn_s_setprio(0);
    asm volatile("s_waitcnt vmcnt(2)" ::: "memory");  // all but Aq1,Aq3(t+1) landed
    __builtin_amdgcn_s_barrier();
  }
  // epilogue
#pragma unroll
  for (int m = 0; m < 8; ++m)
#pragma unroll
    for (int n = 0; n < 4; ++n) {
      int row = brow + wr * 128 + m * 16 + lk * 4;
      int col = bcol + wc * 64 + n * 16 + lr;
#pragma unroll
      for (int j = 0; j < 4; ++j) {
        float v = acc[m][n][j];
        if constexpr (sizeof(OutT) == 2)
          C[(size_t)(row + j) * ldc + col] = (OutT)f2bf(v);
        else
          C[(size_t)(row + j) * ldc + col] = v;
      }
    }
}

// ---------- GEMM 128x256, 3-buffer 4-phase p8 (full-grid variant for gemm2) ----------
// C[M][ldc] = A[M][K]*BT[N][K]^T. M%128==0, N%256==0, K%64==0, K/64>=3,
// grid 1D = (M/128)*(N/256), grid%8==0. 512 thr = 8 waves (2Mr x 4Nc),
// per-wave 64x64 out (acc[4][4]). LDS 144KB = 3 x (A 16KB + B 32KB).
// All of tile t's A and B are needed at its phase 0 (64-row stripes per wave),
// so staging targets t+2 (prefetch depth 2); buffer (t+2)%3 == (t-1)%3, whose
// readers all finished before tile t-1's closing barrier -> no clobber.
// Boundary: vmcnt(6) = t+2's 6 loads may remain, t+1 fully landed (T4: counted,
// never 0 mid-loop); vmcnt-then-barrier makes every wave's slice visible.
template <typename OutT>
__global__ __launch_bounds__(512) void gemmB_kernel(const ushort_t* __restrict__ A,
                                                    const ushort_t* __restrict__ BT,
                                                    OutT* __restrict__ C,
                                                    int M, int N, int K, int ldc) {
  __shared__ ushort_t As[3][128 * 64];  // 48KB
  __shared__ ushort_t Bs[3][256 * 64];  // 96KB
  const int nbx = N >> 8;
  const int nwg = gridDim.x;
  const int id = blockIdx.x;
  const int wg = (id & 7) * (nwg >> 3) + (id >> 3);  // XCD-contiguous (nwg%8==0)
  const int brow = (wg / nbx) << 7, bcol = (wg % nbx) << 8;
  const int tid = threadIdx.x, w = tid >> 6, lane = tid & 63;
  const int wr = w >> 2, wc = w & 3;
  const int lr = lane & 15, lk = lane >> 4;

  const ushort_t* Ab = A + (size_t)brow * K;
  const ushort_t* Bb = BT + (size_t)bcol * K;

  // quarter q = 64 rows x 64 cols, 1 load/thread (512 x 16B = 8KB)
  auto stageQ = [&](const ushort_t* gbase, char* lds, int t, int q) {
    int L = q * 512 + tid;
    int r = L >> 3, sc = L & 7;
    load_lds16(gbase + (size_t)r * K + (t << 6) + ((sc ^ (r & 7)) << 3), lds + L * 16);
  };
  // full-tile stage = A q0,q1 then B q0..q3 (6 loads, this issue order matters)
  auto stageTile = [&](int t, int buf) {
    stageQ(Ab, (char*)&As[buf][0], t, 0);
    stageQ(Ab, (char*)&As[buf][0], t, 1);
#pragma unroll
    for (int q = 0; q < 4; ++q) stageQ(Bb, (char*)&Bs[buf][0], t, q);
  };

  f32x4 acc[4][4] = {};
  const int NT = K >> 6;

  // prologue: tiles 0,1 staged (12 loads); wait tile0 (6 of tile1 remain)
  stageTile(0, 0);
  stageTile(1, 1);
  asm volatile("s_waitcnt vmcnt(6)" ::: "memory");
  __builtin_amdgcn_s_barrier();

  int cur = 0;
  for (int t = 0; t < NT; ++t) {
    const char* Ac = (const char*)&As[cur][0];
    const char* Bc = (const char*)&Bs[cur][0];
    const int nxt = (cur + 2 >= 3) ? cur - 1 : cur + 2;  // (t+2)%3
    char* An = (char*)&As[nxt][0];
    char* Bn = (char*)&Bs[nxt][0];
    const bool pf = (t + 2 < NT);

    bf16x8 af[4][2], bfr[4][2];
    // ===== phase 0: A m0,m1 (4 reads) + B n0,n1 (4 reads); stage Aq0(t+2) =====
#pragma unroll
    for (int mm = 0; mm < 2; ++mm)
#pragma unroll
      for (int ks = 0; ks < 2; ++ks) {
        int rA = wr * 64 + mm * 16 + lr;
        af[mm][ks] = *(const bf16x8*)(Ac + rA * 128 + (((ks * 4 + lk) ^ (rA & 7)) << 4));
      }
#pragma unroll
    for (int n = 0; n < 2; ++n)
#pragma unroll
      for (int ks = 0; ks < 2; ++ks) {
        int rB = wc * 64 + n * 16 + lr;
        bfr[n][ks] = *(const bf16x8*)(Bc + rB * 128 + (((ks * 4 + lk) ^ (rB & 7)) << 4));
      }
    if (pf) stageQ(Ab, An, t + 2, 0);
    __builtin_amdgcn_s_barrier();
    asm volatile("s_waitcnt lgkmcnt(0)" ::: "memory");
    __builtin_amdgcn_sched_barrier(0);
    __builtin_amdgcn_s_setprio(1);
#pragma unroll
    for (int mm = 0; mm < 2; ++mm)
#pragma unroll
      for (int n = 0; n < 2; ++n)
#pragma unroll
        for (int ks = 0; ks < 2; ++ks)
          acc[mm][n] = __builtin_amdgcn_mfma_f32_16x16x32_bf16(af[mm][ks], bfr[n][ks],
                                                               acc[mm][n], 0, 0, 0);
    __builtin_amdgcn_s_setprio(0);
    __builtin_amdgcn_s_barrier();

    // ===== phase 1: B n2,n3 (4 reads); stage Aq1(t+2) =====
#pragma unroll
    for (int n = 2; n < 4; ++n)
#pragma unroll
      for (int ks = 0; ks < 2; ++ks) {
        int rB = wc * 64 + n * 16 + lr;
        bfr[n][ks] = *(const bf16x8*)(Bc + rB * 128 + (((ks * 4 + lk) ^ (rB & 7)) << 4));
      }
    if (pf) stageQ(Ab, An, t + 2, 1);
    __builtin_amdgcn_s_barrier();
    asm volatile("s_waitcnt lgkmcnt(0)" ::: "memory");
    __builtin_amdgcn_sched_barrier(0);
    __builtin_amdgcn_s_setprio(1);
#pragma unroll
    for (int mm = 0; mm < 2; ++mm)
#pragma unroll
      for (int n = 2; n < 4; ++n)
#pragma unroll
        for (int ks = 0; ks < 2; ++ks)
          acc[mm][n] = __builtin_amdgcn_mfma_f32_16x16x32_bf16(af[mm][ks], bfr[n][ks],
                                                               acc[mm][n], 0, 0, 0);
    __builtin_amdgcn_s_setprio(0);
    __builtin_amdgcn_s_barrier();

    // ===== phase 2: A m2,m3 (4 reads); stage Bq0,Bq1(t+2) =====
#pragma unroll
    for (int mm = 0; mm < 2; ++mm)
#pragma unroll
      for (int ks = 0; ks < 2; ++ks) {
        int rA = wr * 64 + (mm + 2) * 16 + lr;
        af[2 + mm][ks] = *(const bf16x8*)(Ac + rA * 128 + (((ks * 4 + lk) ^ (rA & 7)) << 4));
      }
    if (pf) { stageQ(Bb, Bn, t + 2, 0); stageQ(Bb, Bn, t + 2, 1); }
    __builtin_amdgcn_s_barrier();
    asm volatile("s_waitcnt lgkmcnt(0)" ::: "memory");
    __builtin_amdgcn_sched_barrier(0);
    __builtin_amdgcn_s_setprio(1);
#pragma unroll
    for (int mm = 0; mm < 2; ++mm)
#pragma unroll
      for (int n = 0; n < 2; ++n)
#pragma unroll
        for (int ks = 0; ks < 2; ++ks)
          acc[2 + mm][n] = __builtin_amdgcn_mfma_f32_16x16x32_bf16(af[2 + mm][ks], bfr[n][ks],
                                                                   acc[2 + mm][n], 0, 0, 0);
    __builtin_amdgcn_s_setprio(0);
    __builtin_amdgcn_s_barrier();

    // ===== phase 3: no reads; stage Bq2,Bq3(t+2); MFMA; counted boundary =====
    if (pf) { stageQ(Bb, Bn, t + 2, 2); stageQ(Bb, Bn, t + 2, 3); }
    __builtin_amdgcn_s_setprio(1);
#pragma unroll
    for (int mm = 0; mm < 2; ++mm)
#pragma unroll
      for (int n = 2; n < 4; ++n)
#pragma unroll
        for (int ks = 0; ks < 2; ++ks)
          acc[2 + mm][n] = __builtin_amdgcn_mfma_f32_16x16x32_bf16(af[2 + mm][ks], bfr[n][ks],
                                                                   acc[2 + mm][n], 0, 0, 0);
    __builtin_amdgcn_s_setprio(0);
    if (pf)
      asm volatile("s_waitcnt vmcnt(6)" ::: "memory");  // t+1 landed; t+2 in flight
    else if (t + 1 < NT)
      asm volatile("s_waitcnt vmcnt(0)" ::: "memory");  // tail drain
    __builtin_amdgcn_s_barrier();
    cur = (cur == 2) ? 0 : cur + 1;
  }
  // epilogue
#pragma unroll
  for (int m = 0; m < 4; ++m)
#pragma unroll
    for (int n = 0; n < 4; ++n) {
      int row = brow + wr * 64 + m * 16 + lk * 4;
      int col = bcol + wc * 64 + n * 16 + lr;
#pragma unroll
      for (int j = 0; j < 4; ++j) {
        float v = acc[m][n][j];
        if constexpr (sizeof(OutT) == 2)
          C[(size_t)(row + j) * ldc + col] = (OutT)f2bf(v);
        else
          C[(size_t)(row + j) * ldc + col] = v;
      }
    }
}

// ---------- GEMM: C[M][ldc] = A[M][K] * BT[N][K]^T  (m97 structure, fallback) ----------
template <typename OutT>
__global__ __launch_bounds__(256) void gemm128_kernel(const ushort_t* __restrict__ A,
                                                      const ushort_t* __restrict__ BT,
                                                      OutT* __restrict__ C,
                                                      int M, int N, int K, int ldc) {
  __shared__ ushort_t As[128 * 32];
  __shared__ ushort_t Bs[128 * 32];
  int brow = blockIdx.y * 128, bcol = blockIdx.x * 128;
  int tid = threadIdx.x, w = tid >> 6, lane = tid & 63;
  int wr = w >> 1, wc = w & 1;
  int lr = lane & 15, lk = lane >> 4;
  f32x4 acc[4][4] = {};

  int srow = lane >> 2;
  int scol = (lane & 3) * 8;
  const ushort_t* Ab = A + (size_t)brow * K + scol;
  const ushort_t* Bb = BT + (size_t)bcol * K + scol;

  for (int kt = 0; kt < K; kt += 32) {
#pragma unroll
    for (int i = 0; i < 2; i++) {
      int seg = w * 2 + i;
      int row = seg * 16 + srow;
      load_lds16(Ab + (size_t)row * K + kt, (char*)As + seg * 1024);
      load_lds16(Bb + (size_t)row * K + kt, (char*)Bs + seg * 1024);
    }
    __syncthreads();
    bf16x8 af[4], bfr[4];
#pragma unroll
    for (int m = 0; m < 4; m++)
      af[m] = *(const bf16x8*)&As[(wr * 64 + m * 16 + lr) * 32 + lk * 8];
#pragma unroll
    for (int n = 0; n < 4; n++)
      bfr[n] = *(const bf16x8*)&Bs[(wc * 64 + n * 16 + lr) * 32 + lk * 8];
#pragma unroll
    for (int m = 0; m < 4; m++)
#pragma unroll
      for (int n = 0; n < 4; n++)
        acc[m][n] = __builtin_amdgcn_mfma_f32_16x16x32_bf16(af[m], bfr[n], acc[m][n], 0, 0, 0);
    __syncthreads();
  }
#pragma unroll
  for (int m = 0; m < 4; m++)
#pragma unroll
    for (int n = 0; n < 4; n++) {
      int row = brow + wr * 64 + m * 16 + lk * 4;
      int col = bcol + wc * 64 + n * 16 + lr;
#pragma unroll
      for (int j = 0; j < 4; j++) {
        float v = acc[m][n][j];
        if constexpr (sizeof(OutT) == 2)
          C[(size_t)(row + j) * ldc + col] = (OutT)f2bf(v);
        else
          C[(size_t)(row + j) * ldc + col] = v;
      }
    }
}

// ---------- gemmS: P[tile] = exp2(Q K^T) causal, materialized bf16 ----------
__global__ __launch_bounds__(256) void gemmS_kernel(const ushort_t* __restrict__ C1,
                                                    ushort_t* __restrict__ P) {
  int rem = blockIdx.x, rt = 0;
  while (rem > rt) { rem -= (rt + 1); rt++; }
  const int ct = rem;
  const int h = blockIdx.y, hk = h >> 2;

  __shared__ ushort_t As[128 * 32];
  __shared__ ushort_t Bs[128 * 32];
  int tid = threadIdx.x, w = tid >> 6, lane = tid & 63;
  int wr = w >> 1, wc = w & 1;
  int lr = lane & 15, lk = lane >> 4;
  f32x4 acc[4][4] = {};
  int srow = lane >> 2;
  int scol = (lane & 3) * 8;
  const ushort_t* Ab = C1 + (size_t)(rt * 128) * 6144 + h * 128 + scol;         // Q
  const ushort_t* Bb = C1 + (size_t)(ct * 128) * 6144 + 4096 + hk * 128 + scol; // K

  for (int kt = 0; kt < 128; kt += 32) {
#pragma unroll
    for (int i = 0; i < 2; i++) {
      int seg = w * 2 + i;
      int row = seg * 16 + srow;
      load_lds16(Ab + (size_t)row * 6144 + kt, (char*)As + seg * 1024);
      load_lds16(Bb + (size_t)row * 6144 + kt, (char*)Bs + seg * 1024);
    }
    __syncthreads();
    bf16x8 af[4], bfr[4];
#pragma unroll
    for (int m = 0; m < 4; m++)
      af[m] = *(const bf16x8*)&As[(wr * 64 + m * 16 + lr) * 32 + lk * 8];
#pragma unroll
    for (int n = 0; n < 4; n++)
      bfr[n] = *(const bf16x8*)&Bs[(wc * 64 + n * 16 + lr) * 32 + lk * 8];
#pragma unroll
    for (int m = 0; m < 4; m++)
#pragma unroll
      for (int n = 0; n < 4; n++)
        acc[m][n] = __builtin_amdgcn_mfma_f32_16x16x32_bf16(af[m], bfr[n], acc[m][n], 0, 0, 0);
    __syncthreads();
  }
  ushort_t* Pt = P + ((size_t)h * 136 + (size_t)(rt * (rt + 1) / 2) + ct) * 16384;
  const bool diag = (rt == ct);
#pragma unroll
  for (int m = 0; m < 4; m++)
#pragma unroll
    for (int n = 0; n < 4; n++) {
      int row = wr * 64 + m * 16 + lk * 4;
      int col = wc * 64 + n * 16 + lr;
#pragma unroll
      for (int j = 0; j < 4; j++) {
        float v = exp2_hw(acc[m][n][j]);
        if (diag && col > row + j) v = 0.f;
        Pt[(row + j) * 128 + col] = f2bf(v);
      }
    }
}

// ---------- rowsum: inv[h][r] = 1 / sum_k P[h][r][k] ----------
__global__ __launch_bounds__(256) void rowsum_kernel(const ushort_t* __restrict__ P,
                                                     float* __restrict__ inv) {
  int row = blockIdx.x * 4 + (threadIdx.x >> 6);  // 0..65535
  int lane = threadIdx.x & 63;
  int h = row >> 11, r = row & 2047;
  int rt = r >> 7, rr = r & 127;
  const ushort_t* Ph = P + ((size_t)h * 136 + (size_t)(rt * (rt + 1) / 2)) * 16384 + rr * 128;
  float s = 0.f;
  for (int ct0 = 0; ct0 <= rt; ct0 += 4) {
    int ct = ct0 + (lane >> 4);
    if (ct <= rt) {
      bf16x8 v = *(const bf16x8*)(Ph + (size_t)ct * 16384 + (lane & 15) * 8);
#pragma unroll
      for (int j = 0; j < 8; j++) s += bf2f((ushort_t)v[j]);
    }
  }
#pragma unroll
  for (int off = 1; off < 64; off <<= 1) s += __shfl_xor(s, off, 64);
  if (lane == 0) inv[row] = 1.0f / s;
}

// ---------- gemmPV: AO[rt-tile] = (P * V) * inv ----------
__global__ __launch_bounds__(256) void gemmPV_kernel(const ushort_t* __restrict__ P,
                                                     const ushort_t* __restrict__ VT,
                                                     const float* __restrict__ inv,
                                                     ushort_t* __restrict__ AO) {
  const int h = blockIdx.x, hk = h >> 2;
  const int rt = 15 - (int)blockIdx.y;

  __shared__ ushort_t As[128 * 32];
  __shared__ ushort_t Bs[128 * 32];
  int tid = threadIdx.x, w = tid >> 6, lane = tid & 63;
  int wr = w >> 1, wc = w & 1;
  int lr = lane & 15, lk = lane >> 4;
  f32x4 acc[4][4] = {};
  int srow = lane >> 2;
  int scol = (lane & 3) * 8;
  const ushort_t* Ph = P + ((size_t)h * 136 + (size_t)(rt * (rt + 1) / 2)) * 16384;
  const ushort_t* Vh = VT + (size_t)hk * 128 * 2048;

  const int nks = (rt + 1) * 4;
  for (int ks = 0; ks < nks; ks++) {
    int k0 = ks * 32;
    int ctk = k0 >> 7, kin = k0 & 127;
#pragma unroll
    for (int i = 0; i < 2; i++) {
      int seg = w * 2 + i;
      int row = seg * 16 + srow;
      load_lds16(Ph + (size_t)ctk * 16384 + (size_t)row * 128 + kin + scol,
                 (char*)As + seg * 1024);
      load_lds16(Vh + (size_t)row * 2048 + k0 + scol, (char*)Bs + seg * 1024);
    }
    __syncthreads();
    bf16x8 af[4], bfr[4];
#pragma unroll
    for (int m = 0; m < 4; m++)
      af[m] = *(const bf16x8*)&As[(wr * 64 + m * 16 + lr) * 32 + lk * 8];
#pragma unroll
    for (int n = 0; n < 4; n++)
      bfr[n] = *(const bf16x8*)&Bs[(wc * 64 + n * 16 + lr) * 32 + lk * 8];
#pragma unroll
    for (int m = 0; m < 4; m++)
#pragma unroll
      for (int n = 0; n < 4; n++)
        acc[m][n] = __builtin_amdgcn_mfma_f32_16x16x32_bf16(af[m], bfr[n], acc[m][n], 0, 0, 0);
    __syncthreads();
  }
  const int q0 = rt * 128;
#pragma unroll
  for (int m = 0; m < 4; m++)
#pragma unroll
    for (int n = 0; n < 4; n++) {
      int row = wr * 64 + m * 16 + lk * 4;
      int col = wc * 64 + n * 16 + lr;
#pragma unroll
      for (int j = 0; j < 4; j++) {
        float v = acc[m][n][j] * inv[h * 2048 + q0 + row + j];
        AO[(size_t)(q0 + row + j) * 4096 + h * 128 + col] = f2bf(v);
      }
    }
}

// ---------- flash attention (fallback when workspace too small) ----------
__global__ __launch_bounds__(256) void fattn_kernel(const ushort_t* __restrict__ C1,
                                                    const ushort_t* __restrict__ VT,
                                                    ushort_t* __restrict__ AO) {
  __shared__ ushort_t Pl[4][32][72];
  const int h = blockIdx.x, hk = h >> 2;
  const int qt = gridDim.y - 1 - blockIdx.y;
  const int tid = threadIdx.x, w = tid >> 6, lane = tid & 63;
  const int lq = lane & 31, hi = lane >> 5;
  const int qw0 = qt * 128 + w * 32;
  const int qabs = qw0 + lq;

  const ushort_t* Kb = C1 + 4096 + (size_t)hk * 128;
  const ushort_t* Vb = VT + (size_t)hk * 128 * 2048;

  bf16x8 qf[8];
  {
    const ushort_t* qrow = C1 + (size_t)qabs * 6144 + h * 128;
#pragma unroll
    for (int s = 0; s < 8; s++) qf[s] = *(const bf16x8*)(qrow + s * 16 + hi * 8);
  }
  f32x16 ot[4] = {};
  float mrow = -1e30f, ssum = 0.f;

  const int ktmax = (qw0 + 31) >> 6;
  for (int kt = 0; kt <= ktmax; kt++) {
    f32x16 sg[2] = {};
#pragma unroll
    for (int g = 0; g < 2; g++) {
      bf16x8 kfa[8];
      const ushort_t* krow = Kb + (size_t)(kt * 64 + g * 32 + lq) * 6144 + hi * 8;
#pragma unroll
      for (int s = 0; s < 8; s++) kfa[s] = *(const bf16x8*)(krow + s * 16);
#pragma unroll
      for (int s = 0; s < 8; s++)
        sg[g] = __builtin_amdgcn_mfma_f32_32x32x16_bf16(kfa[s], qf[s], sg[g], 0, 0, 0);
    }
    if (kt * 64 + 63 > qw0) {
#pragma unroll
      for (int g = 0; g < 2; g++)
#pragma unroll
        for (int r = 0; r < 16; r++) {
          int key = kt * 64 + g * 32 + (r & 3) + 8 * (r >> 2) + 4 * hi;
          if (key > qabs) sg[g][r] = -1e30f;
        }
    }
    float pm = -1e30f;
#pragma unroll
    for (int g = 0; g < 2; g++)
#pragma unroll
      for (int r = 0; r < 16; r++) pm = fmaxf(pm, sg[g][r]);
    pm = fmaxf(pm, __shfl_xor(pm, 32));
    float mnew = fmaxf(mrow, pm);
    float corr = exp2_hw(mrow - mnew);
    mrow = mnew;
    float ps = 0.f;
#pragma unroll
    for (int g = 0; g < 2; g++)
#pragma unroll
      for (int r = 0; r < 16; r++) {
        float e = exp2_hw(sg[g][r] - mnew);
        sg[g][r] = e;
        ps += e;
      }
    ps += __shfl_xor(ps, 32);
    ssum = ssum * corr + ps;
    if (!__all(corr == 1.f)) {
#pragma unroll
      for (int d = 0; d < 4; d++)
#pragma unroll
        for (int r = 0; r < 16; r++) ot[d][r] *= corr;
    }
#pragma unroll
    for (int g = 0; g < 2; g++)
#pragma unroll
      for (int rq = 0; rq < 4; rq++) {
        bf16x4 pk;
#pragma unroll
        for (int j = 0; j < 4; j++) pk[j] = (short)f2bf(sg[g][rq * 4 + j]);
        *(bf16x4*)&Pl[w][lq][g * 32 + rq * 8 + hi * 4] = pk;
      }
    asm volatile("s_waitcnt lgkmcnt(0)" ::: "memory");
    bf16x8 pf[4];
#pragma unroll
    for (int s = 0; s < 4; s++) pf[s] = *(const bf16x8*)&Pl[w][lq][s * 16 + hi * 8];
#pragma unroll
    for (int d = 0; d < 4; d++) {
      bf16x8 vfa[4];
      const ushort_t* vrow = Vb + (size_t)(d * 32 + lq) * 2048 + kt * 64 + hi * 8;
#pragma unroll
      for (int s = 0; s < 4; s++) vfa[s] = *(const bf16x8*)(vrow + s * 16);
#pragma unroll
      for (int s = 0; s < 4; s++)
        ot[d] = __builtin_amdgcn_mfma_f32_32x32x16_bf16(vfa[s], pf[s], ot[d], 0, 0, 0);
    }
  }
  const float inv = 1.0f / ssum;
  ushort_t* orow = AO + (size_t)qabs * 4096 + h * 128;
#pragma unroll
  for (int d = 0; d < 4; d++)
#pragma unroll
    for (int rq = 0; rq < 4; rq++) {
      bf16x4 ok;
#pragma unroll
      for (int j = 0; j < 4; j++) ok[j] = (short)f2bf(ot[d][rq * 4 + j] * inv);
      *(bf16x4*)(orow + d * 32 + rq * 8 + hi * 4) = ok;
    }
}

// ---------- launch ----------
extern "C" void kernel_launch(void* const* d_in, const int* in_sizes, int n_in,
                              void* d_out, int out_size, void* d_ws, size_t ws_size,
                              hipStream_t stream) {
  (void)in_sizes; (void)n_in; (void)out_size;
  const float* x    = (const float*)d_in[0];
  const float* wq   = (const float*)d_in[1];
  const float* wk   = (const float*)d_in[2];
  const float* wv   = (const float*)d_in[3];
  const float* wo   = (const float*)d_in[4];
  const float* cosb = (const float*)d_in[5];
  const float* sinb = (const float*)d_in[6];

  char* ws = (char*)d_ws;
  const bool fast = ws_size >= (215ull << 20);

  if (fast) {
    // layout (MiB): C1[0,24) VT[24,28) woT[28,60) xb[60,76) wT[76,124)
    //               P[60,196) (xb+wT dead after gemm1)  AO[196,212) inv[212,213)
    ushort_t* C1  = (ushort_t*)(ws);
    ushort_t* VT  = (ushort_t*)(ws + ((size_t)24 << 20));
    ushort_t* woT = (ushort_t*)(ws + ((size_t)28 << 20));
    ushort_t* xb  = (ushort_t*)(ws + ((size_t)60 << 20));
    ushort_t* wT  = (ushort_t*)(ws + ((size_t)76 << 20));
    ushort_t* P   = (ushort_t*)(ws + ((size_t)60 << 20));
    ushort_t* AO  = (ushort_t*)(ws + ((size_t)196 << 20));
    float*    inv = (float*)(ws + ((size_t)212 << 20));

    cvt_x_kernel<<<4096, 256, 0, stream>>>(x, xb);
    tr_cvt_kernel<<<dim3(64, 64), 256, 0, stream>>>(wq, wT, 4096, 4096);
    tr_cvt_kernel<<<dim3(16, 64), 256, 0, stream>>>(wk, wT + (size_t)4096 * 4096, 4096, 1024);
    tr_cvt_kernel<<<dim3(16, 64), 256, 0, stream>>>(wv, wT + (size_t)5120 * 4096, 4096, 1024);
    tr_cvt_kernel<<<dim3(64, 64), 256, 0, stream>>>(wo, woT, 4096, 4096);

    // QKV projection: 256^2 8-phase GEMM, grid 8x24 = 192 (192%8==0)
    gemm256p8_kernel<ushort_t><<<192, 512, 0, stream>>>(xb, wT, C1, 2048, 6144, 4096, 6144);
    rope_kernel<<<5120, 256, 0, stream>>>(C1, cosb, sinb);
    trv_kernel<<<dim3(16, 32), 256, 0, stream>>>(C1, VT);

    gemmS_kernel<<<dim3(136, 32), 256, 0, stream>>>(C1, P);
    rowsum_kernel<<<16384, 256, 0, stream>>>(P, inv);
    gemmPV_kernel<<<dim3(32, 16), 256, 0, stream>>>(P, VT, inv, AO);

    // output projection: 128x256 3-buf p8, grid 16x16 = 256 (FULL chip, %8==0)
    gemmB_kernel<float><<<256, 512, 0, stream>>>(AO, woT, (float*)d_out, 2048, 4096, 4096, 4096);
  } else {
    // proven 92MiB layout + R7 fattn
    ushort_t* xb  = (ushort_t*)(ws);
    ushort_t* wT  = (ushort_t*)(ws + ((size_t)16 << 20));
    ushort_t* C1  = (ushort_t*)(ws + ((size_t)64 << 20));
    ushort_t* VT  = (ushort_t*)(ws + ((size_t)88 << 20));
    ushort_t* AO  = xb;
    ushort_t* woT = wT;

    cvt_x_kernel<<<4096, 256, 0, stream>>>(x, xb);
    tr_cvt_kernel<<<dim3(64, 64), 256, 0, stream>>>(wq, wT, 4096, 4096);
    tr_cvt_kernel<<<dim3(16, 64), 256, 0, stream>>>(wk, wT + (size_t)4096 * 4096, 4096, 1024);
    tr_cvt_kernel<<<dim3(16, 64), 256, 0, stream>>>(wv, wT + (size_t)5120 * 4096, 4096, 1024);
    gemm128_kernel<ushort_t><<<dim3(48, 16), 256, 0, stream>>>(xb, wT, C1, 2048, 6144, 4096, 6144);
    rope_kernel<<<5120, 256, 0, stream>>>(C1, cosb, sinb);
    trv_kernel<<<dim3(16, 32), 256, 0, stream>>>(C1, VT);
    tr_cvt_kernel<<<dim3(64, 64), 256, 0, stream>>>(wo, woT, 4096, 4096);
    fattn_kernel<<<dim3(32, 16), 256, 0, stream>>>(C1, VT, AO);
    gemm128_kernel<float><<<dim3(32, 16), 256, 0, stream>>>(AO, woT, (float*)d_out, 2048, 4096, 4096, 4096);
  }
}

// Round 13
// 389.607 us; speedup vs baseline: 1.0887x; 1.0512x over previous
//
#include <hip/hip_runtime.h>
#include <stdint.h>

typedef unsigned short ushort_t;
typedef short bf16x4 __attribute__((ext_vector_type(4)));
typedef short bf16x8 __attribute__((ext_vector_type(8)));
typedef float f32x4 __attribute__((ext_vector_type(4)));
typedef float f32x16 __attribute__((ext_vector_type(16)));
typedef float f32x4v __attribute__((ext_vector_type(4)));

// ---------- helpers ----------
__device__ __forceinline__ ushort_t f2bf(float f) {
  unsigned int u = __builtin_bit_cast(unsigned int, f);
  u += 0x7fffu + ((u >> 16) & 1u);
  return (ushort_t)(u >> 16);
}
__device__ __forceinline__ float bf2f(ushort_t h) {
  unsigned int u = ((unsigned int)h) << 16;
  return __builtin_bit_cast(float, u);
}
__device__ __forceinline__ float exp2_hw(float x) {
  return __builtin_amdgcn_exp2f(x);  // v_exp_f32: D = 2^S0
}
__device__ __forceinline__ void load_lds16(const void* g, void* l) {
  __builtin_amdgcn_global_load_lds(
      (const __attribute__((address_space(1))) void*)g,
      (__attribute__((address_space(3))) void*)l, 16, 0, 0);
}

// ---------- x fp32 -> bf16 ----------
__global__ __launch_bounds__(256) void cvt_x_kernel(const float* __restrict__ x,
                                                    ushort_t* __restrict__ xb) {
  int i = blockIdx.x * 256 + threadIdx.x;  // each thread: 8 elems
  const f32x4v* xv = (const f32x4v*)x;
  f32x4v a = xv[2 * i], b = xv[2 * i + 1];
  bf16x8 o;
  o[0] = (short)f2bf(a[0]); o[1] = (short)f2bf(a[1]);
  o[2] = (short)f2bf(a[2]); o[3] = (short)f2bf(a[3]);
  o[4] = (short)f2bf(b[0]); o[5] = (short)f2bf(b[1]);
  o[6] = (short)f2bf(b[2]); o[7] = (short)f2bf(b[3]);
  ((bf16x8*)xb)[i] = o;
}

// ---------- weight fp32 [R][C] -> bf16 transposed [C][R] ----------
__global__ __launch_bounds__(256) void tr_cvt_kernel(const float* __restrict__ src,
                                                     ushort_t* __restrict__ dst,
                                                     int R, int C) {
  __shared__ float tile[64][65];
  int r0 = blockIdx.y * 64, c0 = blockIdx.x * 64;
  int t = threadIdx.x;
#pragma unroll
  for (int i = 0; i < 16; i++) {
    int idx = t + i * 256;
    int r = idx >> 6, c = idx & 63;
    tile[r][c] = src[(size_t)(r0 + r) * C + c0 + c];
  }
  __syncthreads();
#pragma unroll
  for (int i = 0; i < 16; i++) {
    int idx = t + i * 256;
    int cr = idx >> 6, cc = idx & 63;
    dst[(size_t)(c0 + cr) * R + r0 + cc] = f2bf(tile[cc][cr]);
  }
}

// ---------- RoPE in-place on C1 (Q cols 0..4095 pre-scaled by scale*log2e) ----------
__global__ __launch_bounds__(256) void rope_kernel(ushort_t* __restrict__ C1,
                                                   const float* __restrict__ cosb,
                                                   const float* __restrict__ sinb) {
  int idx = blockIdx.x * 256 + threadIdx.x;  // 2048 * 640
  int s = idx / 640;
  int col0 = (idx % 640) * 8;
  int i0 = (col0 & 127) >> 1;
  const float qs = (col0 < 4096) ? 0.12753055296570565f : 1.0f;  // scale*log2e
  ushort_t* p = C1 + (size_t)s * 6144 + col0;
  bf16x8 v = *(const bf16x8*)p;
  bf16x8 o;
  const float* cr = cosb + s * 64 + i0;
  const float* sr = sinb + s * 64 + i0;
#pragma unroll
  for (int j = 0; j < 4; j++) {
    float tr = bf2f((ushort_t)v[2 * j]);
    float ti = bf2f((ushort_t)v[2 * j + 1]);
    float c = cr[j], sn = sr[j];
    o[2 * j] = (short)f2bf((tr * c - ti * sn) * qs);
    o[2 * j + 1] = (short)f2bf((tr * sn + ti * c) * qs);
  }
  *(bf16x8*)p = o;
}

// ---------- V part of C1 -> VT [1024][2048] (row = hk*128+d, col = s) ----------
__global__ __launch_bounds__(256) void trv_kernel(const ushort_t* __restrict__ C1,
                                                  ushort_t* __restrict__ VT) {
  __shared__ ushort_t tile[64][65];
  int c0 = blockIdx.x * 64;  // within 1024
  int r0 = blockIdx.y * 64;  // within 2048
  int t = threadIdx.x;
#pragma unroll
  for (int i = 0; i < 16; i++) {
    int idx = t + i * 256;
    int r = idx >> 6, c = idx & 63;
    tile[r][c] = C1[(size_t)(r0 + r) * 6144 + 5120 + c0 + c];
  }
  __syncthreads();
#pragma unroll
  for (int i = 0; i < 16; i++) {
    int idx = t + i * 256;
    int cr = idx >> 6, cc = idx & 63;
    VT[(size_t)(c0 + cr) * 2048 + r0 + cc] = tile[cc][cr];
  }
}

// ---------- GEMM 256x192 p8 (full-coverage variant for gemm1) ----------
// C[M][ldc] = A[M][K]*BT[N][K]^T. M%256==0, N%192==0, K%64==0, K/64>=2,
// grid 1D = (M/256)*(N/192), grid%8==0. 512 thr = 8 waves (2Mr x 4Nc),
// per-wave 128x48 out (acc[8][3]). LDS 112KB = 2 dbuf x (A 32KB + B 24KB).
// Tile staging = 7 quarters (Aq0-3: 64 rows each; Bq0-2: 64 rows each), issue
// order per tile t (staging t+1): ph0 {Aq0,Aq2} ph1 {Bq0,Bq1} ph2 {Bq2,Aq1}
// ph3 {Aq3}. Waits (derived): next-ph0 reads A-mh0 (Aq0,Aq2 = #1,#2) + all B
// (#3,#4,#5) -> boundary vmcnt(2); ph2 reads A-mh1 (Aq1,Aq3 = #6,#7) -> ph1-end
// vmcnt(4) (4 newer issues in flight). Counted, never 0 mid-loop (T4);
// vmcnt-then-barrier publishes all waves' slices. Swizzle: LDS chunk L holds
// global chunk (L&7)^(row&7); ds_read XORs back (measured 0 bank conflicts).
template <typename OutT>
__global__ __launch_bounds__(512) void gemmC_kernel(const ushort_t* __restrict__ A,
                                                    const ushort_t* __restrict__ BT,
                                                    OutT* __restrict__ C,
                                                    int M, int N, int K, int ldc) {
  __shared__ ushort_t As[2][256 * 64];  // 64KB
  __shared__ ushort_t Bs[2][192 * 64];  // 48KB
  const int nbx = N / 192;
  const int nwg = gridDim.x;
  const int id = blockIdx.x;
  const int wg = (id & 7) * (nwg >> 3) + (id >> 3);  // XCD-contiguous (nwg%8==0)
  const int brow = (wg / nbx) << 8, bcol = (wg % nbx) * 192;
  const int tid = threadIdx.x, w = tid >> 6, lane = tid & 63;
  const int wr = w >> 2, wc = w & 3;
  const int lr = lane & 15, lk = lane >> 4;

  const ushort_t* Ab = A + (size_t)brow * K;
  const ushort_t* Bb = BT + (size_t)bcol * K;

  // stage quarter q (64 rows x 64 cols), 1 load/thread
  auto stageQ = [&](const ushort_t* gbase, char* lds, int t, int q) {
    int L = q * 512 + tid;
    int r = L >> 3, sc = L & 7;
    load_lds16(gbase + (size_t)r * K + (t << 6) + ((sc ^ (r & 7)) << 3), lds + L * 16);
  };

  f32x4 acc[8][3] = {};
  const int NT = K >> 6;

  // prologue: tile 0 fully staged (7 loads), drained once
#pragma unroll
  for (int q = 0; q < 4; ++q) stageQ(Ab, (char*)&As[0][0], 0, q);
#pragma unroll
  for (int q = 0; q < 3; ++q) stageQ(Bb, (char*)&Bs[0][0], 0, q);
  asm volatile("s_waitcnt vmcnt(0)" ::: "memory");
  __builtin_amdgcn_s_barrier();

  for (int t = 0; t < NT; ++t) {
    const int c = t & 1;
    const char* Ac = (const char*)&As[c][0];
    const char* Bc = (const char*)&Bs[c][0];
    char* An = (char*)&As[c ^ 1][0];
    char* Bn = (char*)&Bs[c ^ 1][0];
    const bool pf = (t + 1 < NT);

    bf16x8 af[4][2], bfr[3][2];
    // ===== phase 0: A mh0 (8 reads) + B n0,n1 (4 reads); stage Aq0,Aq2 =====
#pragma unroll
    for (int mm = 0; mm < 4; ++mm)
#pragma unroll
      for (int ks = 0; ks < 2; ++ks) {
        int rA = wr * 128 + mm * 16 + lr;
        af[mm][ks] = *(const bf16x8*)(Ac + rA * 128 + (((ks * 4 + lk) ^ (rA & 7)) << 4));
      }
#pragma unroll
    for (int n = 0; n < 2; ++n)
#pragma unroll
      for (int ks = 0; ks < 2; ++ks) {
        int rB = wc * 48 + n * 16 + lr;
        bfr[n][ks] = *(const bf16x8*)(Bc + rB * 128 + (((ks * 4 + lk) ^ (rB & 7)) << 4));
      }
    if (pf) { stageQ(Ab, An, t + 1, 0); stageQ(Ab, An, t + 1, 2); }
    __builtin_amdgcn_s_barrier();
    asm volatile("s_waitcnt lgkmcnt(0)" ::: "memory");
    __builtin_amdgcn_sched_barrier(0);
    __builtin_amdgcn_s_setprio(1);
#pragma unroll
    for (int mm = 0; mm < 4; ++mm)
#pragma unroll
      for (int n = 0; n < 2; ++n)
#pragma unroll
        for (int ks = 0; ks < 2; ++ks)
          acc[mm][n] = __builtin_amdgcn_mfma_f32_16x16x32_bf16(af[mm][ks], bfr[n][ks],
                                                               acc[mm][n], 0, 0, 0);
    __builtin_amdgcn_s_setprio(0);
    __builtin_amdgcn_s_barrier();

    // ===== phase 1: B n2 (2 reads); stage Bq0,Bq1; vmcnt(4) =====
#pragma unroll
    for (int ks = 0; ks < 2; ++ks) {
      int rB = wc * 48 + 32 + lr;
      bfr[2][ks] = *(const bf16x8*)(Bc + rB * 128 + (((ks * 4 + lk) ^ (rB & 7)) << 4));
    }
    if (pf) { stageQ(Bb, Bn, t + 1, 0); stageQ(Bb, Bn, t + 1, 1); }
    __builtin_amdgcn_s_barrier();
    asm volatile("s_waitcnt lgkmcnt(0)" ::: "memory");
    __builtin_amdgcn_sched_barrier(0);
    __builtin_amdgcn_s_setprio(1);
#pragma unroll
    for (int mm = 0; mm < 4; ++mm)
#pragma unroll
      for (int ks = 0; ks < 2; ++ks)
        acc[mm][2] = __builtin_amdgcn_mfma_f32_16x16x32_bf16(af[mm][ks], bfr[2][ks],
                                                             acc[mm][2], 0, 0, 0);
    __builtin_amdgcn_s_setprio(0);
    asm volatile("s_waitcnt vmcnt(4)" ::: "memory");  // Aq1,Aq3 of tile t landed
    __builtin_amdgcn_s_barrier();

    // ===== phase 2: A mh1 (8 reads); stage Bq2,Aq1 =====
#pragma unroll
    for (int mm = 0; mm < 4; ++mm)
#pragma unroll
      for (int ks = 0; ks < 2; ++ks) {
        int rA = wr * 128 + 64 + mm * 16 + lr;
        af[mm][ks] = *(const bf16x8*)(Ac + rA * 128 + (((ks * 4 + lk) ^ (rA & 7)) << 4));
      }
    if (pf) { stageQ(Bb, Bn, t + 1, 2); stageQ(Ab, An, t + 1, 1); }
    __builtin_amdgcn_s_barrier();
    asm volatile("s_waitcnt lgkmcnt(0)" ::: "memory");
    __builtin_amdgcn_sched_barrier(0);
    __builtin_amdgcn_s_setprio(1);
#pragma unroll
    for (int mm = 0; mm < 4; ++mm)
#pragma unroll
      for (int n = 0; n < 2; ++n)
#pragma unroll
        for (int ks = 0; ks < 2; ++ks)
          acc[4 + mm][n] = __builtin_amdgcn_mfma_f32_16x16x32_bf16(af[mm][ks], bfr[n][ks],
                                                                   acc[4 + mm][n], 0, 0, 0);
    __builtin_amdgcn_s_setprio(0);
    __builtin_amdgcn_s_barrier();

    // ===== phase 3: no reads; stage Aq3; MFMA; boundary vmcnt(2) =====
    if (pf) stageQ(Ab, An, t + 1, 3);
    __builtin_amdgcn_s_setprio(1);
#pragma unroll
    for (int mm = 0; mm < 4; ++mm)
#pragma unroll
      for (int ks = 0; ks < 2; ++ks)
        acc[4 + mm][2] = __builtin_amdgcn_mfma_f32_16x16x32_bf16(af[mm][ks], bfr[2][ks],
                                                                 acc[4 + mm][2], 0, 0, 0);
    __builtin_amdgcn_s_setprio(0);
    asm volatile("s_waitcnt vmcnt(2)" ::: "memory");  // all but Aq1,Aq3(t+1) landed
    __builtin_amdgcn_s_barrier();
  }
  // epilogue
#pragma unroll
  for (int m = 0; m < 8; ++m)
#pragma unroll
    for (int n = 0; n < 3; ++n) {
      int row = brow + wr * 128 + m * 16 + lk * 4;
      int col = bcol + wc * 48 + n * 16 + lr;
#pragma unroll
      for (int j = 0; j < 4; ++j) {
        float v = acc[m][n][j];
        if constexpr (sizeof(OutT) == 2)
          C[(size_t)(row + j) * ldc + col] = (OutT)f2bf(v);
        else
          C[(size_t)(row + j) * ldc + col] = v;
      }
    }
}

// ---------- GEMM 128x256, 3-buffer 4-phase p8 (full-grid variant for gemm2) ----------
template <typename OutT>
__global__ __launch_bounds__(512) void gemmB_kernel(const ushort_t* __restrict__ A,
                                                    const ushort_t* __restrict__ BT,
                                                    OutT* __restrict__ C,
                                                    int M, int N, int K, int ldc) {
  __shared__ ushort_t As[3][128 * 64];  // 48KB
  __shared__ ushort_t Bs[3][256 * 64];  // 96KB
  const int nbx = N >> 8;
  const int nwg = gridDim.x;
  const int id = blockIdx.x;
  const int wg = (id & 7) * (nwg >> 3) + (id >> 3);  // XCD-contiguous (nwg%8==0)
  const int brow = (wg / nbx) << 7, bcol = (wg % nbx) << 8;
  const int tid = threadIdx.x, w = tid >> 6, lane = tid & 63;
  const int wr = w >> 2, wc = w & 3;
  const int lr = lane & 15, lk = lane >> 4;

  const ushort_t* Ab = A + (size_t)brow * K;
  const ushort_t* Bb = BT + (size_t)bcol * K;

  auto stageQ = [&](const ushort_t* gbase, char* lds, int t, int q) {
    int L = q * 512 + tid;
    int r = L >> 3, sc = L & 7;
    load_lds16(gbase + (size_t)r * K + (t << 6) + ((sc ^ (r & 7)) << 3), lds + L * 16);
  };
  auto stageTile = [&](int t, int buf) {
    stageQ(Ab, (char*)&As[buf][0], t, 0);
    stageQ(Ab, (char*)&As[buf][0], t, 1);
#pragma unroll
    for (int q = 0; q < 4; ++q) stageQ(Bb, (char*)&Bs[buf][0], t, q);
  };

  f32x4 acc[4][4] = {};
  const int NT = K >> 6;

  stageTile(0, 0);
  stageTile(1, 1);
  asm volatile("s_waitcnt vmcnt(6)" ::: "memory");
  __builtin_amdgcn_s_barrier();

  int cur = 0;
  for (int t = 0; t < NT; ++t) {
    const char* Ac = (const char*)&As[cur][0];
    const char* Bc = (const char*)&Bs[cur][0];
    const int nxt = (cur + 2 >= 3) ? cur - 1 : cur + 2;  // (t+2)%3
    char* An = (char*)&As[nxt][0];
    char* Bn = (char*)&Bs[nxt][0];
    const bool pf = (t + 2 < NT);

    bf16x8 af[4][2], bfr[4][2];
    // ===== phase 0: A m0,m1 (4) + B n0,n1 (4); stage Aq0(t+2) =====
#pragma unroll
    for (int mm = 0; mm < 2; ++mm)
#pragma unroll
      for (int ks = 0; ks < 2; ++ks) {
        int rA = wr * 64 + mm * 16 + lr;
        af[mm][ks] = *(const bf16x8*)(Ac + rA * 128 + (((ks * 4 + lk) ^ (rA & 7)) << 4));
      }
#pragma unroll
    for (int n = 0; n < 2; ++n)
#pragma unroll
      for (int ks = 0; ks < 2; ++ks) {
        int rB = wc * 64 + n * 16 + lr;
        bfr[n][ks] = *(const bf16x8*)(Bc + rB * 128 + (((ks * 4 + lk) ^ (rB & 7)) << 4));
      }
    if (pf) stageQ(Ab, An, t + 2, 0);
    __builtin_amdgcn_s_barrier();
    asm volatile("s_waitcnt lgkmcnt(0)" ::: "memory");
    __builtin_amdgcn_sched_barrier(0);
    __builtin_amdgcn_s_setprio(1);
#pragma unroll
    for (int mm = 0; mm < 2; ++mm)
#pragma unroll
      for (int n = 0; n < 2; ++n)
#pragma unroll
        for (int ks = 0; ks < 2; ++ks)
          acc[mm][n] = __builtin_amdgcn_mfma_f32_16x16x32_bf16(af[mm][ks], bfr[n][ks],
                                                               acc[mm][n], 0, 0, 0);
    __builtin_amdgcn_s_setprio(0);
    __builtin_amdgcn_s_barrier();

    // ===== phase 1: B n2,n3 (4); stage Aq1(t+2) =====
#pragma unroll
    for (int n = 2; n < 4; ++n)
#pragma unroll
      for (int ks = 0; ks < 2; ++ks) {
        int rB = wc * 64 + n * 16 + lr;
        bfr[n][ks] = *(const bf16x8*)(Bc + rB * 128 + (((ks * 4 + lk) ^ (rB & 7)) << 4));
      }
    if (pf) stageQ(Ab, An, t + 2, 1);
    __builtin_amdgcn_s_barrier();
    asm volatile("s_waitcnt lgkmcnt(0)" ::: "memory");
    __builtin_amdgcn_sched_barrier(0);
    __builtin_amdgcn_s_setprio(1);
#pragma unroll
    for (int mm = 0; mm < 2; ++mm)
#pragma unroll
      for (int n = 2; n < 4; ++n)
#pragma unroll
        for (int ks = 0; ks < 2; ++ks)
          acc[mm][n] = __builtin_amdgcn_mfma_f32_16x16x32_bf16(af[mm][ks], bfr[n][ks],
                                                               acc[mm][n], 0, 0, 0);
    __builtin_amdgcn_s_setprio(0);
    __builtin_amdgcn_s_barrier();

    // ===== phase 2: A m2,m3 (4); stage Bq0,Bq1(t+2) =====
#pragma unroll
    for (int mm = 0; mm < 2; ++mm)
#pragma unroll
      for (int ks = 0; ks < 2; ++ks) {
        int rA = wr * 64 + (mm + 2) * 16 + lr;
        af[2 + mm][ks] = *(const bf16x8*)(Ac + rA * 128 + (((ks * 4 + lk) ^ (rA & 7)) << 4));
      }
    if (pf) { stageQ(Bb, Bn, t + 2, 0); stageQ(Bb, Bn, t + 2, 1); }
    __builtin_amdgcn_s_barrier();
    asm volatile("s_waitcnt lgkmcnt(0)" ::: "memory");
    __builtin_amdgcn_sched_barrier(0);
    __builtin_amdgcn_s_setprio(1);
#pragma unroll
    for (int mm = 0; mm < 2; ++mm)
#pragma unroll
      for (int n = 0; n < 2; ++n)
#pragma unroll
        for (int ks = 0; ks < 2; ++ks)
          acc[2 + mm][n] = __builtin_amdgcn_mfma_f32_16x16x32_bf16(af[2 + mm][ks], bfr[n][ks],
                                                                   acc[2 + mm][n], 0, 0, 0);
    __builtin_amdgcn_s_setprio(0);
    __builtin_amdgcn_s_barrier();

    // ===== phase 3: no reads; stage Bq2,Bq3(t+2); MFMA; counted boundary =====
    if (pf) { stageQ(Bb, Bn, t + 2, 2); stageQ(Bb, Bn, t + 2, 3); }
    __builtin_amdgcn_s_setprio(1);
#pragma unroll
    for (int mm = 0; mm < 2; ++mm)
#pragma unroll
      for (int n = 2; n < 4; ++n)
#pragma unroll
        for (int ks = 0; ks < 2; ++ks)
          acc[2 + mm][n] = __builtin_amdgcn_mfma_f32_16x16x32_bf16(af[2 + mm][ks], bfr[n][ks],
                                                                   acc[2 + mm][n], 0, 0, 0);
    __builtin_amdgcn_s_setprio(0);
    if (pf)
      asm volatile("s_waitcnt vmcnt(6)" ::: "memory");  // t+1 landed; t+2 in flight
    else if (t + 1 < NT)
      asm volatile("s_waitcnt vmcnt(0)" ::: "memory");  // tail drain
    __builtin_amdgcn_s_barrier();
    cur = (cur == 2) ? 0 : cur + 1;
  }
#pragma unroll
  for (int m = 0; m < 4; ++m)
#pragma unroll
    for (int n = 0; n < 4; ++n) {
      int row = brow + wr * 64 + m * 16 + lk * 4;
      int col = bcol + wc * 64 + n * 16 + lr;
#pragma unroll
      for (int j = 0; j < 4; ++j) {
        float v = acc[m][n][j];
        if constexpr (sizeof(OutT) == 2)
          C[(size_t)(row + j) * ldc + col] = (OutT)f2bf(v);
        else
          C[(size_t)(row + j) * ldc + col] = v;
      }
    }
}

// ---------- GEMM: C[M][ldc] = A[M][K] * BT[N][K]^T  (m97 structure, fallback) ----------
template <typename OutT>
__global__ __launch_bounds__(256) void gemm128_kernel(const ushort_t* __restrict__ A,
                                                      const ushort_t* __restrict__ BT,
                                                      OutT* __restrict__ C,
                                                      int M, int N, int K, int ldc) {
  __shared__ ushort_t As[128 * 32];
  __shared__ ushort_t Bs[128 * 32];
  int brow = blockIdx.y * 128, bcol = blockIdx.x * 128;
  int tid = threadIdx.x, w = tid >> 6, lane = tid & 63;
  int wr = w >> 1, wc = w & 1;
  int lr = lane & 15, lk = lane >> 4;
  f32x4 acc[4][4] = {};

  int srow = lane >> 2;
  int scol = (lane & 3) * 8;
  const ushort_t* Ab = A + (size_t)brow * K + scol;
  const ushort_t* Bb = BT + (size_t)bcol * K + scol;

  for (int kt = 0; kt < K; kt += 32) {
#pragma unroll
    for (int i = 0; i < 2; i++) {
      int seg = w * 2 + i;
      int row = seg * 16 + srow;
      load_lds16(Ab + (size_t)row * K + kt, (char*)As + seg * 1024);
      load_lds16(Bb + (size_t)row * K + kt, (char*)Bs + seg * 1024);
    }
    __syncthreads();
    bf16x8 af[4], bfr[4];
#pragma unroll
    for (int m = 0; m < 4; m++)
      af[m] = *(const bf16x8*)&As[(wr * 64 + m * 16 + lr) * 32 + lk * 8];
#pragma unroll
    for (int n = 0; n < 4; n++)
      bfr[n] = *(const bf16x8*)&Bs[(wc * 64 + n * 16 + lr) * 32 + lk * 8];
#pragma unroll
    for (int m = 0; m < 4; m++)
#pragma unroll
      for (int n = 0; n < 4; n++)
        acc[m][n] = __builtin_amdgcn_mfma_f32_16x16x32_bf16(af[m], bfr[n], acc[m][n], 0, 0, 0);
    __syncthreads();
  }
#pragma unroll
  for (int m = 0; m < 4; m++)
#pragma unroll
    for (int n = 0; n < 4; n++) {
      int row = brow + wr * 64 + m * 16 + lk * 4;
      int col = bcol + wc * 64 + n * 16 + lr;
#pragma unroll
      for (int j = 0; j < 4; j++) {
        float v = acc[m][n][j];
        if constexpr (sizeof(OutT) == 2)
          C[(size_t)(row + j) * ldc + col] = (OutT)f2bf(v);
        else
          C[(size_t)(row + j) * ldc + col] = v;
      }
    }
}

// ---------- gemmS: P[tile] = exp2(Q K^T) causal, materialized bf16 ----------
__global__ __launch_bounds__(256) void gemmS_kernel(const ushort_t* __restrict__ C1,
                                                    ushort_t* __restrict__ P) {
  int rem = blockIdx.x, rt = 0;
  while (rem > rt) { rem -= (rt + 1); rt++; }
  const int ct = rem;
  const int h = blockIdx.y, hk = h >> 2;

  __shared__ ushort_t As[128 * 32];
  __shared__ ushort_t Bs[128 * 32];
  int tid = threadIdx.x, w = tid >> 6, lane = tid & 63;
  int wr = w >> 1, wc = w & 1;
  int lr = lane & 15, lk = lane >> 4;
  f32x4 acc[4][4] = {};
  int srow = lane >> 2;
  int scol = (lane & 3) * 8;
  const ushort_t* Ab = C1 + (size_t)(rt * 128) * 6144 + h * 128 + scol;         // Q
  const ushort_t* Bb = C1 + (size_t)(ct * 128) * 6144 + 4096 + hk * 128 + scol; // K

  for (int kt = 0; kt < 128; kt += 32) {
#pragma unroll
    for (int i = 0; i < 2; i++) {
      int seg = w * 2 + i;
      int row = seg * 16 + srow;
      load_lds16(Ab + (size_t)row * 6144 + kt, (char*)As + seg * 1024);
      load_lds16(Bb + (size_t)row * 6144 + kt, (char*)Bs + seg * 1024);
    }
    __syncthreads();
    bf16x8 af[4], bfr[4];
#pragma unroll
    for (int m = 0; m < 4; m++)
      af[m] = *(const bf16x8*)&As[(wr * 64 + m * 16 + lr) * 32 + lk * 8];
#pragma unroll
    for (int n = 0; n < 4; n++)
      bfr[n] = *(const bf16x8*)&Bs[(wc * 64 + n * 16 + lr) * 32 + lk * 8];
#pragma unroll
    for (int m = 0; m < 4; m++)
#pragma unroll
      for (int n = 0; n < 4; n++)
        acc[m][n] = __builtin_amdgcn_mfma_f32_16x16x32_bf16(af[m], bfr[n], acc[m][n], 0, 0, 0);
    __syncthreads();
  }
  ushort_t* Pt = P + ((size_t)h * 136 + (size_t)(rt * (rt + 1) / 2) + ct) * 16384;
  const bool diag = (rt == ct);
#pragma unroll
  for (int m = 0; m < 4; m++)
#pragma unroll
    for (int n = 0; n < 4; n++) {
      int row = wr * 64 + m * 16 + lk * 4;
      int col = wc * 64 + n * 16 + lr;
#pragma unroll
      for (int j = 0; j < 4; j++) {
        float v = exp2_hw(acc[m][n][j]);
        if (diag && col > row + j) v = 0.f;
        Pt[(row + j) * 128 + col] = f2bf(v);
      }
    }
}

// ---------- gemmPV: AO[rt-tile] = (P * V) / rowsum(P) ----------
// Row sums fused via an all-ones MFMA: sacc[m] = mfma(af[m], ones, sacc[m])
// gives D[r][c] = sum_k P[r][k] for every c; the C/D layout hands lane
// (lr,lk) exactly the sum for row lk*4+j — the row it writes. No shuffles.
__global__ __launch_bounds__(256) void gemmPV_kernel(const ushort_t* __restrict__ P,
                                                     const ushort_t* __restrict__ VT,
                                                     ushort_t* __restrict__ AO) {
  const int h = blockIdx.x, hk = h >> 2;
  const int rt = 15 - (int)blockIdx.y;

  __shared__ ushort_t As[128 * 32];
  __shared__ ushort_t Bs[128 * 32];
  int tid = threadIdx.x, w = tid >> 6, lane = tid & 63;
  int wr = w >> 1, wc = w & 1;
  int lr = lane & 15, lk = lane >> 4;
  f32x4 acc[4][4] = {};
  f32x4 sacc[4] = {};
  bf16x8 ones;
#pragma unroll
  for (int j = 0; j < 8; j++) ones[j] = (short)0x3F80;  // bf16 1.0
  int srow = lane >> 2;
  int scol = (lane & 3) * 8;
  const ushort_t* Ph = P + ((size_t)h * 136 + (size_t)(rt * (rt + 1) / 2)) * 16384;
  const ushort_t* Vh = VT + (size_t)hk * 128 * 2048;

  const int nks = (rt + 1) * 4;
  for (int ks = 0; ks < nks; ks++) {
    int k0 = ks * 32;
    int ctk = k0 >> 7, kin = k0 & 127;
#pragma unroll
    for (int i = 0; i < 2; i++) {
      int seg = w * 2 + i;
      int row = seg * 16 + srow;
      load_lds16(Ph + (size_t)ctk * 16384 + (size_t)row * 128 + kin + scol,
                 (char*)As + seg * 1024);
      load_lds16(Vh + (size_t)row * 2048 + k0 + scol, (char*)Bs + seg * 1024);
    }
    __syncthreads();
    bf16x8 af[4], bfr[4];
#pragma unroll
    for (int m = 0; m < 4; m++)
      af[m] = *(const bf16x8*)&As[(wr * 64 + m * 16 + lr) * 32 + lk * 8];
#pragma unroll
    for (int n = 0; n < 4; n++)
      bfr[n] = *(const bf16x8*)&Bs[(wc * 64 + n * 16 + lr) * 32 + lk * 8];
#pragma unroll
    for (int m = 0; m < 4; m++) {
#pragma unroll
      for (int n = 0; n < 4; n++)
        acc[m][n] = __builtin_amdgcn_mfma_f32_16x16x32_bf16(af[m], bfr[n], acc[m][n], 0, 0, 0);
      sacc[m] = __builtin_amdgcn_mfma_f32_16x16x32_bf16(af[m], ones, sacc[m], 0, 0, 0);
    }
    __syncthreads();
  }
  const int q0 = rt * 128;
#pragma unroll
  for (int m = 0; m < 4; m++) {
    float invs[4];
#pragma unroll
    for (int j = 0; j < 4; j++) invs[j] = 1.0f / sacc[m][j];
#pragma unroll
    for (int n = 0; n < 4; n++) {
      int row = wr * 64 + m * 16 + lk * 4;
      int col = wc * 64 + n * 16 + lr;
#pragma unroll
      for (int j = 0; j < 4; j++) {
        float v = acc[m][n][j] * invs[j];
        AO[(size_t)(q0 + row + j) * 4096 + h * 128 + col] = f2bf(v);
      }
    }
  }
}

// ---------- flash attention (fallback when workspace too small) ----------
__global__ __launch_bounds__(256) void fattn_kernel(const ushort_t* __restrict__ C1,
                                                    const ushort_t* __restrict__ VT,
                                                    ushort_t* __restrict__ AO) {
  __shared__ ushort_t Pl[4][32][72];
  const int h = blockIdx.x, hk = h >> 2;
  const int qt = gridDim.y - 1 - blockIdx.y;
  const int tid = threadIdx.x, w = tid >> 6, lane = tid & 63;
  const int lq = lane & 31, hi = lane >> 5;
  const int qw0 = qt * 128 + w * 32;
  const int qabs = qw0 + lq;

  const ushort_t* Kb = C1 + 4096 + (size_t)hk * 128;
  const ushort_t* Vb = VT + (size_t)hk * 128 * 2048;

  bf16x8 qf[8];
  {
    const ushort_t* qrow = C1 + (size_t)qabs * 6144 + h * 128;
#pragma unroll
    for (int s = 0; s < 8; s++) qf[s] = *(const bf16x8*)(qrow + s * 16 + hi * 8);
  }
  f32x16 ot[4] = {};
  float mrow = -1e30f, ssum = 0.f;

  const int ktmax = (qw0 + 31) >> 6;
  for (int kt = 0; kt <= ktmax; kt++) {
    f32x16 sg[2] = {};
#pragma unroll
    for (int g = 0; g < 2; g++) {
      bf16x8 kfa[8];
      const ushort_t* krow = Kb + (size_t)(kt * 64 + g * 32 + lq) * 6144 + hi * 8;
#pragma unroll
      for (int s = 0; s < 8; s++) kfa[s] = *(const bf16x8*)(krow + s * 16);
#pragma unroll
      for (int s = 0; s < 8; s++)
        sg[g] = __builtin_amdgcn_mfma_f32_32x32x16_bf16(kfa[s], qf[s], sg[g], 0, 0, 0);
    }
    if (kt * 64 + 63 > qw0) {
#pragma unroll
      for (int g = 0; g < 2; g++)
#pragma unroll
        for (int r = 0; r < 16; r++) {
          int key = kt * 64 + g * 32 + (r & 3) + 8 * (r >> 2) + 4 * hi;
          if (key > qabs) sg[g][r] = -1e30f;
        }
    }
    float pm = -1e30f;
#pragma unroll
    for (int g = 0; g < 2; g++)
#pragma unroll
      for (int r = 0; r < 16; r++) pm = fmaxf(pm, sg[g][r]);
    pm = fmaxf(pm, __shfl_xor(pm, 32));
    float mnew = fmaxf(mrow, pm);
    float corr = exp2_hw(mrow - mnew);
    mrow = mnew;
    float ps = 0.f;
#pragma unroll
    for (int g = 0; g < 2; g++)
#pragma unroll
      for (int r = 0; r < 16; r++) {
        float e = exp2_hw(sg[g][r] - mnew);
        sg[g][r] = e;
        ps += e;
      }
    ps += __shfl_xor(ps, 32);
    ssum = ssum * corr + ps;
    if (!__all(corr == 1.f)) {
#pragma unroll
      for (int d = 0; d < 4; d++)
#pragma unroll
        for (int r = 0; r < 16; r++) ot[d][r] *= corr;
    }
#pragma unroll
    for (int g = 0; g < 2; g++)
#pragma unroll
      for (int rq = 0; rq < 4; rq++) {
        bf16x4 pk;
#pragma unroll
        for (int j = 0; j < 4; j++) pk[j] = (short)f2bf(sg[g][rq * 4 + j]);
        *(bf16x4*)&Pl[w][lq][g * 32 + rq * 8 + hi * 4] = pk;
      }
    asm volatile("s_waitcnt lgkmcnt(0)" ::: "memory");
    bf16x8 pf[4];
#pragma unroll
    for (int s = 0; s < 4; s++) pf[s] = *(const bf16x8*)&Pl[w][lq][s * 16 + hi * 8];
#pragma unroll
    for (int d = 0; d < 4; d++) {
      bf16x8 vfa[4];
      const ushort_t* vrow = Vb + (size_t)(d * 32 + lq) * 2048 + kt * 64 + hi * 8;
#pragma unroll
      for (int s = 0; s < 4; s++) vfa[s] = *(const bf16x8*)(vrow + s * 16);
#pragma unroll
      for (int s = 0; s < 4; s++)
        ot[d] = __builtin_amdgcn_mfma_f32_32x32x16_bf16(vfa[s], pf[s], ot[d], 0, 0, 0);
    }
  }
  const float inv = 1.0f / ssum;
  ushort_t* orow = AO + (size_t)qabs * 4096 + h * 128;
#pragma unroll
  for (int d = 0; d < 4; d++)
#pragma unroll
    for (int rq = 0; rq < 4; rq++) {
      bf16x4 ok;
#pragma unroll
      for (int j = 0; j < 4; j++) ok[j] = (short)f2bf(ot[d][rq * 4 + j] * inv);
      *(bf16x4*)(orow + d * 32 + rq * 8 + hi * 4) = ok;
    }
}

// ---------- launch ----------
extern "C" void kernel_launch(void* const* d_in, const int* in_sizes, int n_in,
                              void* d_out, int out_size, void* d_ws, size_t ws_size,
                              hipStream_t stream) {
  (void)in_sizes; (void)n_in; (void)out_size;
  const float* x    = (const float*)d_in[0];
  const float* wq   = (const float*)d_in[1];
  const float* wk   = (const float*)d_in[2];
  const float* wv   = (const float*)d_in[3];
  const float* wo   = (const float*)d_in[4];
  const float* cosb = (const float*)d_in[5];
  const float* sinb = (const float*)d_in[6];

  char* ws = (char*)d_ws;
  const bool fast = ws_size >= (215ull << 20);

  if (fast) {
    // layout (MiB): C1[0,24) VT[24,28) woT[28,60) xb[60,76) wT[76,124)
    //               P[60,196) (xb+wT dead after gemm1)  AO[196,212)
    ushort_t* C1  = (ushort_t*)(ws);
    ushort_t* VT  = (ushort_t*)(ws + ((size_t)24 << 20));
    ushort_t* woT = (ushort_t*)(ws + ((size_t)28 << 20));
    ushort_t* xb  = (ushort_t*)(ws + ((size_t)60 << 20));
    ushort_t* wT  = (ushort_t*)(ws + ((size_t)76 << 20));
    ushort_t* P   = (ushort_t*)(ws + ((size_t)60 << 20));
    ushort_t* AO  = (ushort_t*)(ws + ((size_t)196 << 20));

    cvt_x_kernel<<<4096, 256, 0, stream>>>(x, xb);
    tr_cvt_kernel<<<dim3(64, 64), 256, 0, stream>>>(wq, wT, 4096, 4096);
    tr_cvt_kernel<<<dim3(16, 64), 256, 0, stream>>>(wk, wT + (size_t)4096 * 4096, 4096, 1024);
    tr_cvt_kernel<<<dim3(16, 64), 256, 0, stream>>>(wv, wT + (size_t)5120 * 4096, 4096, 1024);
    tr_cvt_kernel<<<dim3(64, 64), 256, 0, stream>>>(wo, woT, 4096, 4096);

    // QKV projection: 256x192 p8 GEMM, grid 8x32 = 256 (FULL chip, %8==0)
    gemmC_kernel<ushort_t><<<256, 512, 0, stream>>>(xb, wT, C1, 2048, 6144, 4096, 6144);
    rope_kernel<<<5120, 256, 0, stream>>>(C1, cosb, sinb);
    trv_kernel<<<dim3(16, 32), 256, 0, stream>>>(C1, VT);

    gemmS_kernel<<<dim3(136, 32), 256, 0, stream>>>(C1, P);
    gemmPV_kernel<<<dim3(32, 16), 256, 0, stream>>>(P, VT, AO);  // rowsum fused

    // output projection: 128x256 3-buf p8, grid 16x16 = 256 (FULL chip, %8==0)
    gemmB_kernel<float><<<256, 512, 0, stream>>>(AO, woT, (float*)d_out, 2048, 4096, 4096, 4096);
  } else {
    // proven 92MiB layout + R7 fattn
    ushort_t* xb  = (ushort_t*)(ws);
    ushort_t* wT  = (ushort_t*)(ws + ((size_t)16 << 20));
    ushort_t* C1  = (ushort_t*)(ws + ((size_t)64 << 20));
    ushort_t* VT  = (ushort_t*)(ws + ((size_t)88 << 20));
    ushort_t* AO  = xb;
    ushort_t* woT = wT;

    cvt_x_kernel<<<4096, 256, 0, stream>>>(x, xb);
    tr_cvt_kernel<<<dim3(64, 64), 256, 0, stream>>>(wq, wT, 4096, 4096);
    tr_cvt_kernel<<<dim3(16, 64), 256, 0, stream>>>(wk, wT + (size_t)4096 * 4096, 4096, 1024);
    tr_cvt_kernel<<<dim3(16, 64), 256, 0, stream>>>(wv, wT + (size_t)5120 * 4096, 4096, 1024);
    gemm128_kernel<ushort_t><<<dim3(48, 16), 256, 0, stream>>>(xb, wT, C1, 2048, 6144, 4096, 6144);
    rope_kernel<<<5120, 256, 0, stream>>>(C1, cosb, sinb);
    trv_kernel<<<dim3(16, 32), 256, 0, stream>>>(C1, VT);
    tr_cvt_kernel<<<dim3(64, 64), 256, 0, stream>>>(wo, woT, 4096, 4096);
    fattn_kernel<<<dim3(32, 16), 256, 0, stream>>>(C1, VT, AO);
    gemm128_kernel<float><<<dim3(32, 16), 256, 0, stream>>>(AO, woT, (float*)d_out, 2048, 4096, 4096, 4096);
  }
}

// Round 14
// 377.742 us; speedup vs baseline: 1.1229x; 1.0314x over previous
//
#include <hip/hip_runtime.h>
#include <stdint.h>

typedef unsigned short ushort_t;
typedef short bf16x4 __attribute__((ext_vector_type(4)));
typedef short bf16x8 __attribute__((ext_vector_type(8)));
typedef float f32x4 __attribute__((ext_vector_type(4)));
typedef float f32x16 __attribute__((ext_vector_type(16)));
typedef float f32x4v __attribute__((ext_vector_type(4)));

// ---------- helpers ----------
__device__ __forceinline__ ushort_t f2bf(float f) {
  unsigned int u = __builtin_bit_cast(unsigned int, f);
  u += 0x7fffu + ((u >> 16) & 1u);
  return (ushort_t)(u >> 16);
}
__device__ __forceinline__ float bf2f(ushort_t h) {
  unsigned int u = ((unsigned int)h) << 16;
  return __builtin_bit_cast(float, u);
}
__device__ __forceinline__ float exp2_hw(float x) {
  return __builtin_amdgcn_exp2f(x);  // v_exp_f32: D = 2^S0
}
__device__ __forceinline__ void load_lds16(const void* g, void* l) {
  __builtin_amdgcn_global_load_lds(
      (const __attribute__((address_space(1))) void*)g,
      (__attribute__((address_space(3))) void*)l, 16, 0, 0);
}

// ---------- x fp32 -> bf16 ----------
__global__ __launch_bounds__(256) void cvt_x_kernel(const float* __restrict__ x,
                                                    ushort_t* __restrict__ xb) {
  int i = blockIdx.x * 256 + threadIdx.x;  // each thread: 8 elems
  const f32x4v* xv = (const f32x4v*)x;
  f32x4v a = xv[2 * i], b = xv[2 * i + 1];
  bf16x8 o;
  o[0] = (short)f2bf(a[0]); o[1] = (short)f2bf(a[1]);
  o[2] = (short)f2bf(a[2]); o[3] = (short)f2bf(a[3]);
  o[4] = (short)f2bf(b[0]); o[5] = (short)f2bf(b[1]);
  o[6] = (short)f2bf(b[2]); o[7] = (short)f2bf(b[3]);
  ((bf16x8*)xb)[i] = o;
}

// ---------- weight fp32 [R][C] -> bf16 transposed [C][R] ----------
__global__ __launch_bounds__(256) void tr_cvt_kernel(const float* __restrict__ src,
                                                     ushort_t* __restrict__ dst,
                                                     int R, int C) {
  __shared__ float tile[64][65];
  int r0 = blockIdx.y * 64, c0 = blockIdx.x * 64;
  int t = threadIdx.x;
#pragma unroll
  for (int i = 0; i < 16; i++) {
    int idx = t + i * 256;
    int r = idx >> 6, c = idx & 63;
    tile[r][c] = src[(size_t)(r0 + r) * C + c0 + c];
  }
  __syncthreads();
#pragma unroll
  for (int i = 0; i < 16; i++) {
    int idx = t + i * 256;
    int cr = idx >> 6, cc = idx & 63;
    dst[(size_t)(c0 + cr) * R + r0 + cc] = f2bf(tile[cc][cr]);
  }
}

// ---------- RoPE in-place on C1 (Q cols 0..4095 pre-scaled by scale*log2e) ----------
__global__ __launch_bounds__(256) void rope_kernel(ushort_t* __restrict__ C1,
                                                   const float* __restrict__ cosb,
                                                   const float* __restrict__ sinb) {
  int idx = blockIdx.x * 256 + threadIdx.x;  // 2048 * 640
  int s = idx / 640;
  int col0 = (idx % 640) * 8;
  int i0 = (col0 & 127) >> 1;
  const float qs = (col0 < 4096) ? 0.12753055296570565f : 1.0f;  // scale*log2e
  ushort_t* p = C1 + (size_t)s * 6144 + col0;
  bf16x8 v = *(const bf16x8*)p;
  bf16x8 o;
  const float* cr = cosb + s * 64 + i0;
  const float* sr = sinb + s * 64 + i0;
#pragma unroll
  for (int j = 0; j < 4; j++) {
    float tr = bf2f((ushort_t)v[2 * j]);
    float ti = bf2f((ushort_t)v[2 * j + 1]);
    float c = cr[j], sn = sr[j];
    o[2 * j] = (short)f2bf((tr * c - ti * sn) * qs);
    o[2 * j + 1] = (short)f2bf((tr * sn + ti * c) * qs);
  }
  *(bf16x8*)p = o;
}

// ---------- V part of C1 -> VT [1024][2048] (row = hk*128+d, col = s) ----------
__global__ __launch_bounds__(256) void trv_kernel(const ushort_t* __restrict__ C1,
                                                  ushort_t* __restrict__ VT) {
  __shared__ ushort_t tile[64][65];
  int c0 = blockIdx.x * 64;  // within 1024
  int r0 = blockIdx.y * 64;  // within 2048
  int t = threadIdx.x;
#pragma unroll
  for (int i = 0; i < 16; i++) {
    int idx = t + i * 256;
    int r = idx >> 6, c = idx & 63;
    tile[r][c] = C1[(size_t)(r0 + r) * 6144 + 5120 + c0 + c];
  }
  __syncthreads();
#pragma unroll
  for (int i = 0; i < 16; i++) {
    int idx = t + i * 256;
    int cr = idx >> 6, cc = idx & 63;
    VT[(size_t)(c0 + cr) * 2048 + r0 + cc] = tile[cc][cr];
  }
}

// ---------- 2D-chunked XCD block mapping ----------
// Each XCD (id&7) owns a (nby/2)x(nbx/4) rectangle of the block grid, so the
// per-K-step active A/B slices (~128-192KB) are L2-resident per XCD and each
// 64-col slice is fetched from L3 once, reused 4-8x from L2. Bijective for
// nby%2==0, nbx%4==0, nwg%8==0.
__device__ __forceinline__ void xcd_chunk_map(int id, int nby, int nbx,
                                              int& browi, int& bcoli) {
  const int xcd = id & 7;
  const int j = id >> 3;
  const int rch = nby >> 1, cch = nbx >> 2;  // chunk dims
  const int cr = xcd >> 2, cc = xcd & 3;     // chunk grid is 2 x 4
  const int r = j / cch, c = j % cch;
  browi = cr * rch + r;
  bcoli = cc * cch + c;
}

// ---------- GEMM 256x192 p8 (full-coverage variant for gemm1) ----------
// Schedule unchanged from R13 (verified). Only the block->tile map changed
// to the 2D-chunked XCD map above.
template <typename OutT>
__global__ __launch_bounds__(512) void gemmC_kernel(const ushort_t* __restrict__ A,
                                                    const ushort_t* __restrict__ BT,
                                                    OutT* __restrict__ C,
                                                    int M, int N, int K, int ldc) {
  __shared__ ushort_t As[2][256 * 64];  // 64KB
  __shared__ ushort_t Bs[2][192 * 64];  // 48KB
  const int nbx = N / 192, nby = M >> 8;
  int browi, bcoli;
  xcd_chunk_map((int)blockIdx.x, nby, nbx, browi, bcoli);
  const int brow = browi << 8, bcol = bcoli * 192;
  const int tid = threadIdx.x, w = tid >> 6, lane = tid & 63;
  const int wr = w >> 2, wc = w & 3;
  const int lr = lane & 15, lk = lane >> 4;

  const ushort_t* Ab = A + (size_t)brow * K;
  const ushort_t* Bb = BT + (size_t)bcol * K;

  // stage quarter q (64 rows x 64 cols), 1 load/thread
  auto stageQ = [&](const ushort_t* gbase, char* lds, int t, int q) {
    int L = q * 512 + tid;
    int r = L >> 3, sc = L & 7;
    load_lds16(gbase + (size_t)r * K + (t << 6) + ((sc ^ (r & 7)) << 3), lds + L * 16);
  };

  f32x4 acc[8][3] = {};
  const int NT = K >> 6;

  // prologue: tile 0 fully staged (7 loads), drained once
#pragma unroll
  for (int q = 0; q < 4; ++q) stageQ(Ab, (char*)&As[0][0], 0, q);
#pragma unroll
  for (int q = 0; q < 3; ++q) stageQ(Bb, (char*)&Bs[0][0], 0, q);
  asm volatile("s_waitcnt vmcnt(0)" ::: "memory");
  __builtin_amdgcn_s_barrier();

  for (int t = 0; t < NT; ++t) {
    const int c = t & 1;
    const char* Ac = (const char*)&As[c][0];
    const char* Bc = (const char*)&Bs[c][0];
    char* An = (char*)&As[c ^ 1][0];
    char* Bn = (char*)&Bs[c ^ 1][0];
    const bool pf = (t + 1 < NT);

    bf16x8 af[4][2], bfr[3][2];
    // ===== phase 0: A mh0 (8 reads) + B n0,n1 (4 reads); stage Aq0,Aq2 =====
#pragma unroll
    for (int mm = 0; mm < 4; ++mm)
#pragma unroll
      for (int ks = 0; ks < 2; ++ks) {
        int rA = wr * 128 + mm * 16 + lr;
        af[mm][ks] = *(const bf16x8*)(Ac + rA * 128 + (((ks * 4 + lk) ^ (rA & 7)) << 4));
      }
#pragma unroll
    for (int n = 0; n < 2; ++n)
#pragma unroll
      for (int ks = 0; ks < 2; ++ks) {
        int rB = wc * 48 + n * 16 + lr;
        bfr[n][ks] = *(const bf16x8*)(Bc + rB * 128 + (((ks * 4 + lk) ^ (rB & 7)) << 4));
      }
    if (pf) { stageQ(Ab, An, t + 1, 0); stageQ(Ab, An, t + 1, 2); }
    __builtin_amdgcn_s_barrier();
    asm volatile("s_waitcnt lgkmcnt(0)" ::: "memory");
    __builtin_amdgcn_sched_barrier(0);
    __builtin_amdgcn_s_setprio(1);
#pragma unroll
    for (int mm = 0; mm < 4; ++mm)
#pragma unroll
      for (int n = 0; n < 2; ++n)
#pragma unroll
        for (int ks = 0; ks < 2; ++ks)
          acc[mm][n] = __builtin_amdgcn_mfma_f32_16x16x32_bf16(af[mm][ks], bfr[n][ks],
                                                               acc[mm][n], 0, 0, 0);
    __builtin_amdgcn_s_setprio(0);
    __builtin_amdgcn_s_barrier();

    // ===== phase 1: B n2 (2 reads); stage Bq0,Bq1; vmcnt(4) =====
#pragma unroll
    for (int ks = 0; ks < 2; ++ks) {
      int rB = wc * 48 + 32 + lr;
      bfr[2][ks] = *(const bf16x8*)(Bc + rB * 128 + (((ks * 4 + lk) ^ (rB & 7)) << 4));
    }
    if (pf) { stageQ(Bb, Bn, t + 1, 0); stageQ(Bb, Bn, t + 1, 1); }
    __builtin_amdgcn_s_barrier();
    asm volatile("s_waitcnt lgkmcnt(0)" ::: "memory");
    __builtin_amdgcn_sched_barrier(0);
    __builtin_amdgcn_s_setprio(1);
#pragma unroll
    for (int mm = 0; mm < 4; ++mm)
#pragma unroll
      for (int ks = 0; ks < 2; ++ks)
        acc[mm][2] = __builtin_amdgcn_mfma_f32_16x16x32_bf16(af[mm][ks], bfr[2][ks],
                                                             acc[mm][2], 0, 0, 0);
    __builtin_amdgcn_s_setprio(0);
    asm volatile("s_waitcnt vmcnt(4)" ::: "memory");  // Aq1,Aq3 of tile t landed
    __builtin_amdgcn_s_barrier();

    // ===== phase 2: A mh1 (8 reads); stage Bq2,Aq1 =====
#pragma unroll
    for (int mm = 0; mm < 4; ++mm)
#pragma unroll
      for (int ks = 0; ks < 2; ++ks) {
        int rA = wr * 128 + 64 + mm * 16 + lr;
        af[mm][ks] = *(const bf16x8*)(Ac + rA * 128 + (((ks * 4 + lk) ^ (rA & 7)) << 4));
      }
    if (pf) { stageQ(Bb, Bn, t + 1, 2); stageQ(Ab, An, t + 1, 1); }
    __builtin_amdgcn_s_barrier();
    asm volatile("s_waitcnt lgkmcnt(0)" ::: "memory");
    __builtin_amdgcn_sched_barrier(0);
    __builtin_amdgcn_s_setprio(1);
#pragma unroll
    for (int mm = 0; mm < 4; ++mm)
#pragma unroll
      for (int n = 0; n < 2; ++n)
#pragma unroll
        for (int ks = 0; ks < 2; ++ks)
          acc[4 + mm][n] = __builtin_amdgcn_mfma_f32_16x16x32_bf16(af[mm][ks], bfr[n][ks],
                                                                   acc[4 + mm][n], 0, 0, 0);
    __builtin_amdgcn_s_setprio(0);
    __builtin_amdgcn_s_barrier();

    // ===== phase 3: no reads; stage Aq3; MFMA; boundary vmcnt(2) =====
    if (pf) stageQ(Ab, An, t + 1, 3);
    __builtin_amdgcn_s_setprio(1);
#pragma unroll
    for (int mm = 0; mm < 4; ++mm)
#pragma unroll
      for (int ks = 0; ks < 2; ++ks)
        acc[4 + mm][2] = __builtin_amdgcn_mfma_f32_16x16x32_bf16(af[mm][ks], bfr[2][ks],
                                                                 acc[4 + mm][2], 0, 0, 0);
    __builtin_amdgcn_s_setprio(0);
    asm volatile("s_waitcnt vmcnt(2)" ::: "memory");  // all but Aq1,Aq3(t+1) landed
    __builtin_amdgcn_s_barrier();
  }
  // epilogue
#pragma unroll
  for (int m = 0; m < 8; ++m)
#pragma unroll
    for (int n = 0; n < 3; ++n) {
      int row = brow + wr * 128 + m * 16 + lk * 4;
      int col = bcol + wc * 48 + n * 16 + lr;
#pragma unroll
      for (int j = 0; j < 4; ++j) {
        float v = acc[m][n][j];
        if constexpr (sizeof(OutT) == 2)
          C[(size_t)(row + j) * ldc + col] = (OutT)f2bf(v);
        else
          C[(size_t)(row + j) * ldc + col] = v;
      }
    }
}

// ---------- GEMM 128x256, 3-buffer 4-phase p8 (full-grid variant for gemm2) ----------
// Schedule unchanged from R12/R13 (verified). 2D-chunked XCD map.
template <typename OutT>
__global__ __launch_bounds__(512) void gemmB_kernel(const ushort_t* __restrict__ A,
                                                    const ushort_t* __restrict__ BT,
                                                    OutT* __restrict__ C,
                                                    int M, int N, int K, int ldc) {
  __shared__ ushort_t As[3][128 * 64];  // 48KB
  __shared__ ushort_t Bs[3][256 * 64];  // 96KB
  const int nbx = N >> 8, nby = M >> 7;
  int browi, bcoli;
  xcd_chunk_map((int)blockIdx.x, nby, nbx, browi, bcoli);
  const int brow = browi << 7, bcol = bcoli << 8;
  const int tid = threadIdx.x, w = tid >> 6, lane = tid & 63;
  const int wr = w >> 2, wc = w & 3;
  const int lr = lane & 15, lk = lane >> 4;

  const ushort_t* Ab = A + (size_t)brow * K;
  const ushort_t* Bb = BT + (size_t)bcol * K;

  auto stageQ = [&](const ushort_t* gbase, char* lds, int t, int q) {
    int L = q * 512 + tid;
    int r = L >> 3, sc = L & 7;
    load_lds16(gbase + (size_t)r * K + (t << 6) + ((sc ^ (r & 7)) << 3), lds + L * 16);
  };
  auto stageTile = [&](int t, int buf) {
    stageQ(Ab, (char*)&As[buf][0], t, 0);
    stageQ(Ab, (char*)&As[buf][0], t, 1);
#pragma unroll
    for (int q = 0; q < 4; ++q) stageQ(Bb, (char*)&Bs[buf][0], t, q);
  };

  f32x4 acc[4][4] = {};
  const int NT = K >> 6;

  stageTile(0, 0);
  stageTile(1, 1);
  asm volatile("s_waitcnt vmcnt(6)" ::: "memory");
  __builtin_amdgcn_s_barrier();

  int cur = 0;
  for (int t = 0; t < NT; ++t) {
    const char* Ac = (const char*)&As[cur][0];
    const char* Bc = (const char*)&Bs[cur][0];
    const int nxt = (cur + 2 >= 3) ? cur - 1 : cur + 2;  // (t+2)%3
    char* An = (char*)&As[nxt][0];
    char* Bn = (char*)&Bs[nxt][0];
    const bool pf = (t + 2 < NT);

    bf16x8 af[4][2], bfr[4][2];
    // ===== phase 0: A m0,m1 (4) + B n0,n1 (4); stage Aq0(t+2) =====
#pragma unroll
    for (int mm = 0; mm < 2; ++mm)
#pragma unroll
      for (int ks = 0; ks < 2; ++ks) {
        int rA = wr * 64 + mm * 16 + lr;
        af[mm][ks] = *(const bf16x8*)(Ac + rA * 128 + (((ks * 4 + lk) ^ (rA & 7)) << 4));
      }
#pragma unroll
    for (int n = 0; n < 2; ++n)
#pragma unroll
      for (int ks = 0; ks < 2; ++ks) {
        int rB = wc * 64 + n * 16 + lr;
        bfr[n][ks] = *(const bf16x8*)(Bc + rB * 128 + (((ks * 4 + lk) ^ (rB & 7)) << 4));
      }
    if (pf) stageQ(Ab, An, t + 2, 0);
    __builtin_amdgcn_s_barrier();
    asm volatile("s_waitcnt lgkmcnt(0)" ::: "memory");
    __builtin_amdgcn_sched_barrier(0);
    __builtin_amdgcn_s_setprio(1);
#pragma unroll
    for (int mm = 0; mm < 2; ++mm)
#pragma unroll
      for (int n = 0; n < 2; ++n)
#pragma unroll
        for (int ks = 0; ks < 2; ++ks)
          acc[mm][n] = __builtin_amdgcn_mfma_f32_16x16x32_bf16(af[mm][ks], bfr[n][ks],
                                                               acc[mm][n], 0, 0, 0);
    __builtin_amdgcn_s_setprio(0);
    __builtin_amdgcn_s_barrier();

    // ===== phase 1: B n2,n3 (4); stage Aq1(t+2) =====
#pragma unroll
    for (int n = 2; n < 4; ++n)
#pragma unroll
      for (int ks = 0; ks < 2; ++ks) {
        int rB = wc * 64 + n * 16 + lr;
        bfr[n][ks] = *(const bf16x8*)(Bc + rB * 128 + (((ks * 4 + lk) ^ (rB & 7)) << 4));
      }
    if (pf) stageQ(Ab, An, t + 2, 1);
    __builtin_amdgcn_s_barrier();
    asm volatile("s_waitcnt lgkmcnt(0)" ::: "memory");
    __builtin_amdgcn_sched_barrier(0);
    __builtin_amdgcn_s_setprio(1);
#pragma unroll
    for (int mm = 0; mm < 2; ++mm)
#pragma unroll
      for (int n = 2; n < 4; ++n)
#pragma unroll
        for (int ks = 0; ks < 2; ++ks)
          acc[mm][n] = __builtin_amdgcn_mfma_f32_16x16x32_bf16(af[mm][ks], bfr[n][ks],
                                                               acc[mm][n], 0, 0, 0);
    __builtin_amdgcn_s_setprio(0);
    __builtin_amdgcn_s_barrier();

    // ===== phase 2: A m2,m3 (4); stage Bq0,Bq1(t+2) =====
#pragma unroll
    for (int mm = 0; mm < 2; ++mm)
#pragma unroll
      for (int ks = 0; ks < 2; ++ks) {
        int rA = wr * 64 + (mm + 2) * 16 + lr;
        af[2 + mm][ks] = *(const bf16x8*)(Ac + rA * 128 + (((ks * 4 + lk) ^ (rA & 7)) << 4));
      }
    if (pf) { stageQ(Bb, Bn, t + 2, 0); stageQ(Bb, Bn, t + 2, 1); }
    __builtin_amdgcn_s_barrier();
    asm volatile("s_waitcnt lgkmcnt(0)" ::: "memory");
    __builtin_amdgcn_sched_barrier(0);
    __builtin_amdgcn_s_setprio(1);
#pragma unroll
    for (int mm = 0; mm < 2; ++mm)
#pragma unroll
      for (int n = 0; n < 2; ++n)
#pragma unroll
        for (int ks = 0; ks < 2; ++ks)
          acc[2 + mm][n] = __builtin_amdgcn_mfma_f32_16x16x32_bf16(af[2 + mm][ks], bfr[n][ks],
                                                                   acc[2 + mm][n], 0, 0, 0);
    __builtin_amdgcn_s_setprio(0);
    __builtin_amdgcn_s_barrier();

    // ===== phase 3: no reads; stage Bq2,Bq3(t+2); MFMA; counted boundary =====
    if (pf) { stageQ(Bb, Bn, t + 2, 2); stageQ(Bb, Bn, t + 2, 3); }
    __builtin_amdgcn_s_setprio(1);
#pragma unroll
    for (int mm = 0; mm < 2; ++mm)
#pragma unroll
      for (int n = 2; n < 4; ++n)
#pragma unroll
        for (int ks = 0; ks < 2; ++ks)
          acc[2 + mm][n] = __builtin_amdgcn_mfma_f32_16x16x32_bf16(af[2 + mm][ks], bfr[n][ks],
                                                                   acc[2 + mm][n], 0, 0, 0);
    __builtin_amdgcn_s_setprio(0);
    if (pf)
      asm volatile("s_waitcnt vmcnt(6)" ::: "memory");  // t+1 landed; t+2 in flight
    else if (t + 1 < NT)
      asm volatile("s_waitcnt vmcnt(0)" ::: "memory");  // tail drain
    __builtin_amdgcn_s_barrier();
    cur = (cur == 2) ? 0 : cur + 1;
  }
#pragma unroll
  for (int m = 0; m < 4; ++m)
#pragma unroll
    for (int n = 0; n < 4; ++n) {
      int row = brow + wr * 64 + m * 16 + lk * 4;
      int col = bcol + wc * 64 + n * 16 + lr;
#pragma unroll
      for (int j = 0; j < 4; ++j) {
        float v = acc[m][n][j];
        if constexpr (sizeof(OutT) == 2)
          C[(size_t)(row + j) * ldc + col] = (OutT)f2bf(v);
        else
          C[(size_t)(row + j) * ldc + col] = v;
      }
    }
}

// ---------- GEMM: C[M][ldc] = A[M][K] * BT[N][K]^T  (m97 structure, fallback) ----------
template <typename OutT>
__global__ __launch_bounds__(256) void gemm128_kernel(const ushort_t* __restrict__ A,
                                                      const ushort_t* __restrict__ BT,
                                                      OutT* __restrict__ C,
                                                      int M, int N, int K, int ldc) {
  __shared__ ushort_t As[128 * 32];
  __shared__ ushort_t Bs[128 * 32];
  int brow = blockIdx.y * 128, bcol = blockIdx.x * 128;
  int tid = threadIdx.x, w = tid >> 6, lane = tid & 63;
  int wr = w >> 1, wc = w & 1;
  int lr = lane & 15, lk = lane >> 4;
  f32x4 acc[4][4] = {};

  int srow = lane >> 2;
  int scol = (lane & 3) * 8;
  const ushort_t* Ab = A + (size_t)brow * K + scol;
  const ushort_t* Bb = BT + (size_t)bcol * K + scol;

  for (int kt = 0; kt < K; kt += 32) {
#pragma unroll
    for (int i = 0; i < 2; i++) {
      int seg = w * 2 + i;
      int row = seg * 16 + srow;
      load_lds16(Ab + (size_t)row * K + kt, (char*)As + seg * 1024);
      load_lds16(Bb + (size_t)row * K + kt, (char*)Bs + seg * 1024);
    }
    __syncthreads();
    bf16x8 af[4], bfr[4];
#pragma unroll
    for (int m = 0; m < 4; m++)
      af[m] = *(const bf16x8*)&As[(wr * 64 + m * 16 + lr) * 32 + lk * 8];
#pragma unroll
    for (int n = 0; n < 4; n++)
      bfr[n] = *(const bf16x8*)&Bs[(wc * 64 + n * 16 + lr) * 32 + lk * 8];
#pragma unroll
    for (int m = 0; m < 4; m++)
#pragma unroll
      for (int n = 0; n < 4; n++)
        acc[m][n] = __builtin_amdgcn_mfma_f32_16x16x32_bf16(af[m], bfr[n], acc[m][n], 0, 0, 0);
    __syncthreads();
  }
#pragma unroll
  for (int m = 0; m < 4; m++)
#pragma unroll
    for (int n = 0; n < 4; n++) {
      int row = brow + wr * 64 + m * 16 + lk * 4;
      int col = bcol + wc * 64 + n * 16 + lr;
#pragma unroll
      for (int j = 0; j < 4; j++) {
        float v = acc[m][n][j];
        if constexpr (sizeof(OutT) == 2)
          C[(size_t)(row + j) * ldc + col] = (OutT)f2bf(v);
        else
          C[(size_t)(row + j) * ldc + col] = v;
      }
    }
}

// ---------- gemmS: P[tile] = exp2(Q K^T) causal, materialized bf16 ----------
__global__ __launch_bounds__(256) void gemmS_kernel(const ushort_t* __restrict__ C1,
                                                    ushort_t* __restrict__ P) {
  int rem = blockIdx.x, rt = 0;
  while (rem > rt) { rem -= (rt + 1); rt++; }
  const int ct = rem;
  const int h = blockIdx.y, hk = h >> 2;

  __shared__ ushort_t As[128 * 32];
  __shared__ ushort_t Bs[128 * 32];
  int tid = threadIdx.x, w = tid >> 6, lane = tid & 63;
  int wr = w >> 1, wc = w & 1;
  int lr = lane & 15, lk = lane >> 4;
  f32x4 acc[4][4] = {};
  int srow = lane >> 2;
  int scol = (lane & 3) * 8;
  const ushort_t* Ab = C1 + (size_t)(rt * 128) * 6144 + h * 128 + scol;         // Q
  const ushort_t* Bb = C1 + (size_t)(ct * 128) * 6144 + 4096 + hk * 128 + scol; // K

  for (int kt = 0; kt < 128; kt += 32) {
#pragma unroll
    for (int i = 0; i < 2; i++) {
      int seg = w * 2 + i;
      int row = seg * 16 + srow;
      load_lds16(Ab + (size_t)row * 6144 + kt, (char*)As + seg * 1024);
      load_lds16(Bb + (size_t)row * 6144 + kt, (char*)Bs + seg * 1024);
    }
    __syncthreads();
    bf16x8 af[4], bfr[4];
#pragma unroll
    for (int m = 0; m < 4; m++)
      af[m] = *(const bf16x8*)&As[(wr * 64 + m * 16 + lr) * 32 + lk * 8];
#pragma unroll
    for (int n = 0; n < 4; n++)
      bfr[n] = *(const bf16x8*)&Bs[(wc * 64 + n * 16 + lr) * 32 + lk * 8];
#pragma unroll
    for (int m = 0; m < 4; m++)
#pragma unroll
      for (int n = 0; n < 4; n++)
        acc[m][n] = __builtin_amdgcn_mfma_f32_16x16x32_bf16(af[m], bfr[n], acc[m][n], 0, 0, 0);
    __syncthreads();
  }
  ushort_t* Pt = P + ((size_t)h * 136 + (size_t)(rt * (rt + 1) / 2) + ct) * 16384;
  const bool diag = (rt == ct);
#pragma unroll
  for (int m = 0; m < 4; m++)
#pragma unroll
    for (int n = 0; n < 4; n++) {
      int row = wr * 64 + m * 16 + lk * 4;
      int col = wc * 64 + n * 16 + lr;
#pragma unroll
      for (int j = 0; j < 4; j++) {
        float v = exp2_hw(acc[m][n][j]);
        if (diag && col > row + j) v = 0.f;
        Pt[(row + j) * 128 + col] = f2bf(v);
      }
    }
}

// ---------- gemmPV: AO[rt-tile] = (P * V) / rowsum(P) ----------
// Row sums fused via an all-ones MFMA (verified R13).
__global__ __launch_bounds__(256) void gemmPV_kernel(const ushort_t* __restrict__ P,
                                                     const ushort_t* __restrict__ VT,
                                                     ushort_t* __restrict__ AO) {
  const int h = blockIdx.x, hk = h >> 2;
  const int rt = 15 - (int)blockIdx.y;

  __shared__ ushort_t As[128 * 32];
  __shared__ ushort_t Bs[128 * 32];
  int tid = threadIdx.x, w = tid >> 6, lane = tid & 63;
  int wr = w >> 1, wc = w & 1;
  int lr = lane & 15, lk = lane >> 4;
  f32x4 acc[4][4] = {};
  f32x4 sacc[4] = {};
  bf16x8 ones;
#pragma unroll
  for (int j = 0; j < 8; j++) ones[j] = (short)0x3F80;  // bf16 1.0
  int srow = lane >> 2;
  int scol = (lane & 3) * 8;
  const ushort_t* Ph = P + ((size_t)h * 136 + (size_t)(rt * (rt + 1) / 2)) * 16384;
  const ushort_t* Vh = VT + (size_t)hk * 128 * 2048;

  const int nks = (rt + 1) * 4;
  for (int ks = 0; ks < nks; ks++) {
    int k0 = ks * 32;
    int ctk = k0 >> 7, kin = k0 & 127;
#pragma unroll
    for (int i = 0; i < 2; i++) {
      int seg = w * 2 + i;
      int row = seg * 16 + srow;
      load_lds16(Ph + (size_t)ctk * 16384 + (size_t)row * 128 + kin + scol,
                 (char*)As + seg * 1024);
      load_lds16(Vh + (size_t)row * 2048 + k0 + scol, (char*)Bs + seg * 1024);
    }
    __syncthreads();
    bf16x8 af[4], bfr[4];
#pragma unroll
    for (int m = 0; m < 4; m++)
      af[m] = *(const bf16x8*)&As[(wr * 64 + m * 16 + lr) * 32 + lk * 8];
#pragma unroll
    for (int n = 0; n < 4; n++)
      bfr[n] = *(const bf16x8*)&Bs[(wc * 64 + n * 16 + lr) * 32 + lk * 8];
#pragma unroll
    for (int m = 0; m < 4; m++) {
#pragma unroll
      for (int n = 0; n < 4; n++)
        acc[m][n] = __builtin_amdgcn_mfma_f32_16x16x32_bf16(af[m], bfr[n], acc[m][n], 0, 0, 0);
      sacc[m] = __builtin_amdgcn_mfma_f32_16x16x32_bf16(af[m], ones, sacc[m], 0, 0, 0);
    }
    __syncthreads();
  }
  const int q0 = rt * 128;
#pragma unroll
  for (int m = 0; m < 4; m++) {
    float invs[4];
#pragma unroll
    for (int j = 0; j < 4; j++) invs[j] = 1.0f / sacc[m][j];
#pragma unroll
    for (int n = 0; n < 4; n++) {
      int row = wr * 64 + m * 16 + lk * 4;
      int col = wc * 64 + n * 16 + lr;
#pragma unroll
      for (int j = 0; j < 4; j++) {
        float v = acc[m][n][j] * invs[j];
        AO[(size_t)(q0 + row + j) * 4096 + h * 128 + col] = f2bf(v);
      }
    }
  }
}

// ---------- flash attention (fallback when workspace too small) ----------
__global__ __launch_bounds__(256) void fattn_kernel(const ushort_t* __restrict__ C1,
                                                    const ushort_t* __restrict__ VT,
                                                    ushort_t* __restrict__ AO) {
  __shared__ ushort_t Pl[4][32][72];
  const int h = blockIdx.x, hk = h >> 2;
  const int qt = gridDim.y - 1 - blockIdx.y;
  const int tid = threadIdx.x, w = tid >> 6, lane = tid & 63;
  const int lq = lane & 31, hi = lane >> 5;
  const int qw0 = qt * 128 + w * 32;
  const int qabs = qw0 + lq;

  const ushort_t* Kb = C1 + 4096 + (size_t)hk * 128;
  const ushort_t* Vb = VT + (size_t)hk * 128 * 2048;

  bf16x8 qf[8];
  {
    const ushort_t* qrow = C1 + (size_t)qabs * 6144 + h * 128;
#pragma unroll
    for (int s = 0; s < 8; s++) qf[s] = *(const bf16x8*)(qrow + s * 16 + hi * 8);
  }
  f32x16 ot[4] = {};
  float mrow = -1e30f, ssum = 0.f;

  const int ktmax = (qw0 + 31) >> 6;
  for (int kt = 0; kt <= ktmax; kt++) {
    f32x16 sg[2] = {};
#pragma unroll
    for (int g = 0; g < 2; g++) {
      bf16x8 kfa[8];
      const ushort_t* krow = Kb + (size_t)(kt * 64 + g * 32 + lq) * 6144 + hi * 8;
#pragma unroll
      for (int s = 0; s < 8; s++) kfa[s] = *(const bf16x8*)(krow + s * 16);
#pragma unroll
      for (int s = 0; s < 8; s++)
        sg[g] = __builtin_amdgcn_mfma_f32_32x32x16_bf16(kfa[s], qf[s], sg[g], 0, 0, 0);
    }
    if (kt * 64 + 63 > qw0) {
#pragma unroll
      for (int g = 0; g < 2; g++)
#pragma unroll
        for (int r = 0; r < 16; r++) {
          int key = kt * 64 + g * 32 + (r & 3) + 8 * (r >> 2) + 4 * hi;
          if (key > qabs) sg[g][r] = -1e30f;
        }
    }
    float pm = -1e30f;
#pragma unroll
    for (int g = 0; g < 2; g++)
#pragma unroll
      for (int r = 0; r < 16; r++) pm = fmaxf(pm, sg[g][r]);
    pm = fmaxf(pm, __shfl_xor(pm, 32));
    float mnew = fmaxf(mrow, pm);
    float corr = exp2_hw(mrow - mnew);
    mrow = mnew;
    float ps = 0.f;
#pragma unroll
    for (int g = 0; g < 2; g++)
#pragma unroll
      for (int r = 0; r < 16; r++) {
        float e = exp2_hw(sg[g][r] - mnew);
        sg[g][r] = e;
        ps += e;
      }
    ps += __shfl_xor(ps, 32);
    ssum = ssum * corr + ps;
    if (!__all(corr == 1.f)) {
#pragma unroll
      for (int d = 0; d < 4; d++)
#pragma unroll
        for (int r = 0; r < 16; r++) ot[d][r] *= corr;
    }
#pragma unroll
    for (int g = 0; g < 2; g++)
#pragma unroll
      for (int rq = 0; rq < 4; rq++) {
        bf16x4 pk;
#pragma unroll
        for (int j = 0; j < 4; j++) pk[j] = (short)f2bf(sg[g][rq * 4 + j]);
        *(bf16x4*)&Pl[w][lq][g * 32 + rq * 8 + hi * 4] = pk;
      }
    asm volatile("s_waitcnt lgkmcnt(0)" ::: "memory");
    bf16x8 pf[4];
#pragma unroll
    for (int s = 0; s < 4; s++) pf[s] = *(const bf16x8*)&Pl[w][lq][s * 16 + hi * 8];
#pragma unroll
    for (int d = 0; d < 4; d++) {
      bf16x8 vfa[4];
      const ushort_t* vrow = Vb + (size_t)(d * 32 + lq) * 2048 + kt * 64 + hi * 8;
#pragma unroll
      for (int s = 0; s < 4; s++) vfa[s] = *(const bf16x8*)(vrow + s * 16);
#pragma unroll
      for (int s = 0; s < 4; s++)
        ot[d] = __builtin_amdgcn_mfma_f32_32x32x16_bf16(vfa[s], pf[s], ot[d], 0, 0, 0);
    }
  }
  const float inv = 1.0f / ssum;
  ushort_t* orow = AO + (size_t)qabs * 4096 + h * 128;
#pragma unroll
  for (int d = 0; d < 4; d++)
#pragma unroll
    for (int rq = 0; rq < 4; rq++) {
      bf16x4 ok;
#pragma unroll
      for (int j = 0; j < 4; j++) ok[j] = (short)f2bf(ot[d][rq * 4 + j] * inv);
      *(bf16x4*)(orow + d * 32 + rq * 8 + hi * 4) = ok;
    }
}

// ---------- launch ----------
extern "C" void kernel_launch(void* const* d_in, const int* in_sizes, int n_in,
                              void* d_out, int out_size, void* d_ws, size_t ws_size,
                              hipStream_t stream) {
  (void)in_sizes; (void)n_in; (void)out_size;
  const float* x    = (const float*)d_in[0];
  const float* wq   = (const float*)d_in[1];
  const float* wk   = (const float*)d_in[2];
  const float* wv   = (const float*)d_in[3];
  const float* wo   = (const float*)d_in[4];
  const float* cosb = (const float*)d_in[5];
  const float* sinb = (const float*)d_in[6];

  char* ws = (char*)d_ws;
  const bool fast = ws_size >= (215ull << 20);

  if (fast) {
    // layout (MiB): C1[0,24) VT[24,28) woT[28,60) xb[60,76) wT[76,124)
    //               P[60,196) (xb+wT dead after gemm1)  AO[196,212)
    ushort_t* C1  = (ushort_t*)(ws);
    ushort_t* VT  = (ushort_t*)(ws + ((size_t)24 << 20));
    ushort_t* woT = (ushort_t*)(ws + ((size_t)28 << 20));
    ushort_t* xb  = (ushort_t*)(ws + ((size_t)60 << 20));
    ushort_t* wT  = (ushort_t*)(ws + ((size_t)76 << 20));
    ushort_t* P   = (ushort_t*)(ws + ((size_t)60 << 20));
    ushort_t* AO  = (ushort_t*)(ws + ((size_t)196 << 20));

    cvt_x_kernel<<<4096, 256, 0, stream>>>(x, xb);
    tr_cvt_kernel<<<dim3(64, 64), 256, 0, stream>>>(wq, wT, 4096, 4096);
    tr_cvt_kernel<<<dim3(16, 64), 256, 0, stream>>>(wk, wT + (size_t)4096 * 4096, 4096, 1024);
    tr_cvt_kernel<<<dim3(16, 64), 256, 0, stream>>>(wv, wT + (size_t)5120 * 4096, 4096, 1024);
    tr_cvt_kernel<<<dim3(64, 64), 256, 0, stream>>>(wo, woT, 4096, 4096);

    // QKV projection: 256x192 p8 GEMM, grid 8x32 = 256, 2D-chunked XCD map
    gemmC_kernel<ushort_t><<<256, 512, 0, stream>>>(xb, wT, C1, 2048, 6144, 4096, 6144);
    rope_kernel<<<5120, 256, 0, stream>>>(C1, cosb, sinb);
    trv_kernel<<<dim3(16, 32), 256, 0, stream>>>(C1, VT);

    gemmS_kernel<<<dim3(136, 32), 256, 0, stream>>>(C1, P);
    gemmPV_kernel<<<dim3(32, 16), 256, 0, stream>>>(P, VT, AO);  // rowsum fused

    // output projection: 128x256 3-buf p8, grid 16x16 = 256, 2D-chunked XCD map
    gemmB_kernel<float><<<256, 512, 0, stream>>>(AO, woT, (float*)d_out, 2048, 4096, 4096, 4096);
  } else {
    // proven 92MiB layout + R7 fattn
    ushort_t* xb  = (ushort_t*)(ws);
    ushort_t* wT  = (ushort_t*)(ws + ((size_t)16 << 20));
    ushort_t* C1  = (ushort_t*)(ws + ((size_t)64 << 20));
    ushort_t* VT  = (ushort_t*)(ws + ((size_t)88 << 20));
    ushort_t* AO  = xb;
    ushort_t* woT = wT;

    cvt_x_kernel<<<4096, 256, 0, stream>>>(x, xb);
    tr_cvt_kernel<<<dim3(64, 64), 256, 0, stream>>>(wq, wT, 4096, 4096);
    tr_cvt_kernel<<<dim3(16, 64), 256, 0, stream>>>(wk, wT + (size_t)4096 * 4096, 4096, 1024);
    tr_cvt_kernel<<<dim3(16, 64), 256, 0, stream>>>(wv, wT + (size_t)5120 * 4096, 4096, 1024);
    gemm128_kernel<ushort_t><<<dim3(48, 16), 256, 0, stream>>>(xb, wT, C1, 2048, 6144, 4096, 6144);
    rope_kernel<<<5120, 256, 0, stream>>>(C1, cosb, sinb);
    trv_kernel<<<dim3(16, 32), 256, 0, stream>>>(C1, VT);
    tr_cvt_kernel<<<dim3(64, 64), 256, 0, stream>>>(wo, woT, 4096, 4096);
    fattn_kernel<<<dim3(32, 16), 256, 0, stream>>>(C1, VT, AO);
    gemm128_kernel<float><<<dim3(32, 16), 256, 0, stream>>>(AO, woT, (float*)d_out, 2048, 4096, 4096, 4096);
  }
}

// Round 15
// 373.380 us; speedup vs baseline: 1.1360x; 1.0117x over previous
//
#include <hip/hip_runtime.h>
#include <stdint.h>

typedef unsigned short ushort_t;
typedef short bf16x4 __attribute__((ext_vector_type(4)));
typedef short bf16x8 __attribute__((ext_vector_type(8)));
typedef float f32x4 __attribute__((ext_vector_type(4)));
typedef float f32x16 __attribute__((ext_vector_type(16)));
typedef float f32x4v __attribute__((ext_vector_type(4)));

// ---------- helpers ----------
__device__ __forceinline__ ushort_t f2bf(float f) {
  unsigned int u = __builtin_bit_cast(unsigned int, f);
  u += 0x7fffu + ((u >> 16) & 1u);
  return (ushort_t)(u >> 16);
}
__device__ __forceinline__ float bf2f(ushort_t h) {
  unsigned int u = ((unsigned int)h) << 16;
  return __builtin_bit_cast(float, u);
}
__device__ __forceinline__ float exp2_hw(float x) {
  return __builtin_amdgcn_exp2f(x);  // v_exp_f32: D = 2^S0
}
__device__ __forceinline__ void load_lds16(const void* g, void* l) {
  __builtin_amdgcn_global_load_lds(
      (const __attribute__((address_space(1))) void*)g,
      (__attribute__((address_space(3))) void*)l, 16, 0, 0);
}

// ---------- x fp32 -> bf16 ----------
__global__ __launch_bounds__(256) void cvt_x_kernel(const float* __restrict__ x,
                                                    ushort_t* __restrict__ xb) {
  int i = blockIdx.x * 256 + threadIdx.x;  // each thread: 8 elems
  const f32x4v* xv = (const f32x4v*)x;
  f32x4v a = xv[2 * i], b = xv[2 * i + 1];
  bf16x8 o;
  o[0] = (short)f2bf(a[0]); o[1] = (short)f2bf(a[1]);
  o[2] = (short)f2bf(a[2]); o[3] = (short)f2bf(a[3]);
  o[4] = (short)f2bf(b[0]); o[5] = (short)f2bf(b[1]);
  o[6] = (short)f2bf(b[2]); o[7] = (short)f2bf(b[3]);
  ((bf16x8*)xb)[i] = o;
}

// ---------- weight fp32 [R][C] -> bf16 transposed [C][R], vectorized ----------
// read f32x4 (16B/thread-iter), write bf16x4 (8B/thread-iter).
// dst[(c0+X)*R + r0+Y] = src[(r0+Y)*C + c0+X]; X=cr, Y=cg*4+j (verified map).
__global__ __launch_bounds__(256) void tr_cvt_kernel(const float* __restrict__ src,
                                                     ushort_t* __restrict__ dst,
                                                     int R, int C) {
  __shared__ float tile[64][65];
  int r0 = blockIdx.y * 64, c0 = blockIdx.x * 64;
  int t = threadIdx.x;
#pragma unroll
  for (int i = 0; i < 4; i++) {
    int idx = t + i * 256;          // 0..1023
    int r = idx >> 4, c4 = idx & 15;
    f32x4v v = *(const f32x4v*)&src[(size_t)(r0 + r) * C + c0 + c4 * 4];
#pragma unroll
    for (int j = 0; j < 4; j++) tile[r][c4 * 4 + j] = v[j];
  }
  __syncthreads();
#pragma unroll
  for (int i = 0; i < 4; i++) {
    int idx = t + i * 256;
    int cr = idx >> 4, cg = idx & 15;
    bf16x4 o;
#pragma unroll
    for (int j = 0; j < 4; j++) o[j] = (short)f2bf(tile[cg * 4 + j][cr]);
    *(bf16x4*)&dst[(size_t)(c0 + cr) * R + r0 + cg * 4] = o;
  }
}

// ---------- RoPE in-place on C1 (Q cols 0..4095 pre-scaled by scale*log2e) ----------
__global__ __launch_bounds__(256) void rope_kernel(ushort_t* __restrict__ C1,
                                                   const float* __restrict__ cosb,
                                                   const float* __restrict__ sinb) {
  int idx = blockIdx.x * 256 + threadIdx.x;  // 2048 * 640
  int s = idx / 640;
  int col0 = (idx % 640) * 8;
  int i0 = (col0 & 127) >> 1;
  const float qs = (col0 < 4096) ? 0.12753055296570565f : 1.0f;  // scale*log2e
  ushort_t* p = C1 + (size_t)s * 6144 + col0;
  bf16x8 v = *(const bf16x8*)p;
  bf16x8 o;
  const float* cr = cosb + s * 64 + i0;
  const float* sr = sinb + s * 64 + i0;
#pragma unroll
  for (int j = 0; j < 4; j++) {
    float tr = bf2f((ushort_t)v[2 * j]);
    float ti = bf2f((ushort_t)v[2 * j + 1]);
    float c = cr[j], sn = sr[j];
    o[2 * j] = (short)f2bf((tr * c - ti * sn) * qs);
    o[2 * j + 1] = (short)f2bf((tr * sn + ti * c) * qs);
  }
  *(bf16x8*)p = o;
}

// ---------- V part of C1 -> VT [1024][2048] (row = hk*128+d, col = s) ----------
__global__ __launch_bounds__(256) void trv_kernel(const ushort_t* __restrict__ C1,
                                                  ushort_t* __restrict__ VT) {
  __shared__ ushort_t tile[64][65];
  int c0 = blockIdx.x * 64;  // within 1024
  int r0 = blockIdx.y * 64;  // within 2048
  int t = threadIdx.x;
#pragma unroll
  for (int i = 0; i < 16; i++) {
    int idx = t + i * 256;
    int r = idx >> 6, c = idx & 63;
    tile[r][c] = C1[(size_t)(r0 + r) * 6144 + 5120 + c0 + c];
  }
  __syncthreads();
#pragma unroll
  for (int i = 0; i < 16; i++) {
    int idx = t + i * 256;
    int cr = idx >> 6, cc = idx & 63;
    VT[(size_t)(c0 + cr) * 2048 + r0 + cc] = tile[cc][cr];
  }
}

// ---------- 2D-chunked XCD block mapping ----------
__device__ __forceinline__ void xcd_chunk_map(int id, int nby, int nbx,
                                              int& browi, int& bcoli) {
  const int xcd = id & 7;
  const int j = id >> 3;
  const int rch = nby >> 1, cch = nbx >> 2;  // chunk dims
  const int cr = xcd >> 2, cc = xcd & 3;     // chunk grid is 2 x 4
  const int r = j / cch, c = j % cch;
  browi = cr * rch + r;
  bcoli = cc * cch + c;
}

// ---------- GEMM 256x192 p8 v2: asymmetric deep prefetch ----------
// A 2-buf (depth-1, issued EARLY: q0,q2 at ph0; q1,q3 at ph1), B 3-buf
// (depth-2: B(t+2) issued ph2/ph3) -> B gets >=4-phase (~900cy) latency slack.
// FIFO-derived waits (issue order per tile: [A(t+1)q0,q2][A(t+1)q1,q3]
// [B(t+2)q0,q1][B(t+2)q2]):
//  - prologue: B(0)x3, A(0)x4, B(1)x3 issued -> vmcnt(5) = B(0)+A(0)q0,q2 landed.
//  - ph1-end vmcnt(7): drains A(t)q1,q3 (needed by ph2); leaves B(t+1)x3+A(t+1)x4.
//  - boundary vmcnt(5): drains B(t+1)x3 + A(t+1)q0,q2 (needed by next ph0);
//    leaves A(t+1)q1,q3 + B(t+2)x3. Tail (t+2>=NT): vmcnt(0).
// All waits sit vmcnt-then-barrier so every wave's slice is published.
template <typename OutT>
__global__ __launch_bounds__(512) void gemmC_kernel(const ushort_t* __restrict__ A,
                                                    const ushort_t* __restrict__ BT,
                                                    OutT* __restrict__ C,
                                                    int M, int N, int K, int ldc) {
  __shared__ ushort_t As[2][256 * 64];  // 64KB
  __shared__ ushort_t Bs[3][192 * 64];  // 72KB
  const int nbx = N / 192, nby = M >> 8;
  int browi, bcoli;
  xcd_chunk_map((int)blockIdx.x, nby, nbx, browi, bcoli);
  const int brow = browi << 8, bcol = bcoli * 192;
  const int tid = threadIdx.x, w = tid >> 6, lane = tid & 63;
  const int wr = w >> 2, wc = w & 3;
  const int lr = lane & 15, lk = lane >> 4;

  const ushort_t* Ab = A + (size_t)brow * K;
  const ushort_t* Bb = BT + (size_t)bcol * K;

  // stage quarter q (64 rows x 64 cols), 1 load/thread
  auto stageQ = [&](const ushort_t* gbase, char* lds, int t, int q) {
    int L = q * 512 + tid;
    int r = L >> 3, sc = L & 7;
    load_lds16(gbase + (size_t)r * K + (t << 6) + ((sc ^ (r & 7)) << 3), lds + L * 16);
  };

  f32x4 acc[8][3] = {};
  const int NT = K >> 6;  // requires NT >= 3

  // prologue: B(0)x3, A(0)q0,q2,q1,q3, B(1)x3
#pragma unroll
  for (int q = 0; q < 3; ++q) stageQ(Bb, (char*)&Bs[0][0], 0, q);
  stageQ(Ab, (char*)&As[0][0], 0, 0);
  stageQ(Ab, (char*)&As[0][0], 0, 2);
  stageQ(Ab, (char*)&As[0][0], 0, 1);
  stageQ(Ab, (char*)&As[0][0], 0, 3);
#pragma unroll
  for (int q = 0; q < 3; ++q) stageQ(Bb, (char*)&Bs[1][0], 1, q);
  asm volatile("s_waitcnt vmcnt(5)" ::: "memory");
  __builtin_amdgcn_s_barrier();

  int bcur = 0;
  for (int t = 0; t < NT; ++t) {
    const int c = t & 1;
    const char* Ac = (const char*)&As[c][0];
    const char* Bc = (const char*)&Bs[bcur][0];
    char* An = (char*)&As[c ^ 1][0];
    const int bnxt = (bcur + 2 >= 3) ? bcur - 1 : bcur + 2;  // (t+2)%3
    char* Bn = (char*)&Bs[bnxt][0];
    const bool pfA = (t + 1 < NT), pfB = (t + 2 < NT);

    bf16x8 af[4][2], bfr[3][2];
    // ===== phase 0: A mh0 (8 reads) + B n0,n1 (4 reads); stage A(t+1)q0,q2 =====
#pragma unroll
    for (int mm = 0; mm < 4; ++mm)
#pragma unroll
      for (int ks = 0; ks < 2; ++ks) {
        int rA = wr * 128 + mm * 16 + lr;
        af[mm][ks] = *(const bf16x8*)(Ac + rA * 128 + (((ks * 4 + lk) ^ (rA & 7)) << 4));
      }
#pragma unroll
    for (int n = 0; n < 2; ++n)
#pragma unroll
      for (int ks = 0; ks < 2; ++ks) {
        int rB = wc * 48 + n * 16 + lr;
        bfr[n][ks] = *(const bf16x8*)(Bc + rB * 128 + (((ks * 4 + lk) ^ (rB & 7)) << 4));
      }
    if (pfA) { stageQ(Ab, An, t + 1, 0); stageQ(Ab, An, t + 1, 2); }
    __builtin_amdgcn_s_barrier();
    asm volatile("s_waitcnt lgkmcnt(0)" ::: "memory");
    __builtin_amdgcn_sched_barrier(0);
    __builtin_amdgcn_s_setprio(1);
#pragma unroll
    for (int mm = 0; mm < 4; ++mm)
#pragma unroll
      for (int n = 0; n < 2; ++n)
#pragma unroll
        for (int ks = 0; ks < 2; ++ks)
          acc[mm][n] = __builtin_amdgcn_mfma_f32_16x16x32_bf16(af[mm][ks], bfr[n][ks],
                                                               acc[mm][n], 0, 0, 0);
    __builtin_amdgcn_s_setprio(0);
    __builtin_amdgcn_s_barrier();

    // ===== phase 1: B n2 (2 reads); stage A(t+1)q1,q3; vmcnt(7) =====
#pragma unroll
    for (int ks = 0; ks < 2; ++ks) {
      int rB = wc * 48 + 32 + lr;
      bfr[2][ks] = *(const bf16x8*)(Bc + rB * 128 + (((ks * 4 + lk) ^ (rB & 7)) << 4));
    }
    if (pfA) { stageQ(Ab, An, t + 1, 1); stageQ(Ab, An, t + 1, 3); }
    __builtin_amdgcn_s_barrier();
    asm volatile("s_waitcnt lgkmcnt(0)" ::: "memory");
    __builtin_amdgcn_sched_barrier(0);
    __builtin_amdgcn_s_setprio(1);
#pragma unroll
    for (int mm = 0; mm < 4; ++mm)
#pragma unroll
      for (int ks = 0; ks < 2; ++ks)
        acc[mm][2] = __builtin_amdgcn_mfma_f32_16x16x32_bf16(af[mm][ks], bfr[2][ks],
                                                             acc[mm][2], 0, 0, 0);
    __builtin_amdgcn_s_setprio(0);
    asm volatile("s_waitcnt vmcnt(7)" ::: "memory");  // A(t)q1,q3 landed
    __builtin_amdgcn_s_barrier();

    // ===== phase 2: A mh1 (8 reads); stage B(t+2)q0,q1 =====
#pragma unroll
    for (int mm = 0; mm < 4; ++mm)
#pragma unroll
      for (int ks = 0; ks < 2; ++ks) {
        int rA = wr * 128 + 64 + mm * 16 + lr;
        af[mm][ks] = *(const bf16x8*)(Ac + rA * 128 + (((ks * 4 + lk) ^ (rA & 7)) << 4));
      }
    if (pfB) { stageQ(Bb, Bn, t + 2, 0); stageQ(Bb, Bn, t + 2, 1); }
    __builtin_amdgcn_s_barrier();
    asm volatile("s_waitcnt lgkmcnt(0)" ::: "memory");
    __builtin_amdgcn_sched_barrier(0);
    __builtin_amdgcn_s_setprio(1);
#pragma unroll
    for (int mm = 0; mm < 4; ++mm)
#pragma unroll
      for (int n = 0; n < 2; ++n)
#pragma unroll
        for (int ks = 0; ks < 2; ++ks)
          acc[4 + mm][n] = __builtin_amdgcn_mfma_f32_16x16x32_bf16(af[mm][ks], bfr[n][ks],
                                                                   acc[4 + mm][n], 0, 0, 0);
    __builtin_amdgcn_s_setprio(0);
    __builtin_amdgcn_s_barrier();

    // ===== phase 3: no reads; stage B(t+2)q2; MFMA; boundary wait =====
    if (pfB) stageQ(Bb, Bn, t + 2, 2);
    __builtin_amdgcn_s_setprio(1);
#pragma unroll
    for (int mm = 0; mm < 4; ++mm)
#pragma unroll
      for (int ks = 0; ks < 2; ++ks)
        acc[4 + mm][2] = __builtin_amdgcn_mfma_f32_16x16x32_bf16(af[mm][ks], bfr[2][ks],
                                                                 acc[4 + mm][2], 0, 0, 0);
    __builtin_amdgcn_s_setprio(0);
    if (pfB)
      asm volatile("s_waitcnt vmcnt(5)" ::: "memory");  // B(t+1)+A(t+1)q0,q2 landed
    else
      asm volatile("s_waitcnt vmcnt(0)" ::: "memory");  // tail drain (last 2 tiles)
    __builtin_amdgcn_s_barrier();
    bcur = (bcur + 1 == 3) ? 0 : bcur + 1;
  }
  // epilogue
#pragma unroll
  for (int m = 0; m < 8; ++m)
#pragma unroll
    for (int n = 0; n < 3; ++n) {
      int row = brow + wr * 128 + m * 16 + lk * 4;
      int col = bcol + wc * 48 + n * 16 + lr;
#pragma unroll
      for (int j = 0; j < 4; ++j) {
        float v = acc[m][n][j];
        if constexpr (sizeof(OutT) == 2)
          C[(size_t)(row + j) * ldc + col] = (OutT)f2bf(v);
        else
          C[(size_t)(row + j) * ldc + col] = v;
      }
    }
}

// ---------- GEMM 128x256, 3-buffer 4-phase p8 (full-grid variant for gemm2) ----------
// Schedule unchanged (verified R12-R14). 2D-chunked XCD map.
template <typename OutT>
__global__ __launch_bounds__(512) void gemmB_kernel(const ushort_t* __restrict__ A,
                                                    const ushort_t* __restrict__ BT,
                                                    OutT* __restrict__ C,
                                                    int M, int N, int K, int ldc) {
  __shared__ ushort_t As[3][128 * 64];  // 48KB
  __shared__ ushort_t Bs[3][256 * 64];  // 96KB
  const int nbx = N >> 8, nby = M >> 7;
  int browi, bcoli;
  xcd_chunk_map((int)blockIdx.x, nby, nbx, browi, bcoli);
  const int brow = browi << 7, bcol = bcoli << 8;
  const int tid = threadIdx.x, w = tid >> 6, lane = tid & 63;
  const int wr = w >> 2, wc = w & 3;
  const int lr = lane & 15, lk = lane >> 4;

  const ushort_t* Ab = A + (size_t)brow * K;
  const ushort_t* Bb = BT + (size_t)bcol * K;

  auto stageQ = [&](const ushort_t* gbase, char* lds, int t, int q) {
    int L = q * 512 + tid;
    int r = L >> 3, sc = L & 7;
    load_lds16(gbase + (size_t)r * K + (t << 6) + ((sc ^ (r & 7)) << 3), lds + L * 16);
  };
  auto stageTile = [&](int t, int buf) {
    stageQ(Ab, (char*)&As[buf][0], t, 0);
    stageQ(Ab, (char*)&As[buf][0], t, 1);
#pragma unroll
    for (int q = 0; q < 4; ++q) stageQ(Bb, (char*)&Bs[buf][0], t, q);
  };

  f32x4 acc[4][4] = {};
  const int NT = K >> 6;

  stageTile(0, 0);
  stageTile(1, 1);
  asm volatile("s_waitcnt vmcnt(6)" ::: "memory");
  __builtin_amdgcn_s_barrier();

  int cur = 0;
  for (int t = 0; t < NT; ++t) {
    const char* Ac = (const char*)&As[cur][0];
    const char* Bc = (const char*)&Bs[cur][0];
    const int nxt = (cur + 2 >= 3) ? cur - 1 : cur + 2;  // (t+2)%3
    char* An = (char*)&As[nxt][0];
    char* Bn = (char*)&Bs[nxt][0];
    const bool pf = (t + 2 < NT);

    bf16x8 af[4][2], bfr[4][2];
    // ===== phase 0: A m0,m1 (4) + B n0,n1 (4); stage Aq0(t+2) =====
#pragma unroll
    for (int mm = 0; mm < 2; ++mm)
#pragma unroll
      for (int ks = 0; ks < 2; ++ks) {
        int rA = wr * 64 + mm * 16 + lr;
        af[mm][ks] = *(const bf16x8*)(Ac + rA * 128 + (((ks * 4 + lk) ^ (rA & 7)) << 4));
      }
#pragma unroll
    for (int n = 0; n < 2; ++n)
#pragma unroll
      for (int ks = 0; ks < 2; ++ks) {
        int rB = wc * 64 + n * 16 + lr;
        bfr[n][ks] = *(const bf16x8*)(Bc + rB * 128 + (((ks * 4 + lk) ^ (rB & 7)) << 4));
      }
    if (pf) stageQ(Ab, An, t + 2, 0);
    __builtin_amdgcn_s_barrier();
    asm volatile("s_waitcnt lgkmcnt(0)" ::: "memory");
    __builtin_amdgcn_sched_barrier(0);
    __builtin_amdgcn_s_setprio(1);
#pragma unroll
    for (int mm = 0; mm < 2; ++mm)
#pragma unroll
      for (int n = 0; n < 2; ++n)
#pragma unroll
        for (int ks = 0; ks < 2; ++ks)
          acc[mm][n] = __builtin_amdgcn_mfma_f32_16x16x32_bf16(af[mm][ks], bfr[n][ks],
                                                               acc[mm][n], 0, 0, 0);
    __builtin_amdgcn_s_setprio(0);
    __builtin_amdgcn_s_barrier();

    // ===== phase 1: B n2,n3 (4); stage Aq1(t+2) =====
#pragma unroll
    for (int n = 2; n < 4; ++n)
#pragma unroll
      for (int ks = 0; ks < 2; ++ks) {
        int rB = wc * 64 + n * 16 + lr;
        bfr[n][ks] = *(const bf16x8*)(Bc + rB * 128 + (((ks * 4 + lk) ^ (rB & 7)) << 4));
      }
    if (pf) stageQ(Ab, An, t + 2, 1);
    __builtin_amdgcn_s_barrier();
    asm volatile("s_waitcnt lgkmcnt(0)" ::: "memory");
    __builtin_amdgcn_sched_barrier(0);
    __builtin_amdgcn_s_setprio(1);
#pragma unroll
    for (int mm = 0; mm < 2; ++mm)
#pragma unroll
      for (int n = 2; n < 4; ++n)
#pragma unroll
        for (int ks = 0; ks < 2; ++ks)
          acc[mm][n] = __builtin_amdgcn_mfma_f32_16x16x32_bf16(af[mm][ks], bfr[n][ks],
                                                               acc[mm][n], 0, 0, 0);
    __builtin_amdgcn_s_setprio(0);
    __builtin_amdgcn_s_barrier();

    // ===== phase 2: A m2,m3 (4); stage Bq0,Bq1(t+2) =====
#pragma unroll
    for (int mm = 0; mm < 2; ++mm)
#pragma unroll
      for (int ks = 0; ks < 2; ++ks) {
        int rA = wr * 64 + (mm + 2) * 16 + lr;
        af[2 + mm][ks] = *(const bf16x8*)(Ac + rA * 128 + (((ks * 4 + lk) ^ (rA & 7)) << 4));
      }
    if (pf) { stageQ(Bb, Bn, t + 2, 0); stageQ(Bb, Bn, t + 2, 1); }
    __builtin_amdgcn_s_barrier();
    asm volatile("s_waitcnt lgkmcnt(0)" ::: "memory");
    __builtin_amdgcn_sched_barrier(0);
    __builtin_amdgcn_s_setprio(1);
#pragma unroll
    for (int mm = 0; mm < 2; ++mm)
#pragma unroll
      for (int n = 0; n < 2; ++n)
#pragma unroll
        for (int ks = 0; ks < 2; ++ks)
          acc[2 + mm][n] = __builtin_amdgcn_mfma_f32_16x16x32_bf16(af[2 + mm][ks], bfr[n][ks],
                                                                   acc[2 + mm][n], 0, 0, 0);
    __builtin_amdgcn_s_setprio(0);
    __builtin_amdgcn_s_barrier();

    // ===== phase 3: no reads; stage Bq2,Bq3(t+2); MFMA; counted boundary =====
    if (pf) { stageQ(Bb, Bn, t + 2, 2); stageQ(Bb, Bn, t + 2, 3); }
    __builtin_amdgcn_s_setprio(1);
#pragma unroll
    for (int mm = 0; mm < 2; ++mm)
#pragma unroll
      for (int n = 2; n < 4; ++n)
#pragma unroll
        for (int ks = 0; ks < 2; ++ks)
          acc[2 + mm][n] = __builtin_amdgcn_mfma_f32_16x16x32_bf16(af[2 + mm][ks], bfr[n][ks],
                                                                   acc[2 + mm][n], 0, 0, 0);
    __builtin_amdgcn_s_setprio(0);
    if (pf)
      asm volatile("s_waitcnt vmcnt(6)" ::: "memory");  // t+1 landed; t+2 in flight
    else if (t + 1 < NT)
      asm volatile("s_waitcnt vmcnt(0)" ::: "memory");  // tail drain
    __builtin_amdgcn_s_barrier();
    cur = (cur == 2) ? 0 : cur + 1;
  }
#pragma unroll
  for (int m = 0; m < 4; ++m)
#pragma unroll
    for (int n = 0; n < 4; ++n) {
      int row = brow + wr * 64 + m * 16 + lk * 4;
      int col = bcol + wc * 64 + n * 16 + lr;
#pragma unroll
      for (int j = 0; j < 4; ++j) {
        float v = acc[m][n][j];
        if constexpr (sizeof(OutT) == 2)
          C[(size_t)(row + j) * ldc + col] = (OutT)f2bf(v);
        else
          C[(size_t)(row + j) * ldc + col] = v;
      }
    }
}

// ---------- GEMM: C[M][ldc] = A[M][K] * BT[N][K]^T  (m97 structure, fallback) ----------
template <typename OutT>
__global__ __launch_bounds__(256) void gemm128_kernel(const ushort_t* __restrict__ A,
                                                      const ushort_t* __restrict__ BT,
                                                      OutT* __restrict__ C,
                                                      int M, int N, int K, int ldc) {
  __shared__ ushort_t As[128 * 32];
  __shared__ ushort_t Bs[128 * 32];
  int brow = blockIdx.y * 128, bcol = blockIdx.x * 128;
  int tid = threadIdx.x, w = tid >> 6, lane = tid & 63;
  int wr = w >> 1, wc = w & 1;
  int lr = lane & 15, lk = lane >> 4;
  f32x4 acc[4][4] = {};

  int srow = lane >> 2;
  int scol = (lane & 3) * 8;
  const ushort_t* Ab = A + (size_t)brow * K + scol;
  const ushort_t* Bb = BT + (size_t)bcol * K + scol;

  for (int kt = 0; kt < K; kt += 32) {
#pragma unroll
    for (int i = 0; i < 2; i++) {
      int seg = w * 2 + i;
      int row = seg * 16 + srow;
      load_lds16(Ab + (size_t)row * K + kt, (char*)As + seg * 1024);
      load_lds16(Bb + (size_t)row * K + kt, (char*)Bs + seg * 1024);
    }
    __syncthreads();
    bf16x8 af[4], bfr[4];
#pragma unroll
    for (int m = 0; m < 4; m++)
      af[m] = *(const bf16x8*)&As[(wr * 64 + m * 16 + lr) * 32 + lk * 8];
#pragma unroll
    for (int n = 0; n < 4; n++)
      bfr[n] = *(const bf16x8*)&Bs[(wc * 64 + n * 16 + lr) * 32 + lk * 8];
#pragma unroll
    for (int m = 0; m < 4; m++)
#pragma unroll
      for (int n = 0; n < 4; n++)
        acc[m][n] = __builtin_amdgcn_mfma_f32_16x16x32_bf16(af[m], bfr[n], acc[m][n], 0, 0, 0);
    __syncthreads();
  }
#pragma unroll
  for (int m = 0; m < 4; m++)
#pragma unroll
    for (int n = 0; n < 4; n++) {
      int row = brow + wr * 64 + m * 16 + lk * 4;
      int col = bcol + wc * 64 + n * 16 + lr;
#pragma unroll
      for (int j = 0; j < 4; j++) {
        float v = acc[m][n][j];
        if constexpr (sizeof(OutT) == 2)
          C[(size_t)(row + j) * ldc + col] = (OutT)f2bf(v);
        else
          C[(size_t)(row + j) * ldc + col] = v;
      }
    }
}

// ---------- gemmS: P[tile] = exp2(Q K^T) causal, materialized bf16 ----------
__global__ __launch_bounds__(256) void gemmS_kernel(const ushort_t* __restrict__ C1,
                                                    ushort_t* __restrict__ P) {
  int rem = blockIdx.x, rt = 0;
  while (rem > rt) { rem -= (rt + 1); rt++; }
  const int ct = rem;
  const int h = blockIdx.y, hk = h >> 2;

  __shared__ ushort_t As[128 * 32];
  __shared__ ushort_t Bs[128 * 32];
  int tid = threadIdx.x, w = tid >> 6, lane = tid & 63;
  int wr = w >> 1, wc = w & 1;
  int lr = lane & 15, lk = lane >> 4;
  f32x4 acc[4][4] = {};
  int srow = lane >> 2;
  int scol = (lane & 3) * 8;
  const ushort_t* Ab = C1 + (size_t)(rt * 128) * 6144 + h * 128 + scol;         // Q
  const ushort_t* Bb = C1 + (size_t)(ct * 128) * 6144 + 4096 + hk * 128 + scol; // K

  for (int kt = 0; kt < 128; kt += 32) {
#pragma unroll
    for (int i = 0; i < 2; i++) {
      int seg = w * 2 + i;
      int row = seg * 16 + srow;
      load_lds16(Ab + (size_t)row * 6144 + kt, (char*)As + seg * 1024);
      load_lds16(Bb + (size_t)row * 6144 + kt, (char*)Bs + seg * 1024);
    }
    __syncthreads();
    bf16x8 af[4], bfr[4];
#pragma unroll
    for (int m = 0; m < 4; m++)
      af[m] = *(const bf16x8*)&As[(wr * 64 + m * 16 + lr) * 32 + lk * 8];
#pragma unroll
    for (int n = 0; n < 4; n++)
      bfr[n] = *(const bf16x8*)&Bs[(wc * 64 + n * 16 + lr) * 32 + lk * 8];
#pragma unroll
    for (int m = 0; m < 4; m++)
#pragma unroll
      for (int n = 0; n < 4; n++)
        acc[m][n] = __builtin_amdgcn_mfma_f32_16x16x32_bf16(af[m], bfr[n], acc[m][n], 0, 0, 0);
    __syncthreads();
  }
  ushort_t* Pt = P + ((size_t)h * 136 + (size_t)(rt * (rt + 1) / 2) + ct) * 16384;
  const bool diag = (rt == ct);
#pragma unroll
  for (int m = 0; m < 4; m++)
#pragma unroll
    for (int n = 0; n < 4; n++) {
      int row = wr * 64 + m * 16 + lk * 4;
      int col = wc * 64 + n * 16 + lr;
#pragma unroll
      for (int j = 0; j < 4; j++) {
        float v = exp2_hw(acc[m][n][j]);
        if (diag && col > row + j) v = 0.f;
        Pt[(row + j) * 128 + col] = f2bf(v);
      }
    }
}

// ---------- gemmPV: AO[rt-tile] = (P * V) / rowsum(P) ----------
// Row sums fused via an all-ones MFMA (verified R13).
__global__ __launch_bounds__(256) void gemmPV_kernel(const ushort_t* __restrict__ P,
                                                     const ushort_t* __restrict__ VT,
                                                     ushort_t* __restrict__ AO) {
  const int h = blockIdx.x, hk = h >> 2;
  const int rt = 15 - (int)blockIdx.y;

  __shared__ ushort_t As[128 * 32];
  __shared__ ushort_t Bs[128 * 32];
  int tid = threadIdx.x, w = tid >> 6, lane = tid & 63;
  int wr = w >> 1, wc = w & 1;
  int lr = lane & 15, lk = lane >> 4;
  f32x4 acc[4][4] = {};
  f32x4 sacc[4] = {};
  bf16x8 ones;
#pragma unroll
  for (int j = 0; j < 8; j++) ones[j] = (short)0x3F80;  // bf16 1.0
  int srow = lane >> 2;
  int scol = (lane & 3) * 8;
  const ushort_t* Ph = P + ((size_t)h * 136 + (size_t)(rt * (rt + 1) / 2)) * 16384;
  const ushort_t* Vh = VT + (size_t)hk * 128 * 2048;

  const int nks = (rt + 1) * 4;
  for (int ks = 0; ks < nks; ks++) {
    int k0 = ks * 32;
    int ctk = k0 >> 7, kin = k0 & 127;
#pragma unroll
    for (int i = 0; i < 2; i++) {
      int seg = w * 2 + i;
      int row = seg * 16 + srow;
      load_lds16(Ph + (size_t)ctk * 16384 + (size_t)row * 128 + kin + scol,
                 (char*)As + seg * 1024);
      load_lds16(Vh + (size_t)row * 2048 + k0 + scol, (char*)Bs + seg * 1024);
    }
    __syncthreads();
    bf16x8 af[4], bfr[4];
#pragma unroll
    for (int m = 0; m < 4; m++)
      af[m] = *(const bf16x8*)&As[(wr * 64 + m * 16 + lr) * 32 + lk * 8];
#pragma unroll
    for (int n = 0; n < 4; n++)
      bfr[n] = *(const bf16x8*)&Bs[(wc * 64 + n * 16 + lr) * 32 + lk * 8];
#pragma unroll
    for (int m = 0; m < 4; m++) {
#pragma unroll
      for (int n = 0; n < 4; n++)
        acc[m][n] = __builtin_amdgcn_mfma_f32_16x16x32_bf16(af[m], bfr[n], acc[m][n], 0, 0, 0);
      sacc[m] = __builtin_amdgcn_mfma_f32_16x16x32_bf16(af[m], ones, sacc[m], 0, 0, 0);
    }
    __syncthreads();
  }
  const int q0 = rt * 128;
#pragma unroll
  for (int m = 0; m < 4; m++) {
    float invs[4];
#pragma unroll
    for (int j = 0; j < 4; j++) invs[j] = 1.0f / sacc[m][j];
#pragma unroll
    for (int n = 0; n < 4; n++) {
      int row = wr * 64 + m * 16 + lk * 4;
      int col = wc * 64 + n * 16 + lr;
#pragma unroll
      for (int j = 0; j < 4; j++) {
        float v = acc[m][n][j] * invs[j];
        AO[(size_t)(q0 + row + j) * 4096 + h * 128 + col] = f2bf(v);
      }
    }
  }
}

// ---------- flash attention (fallback when workspace too small) ----------
__global__ __launch_bounds__(256) void fattn_kernel(const ushort_t* __restrict__ C1,
                                                    const ushort_t* __restrict__ VT,
                                                    ushort_t* __restrict__ AO) {
  __shared__ ushort_t Pl[4][32][72];
  const int h = blockIdx.x, hk = h >> 2;
  const int qt = gridDim.y - 1 - blockIdx.y;
  const int tid = threadIdx.x, w = tid >> 6, lane = tid & 63;
  const int lq = lane & 31, hi = lane >> 5;
  const int qw0 = qt * 128 + w * 32;
  const int qabs = qw0 + lq;

  const ushort_t* Kb = C1 + 4096 + (size_t)hk * 128;
  const ushort_t* Vb = VT + (size_t)hk * 128 * 2048;

  bf16x8 qf[8];
  {
    const ushort_t* qrow = C1 + (size_t)qabs * 6144 + h * 128;
#pragma unroll
    for (int s = 0; s < 8; s++) qf[s] = *(const bf16x8*)(qrow + s * 16 + hi * 8);
  }
  f32x16 ot[4] = {};
  float mrow = -1e30f, ssum = 0.f;

  const int ktmax = (qw0 + 31) >> 6;
  for (int kt = 0; kt <= ktmax; kt++) {
    f32x16 sg[2] = {};
#pragma unroll
    for (int g = 0; g < 2; g++) {
      bf16x8 kfa[8];
      const ushort_t* krow = Kb + (size_t)(kt * 64 + g * 32 + lq) * 6144 + hi * 8;
#pragma unroll
      for (int s = 0; s < 8; s++) kfa[s] = *(const bf16x8*)(krow + s * 16);
#pragma unroll
      for (int s = 0; s < 8; s++)
        sg[g] = __builtin_amdgcn_mfma_f32_32x32x16_bf16(kfa[s], qf[s], sg[g], 0, 0, 0);
    }
    if (kt * 64 + 63 > qw0) {
#pragma unroll
      for (int g = 0; g < 2; g++)
#pragma unroll
        for (int r = 0; r < 16; r++) {
          int key = kt * 64 + g * 32 + (r & 3) + 8 * (r >> 2) + 4 * hi;
          if (key > qabs) sg[g][r] = -1e30f;
        }
    }
    float pm = -1e30f;
#pragma unroll
    for (int g = 0; g < 2; g++)
#pragma unroll
      for (int r = 0; r < 16; r++) pm = fmaxf(pm, sg[g][r]);
    pm = fmaxf(pm, __shfl_xor(pm, 32));
    float mnew = fmaxf(mrow, pm);
    float corr = exp2_hw(mrow - mnew);
    mrow = mnew;
    float ps = 0.f;
#pragma unroll
    for (int g = 0; g < 2; g++)
#pragma unroll
      for (int r = 0; r < 16; r++) {
        float e = exp2_hw(sg[g][r] - mnew);
        sg[g][r] = e;
        ps += e;
      }
    ps += __shfl_xor(ps, 32);
    ssum = ssum * corr + ps;
    if (!__all(corr == 1.f)) {
#pragma unroll
      for (int d = 0; d < 4; d++)
#pragma unroll
        for (int r = 0; r < 16; r++) ot[d][r] *= corr;
    }
#pragma unroll
    for (int g = 0; g < 2; g++)
#pragma unroll
      for (int rq = 0; rq < 4; rq++) {
        bf16x4 pk;
#pragma unroll
        for (int j = 0; j < 4; j++) pk[j] = (short)f2bf(sg[g][rq * 4 + j]);
        *(bf16x4*)&Pl[w][lq][g * 32 + rq * 8 + hi * 4] = pk;
      }
    asm volatile("s_waitcnt lgkmcnt(0)" ::: "memory");
    bf16x8 pf[4];
#pragma unroll
    for (int s = 0; s < 4; s++) pf[s] = *(const bf16x8*)&Pl[w][lq][s * 16 + hi * 8];
#pragma unroll
    for (int d = 0; d < 4; d++) {
      bf16x8 vfa[4];
      const ushort_t* vrow = Vb + (size_t)(d * 32 + lq) * 2048 + kt * 64 + hi * 8;
#pragma unroll
      for (int s = 0; s < 4; s++) vfa[s] = *(const bf16x8*)(vrow + s * 16);
#pragma unroll
      for (int s = 0; s < 4; s++)
        ot[d] = __builtin_amdgcn_mfma_f32_32x32x16_bf16(vfa[s], pf[s], ot[d], 0, 0, 0);
    }
  }
  const float inv = 1.0f / ssum;
  ushort_t* orow = AO + (size_t)qabs * 4096 + h * 128;
#pragma unroll
  for (int d = 0; d < 4; d++)
#pragma unroll
    for (int rq = 0; rq < 4; rq++) {
      bf16x4 ok;
#pragma unroll
      for (int j = 0; j < 4; j++) ok[j] = (short)f2bf(ot[d][rq * 4 + j] * inv);
      *(bf16x4*)(orow + d * 32 + rq * 8 + hi * 4) = ok;
    }
}

// ---------- launch ----------
extern "C" void kernel_launch(void* const* d_in, const int* in_sizes, int n_in,
                              void* d_out, int out_size, void* d_ws, size_t ws_size,
                              hipStream_t stream) {
  (void)in_sizes; (void)n_in; (void)out_size;
  const float* x    = (const float*)d_in[0];
  const float* wq   = (const float*)d_in[1];
  const float* wk   = (const float*)d_in[2];
  const float* wv   = (const float*)d_in[3];
  const float* wo   = (const float*)d_in[4];
  const float* cosb = (const float*)d_in[5];
  const float* sinb = (const float*)d_in[6];

  char* ws = (char*)d_ws;
  const bool fast = ws_size >= (215ull << 20);

  if (fast) {
    // layout (MiB): C1[0,24) VT[24,28) woT[28,60) xb[60,76) wT[76,124)
    //               P[60,196) (xb+wT dead after gemm1)  AO[196,212)
    ushort_t* C1  = (ushort_t*)(ws);
    ushort_t* VT  = (ushort_t*)(ws + ((size_t)24 << 20));
    ushort_t* woT = (ushort_t*)(ws + ((size_t)28 << 20));
    ushort_t* xb  = (ushort_t*)(ws + ((size_t)60 << 20));
    ushort_t* wT  = (ushort_t*)(ws + ((size_t)76 << 20));
    ushort_t* P   = (ushort_t*)(ws + ((size_t)60 << 20));
    ushort_t* AO  = (ushort_t*)(ws + ((size_t)196 << 20));

    cvt_x_kernel<<<4096, 256, 0, stream>>>(x, xb);
    tr_cvt_kernel<<<dim3(64, 64), 256, 0, stream>>>(wq, wT, 4096, 4096);
    tr_cvt_kernel<<<dim3(16, 64), 256, 0, stream>>>(wk, wT + (size_t)4096 * 4096, 4096, 1024);
    tr_cvt_kernel<<<dim3(16, 64), 256, 0, stream>>>(wv, wT + (size_t)5120 * 4096, 4096, 1024);
    tr_cvt_kernel<<<dim3(64, 64), 256, 0, stream>>>(wo, woT, 4096, 4096);

    // QKV projection: 256x192 p8 v2 (deep prefetch), grid 256, 2D-chunked XCD map
    gemmC_kernel<ushort_t><<<256, 512, 0, stream>>>(xb, wT, C1, 2048, 6144, 4096, 6144);
    rope_kernel<<<5120, 256, 0, stream>>>(C1, cosb, sinb);
    trv_kernel<<<dim3(16, 32), 256, 0, stream>>>(C1, VT);

    gemmS_kernel<<<dim3(136, 32), 256, 0, stream>>>(C1, P);
    gemmPV_kernel<<<dim3(32, 16), 256, 0, stream>>>(P, VT, AO);  // rowsum fused

    // output projection: 128x256 3-buf p8, grid 256, 2D-chunked XCD map
    gemmB_kernel<float><<<256, 512, 0, stream>>>(AO, woT, (float*)d_out, 2048, 4096, 4096, 4096);
  } else {
    // proven 92MiB layout + R7 fattn
    ushort_t* xb  = (ushort_t*)(ws);
    ushort_t* wT  = (ushort_t*)(ws + ((size_t)16 << 20));
    ushort_t* C1  = (ushort_t*)(ws + ((size_t)64 << 20));
    ushort_t* VT  = (ushort_t*)(ws + ((size_t)88 << 20));
    ushort_t* AO  = xb;
    ushort_t* woT = wT;

    cvt_x_kernel<<<4096, 256, 0, stream>>>(x, xb);
    tr_cvt_kernel<<<dim3(64, 64), 256, 0, stream>>>(wq, wT, 4096, 4096);
    tr_cvt_kernel<<<dim3(16, 64), 256, 0, stream>>>(wk, wT + (size_t)4096 * 4096, 4096, 1024);
    tr_cvt_kernel<<<dim3(16, 64), 256, 0, stream>>>(wv, wT + (size_t)5120 * 4096, 4096, 1024);
    gemm128_kernel<ushort_t><<<dim3(48, 16), 256, 0, stream>>>(xb, wT, C1, 2048, 6144, 4096, 6144);
    rope_kernel<<<5120, 256, 0, stream>>>(C1, cosb, sinb);
    trv_kernel<<<dim3(16, 32), 256, 0, stream>>>(C1, VT);
    tr_cvt_kernel<<<dim3(64, 64), 256, 0, stream>>>(wo, woT, 4096, 4096);
    fattn_kernel<<<dim3(32, 16), 256, 0, stream>>>(C1, VT, AO);
    gemm128_kernel<float><<<dim3(32, 16), 256, 0, stream>>>(AO, woT, (float*)d_out, 2048, 4096, 4096, 4096);
  }
}

// Round 16
// 371.991 us; speedup vs baseline: 1.1402x; 1.0037x over previous
//
#include <hip/hip_runtime.h>
#include <stdint.h>

typedef unsigned short ushort_t;
typedef short bf16x4 __attribute__((ext_vector_type(4)));
typedef short bf16x8 __attribute__((ext_vector_type(8)));
typedef float f32x4 __attribute__((ext_vector_type(4)));
typedef float f32x16 __attribute__((ext_vector_type(16)));
typedef float f32x4v __attribute__((ext_vector_type(4)));

// ---------- helpers ----------
__device__ __forceinline__ ushort_t f2bf(float f) {
  unsigned int u = __builtin_bit_cast(unsigned int, f);
  u += 0x7fffu + ((u >> 16) & 1u);
  return (ushort_t)(u >> 16);
}
__device__ __forceinline__ float bf2f(ushort_t h) {
  unsigned int u = ((unsigned int)h) << 16;
  return __builtin_bit_cast(float, u);
}
__device__ __forceinline__ float exp2_hw(float x) {
  return __builtin_amdgcn_exp2f(x);  // v_exp_f32: D = 2^S0
}
__device__ __forceinline__ void load_lds16(const void* g, void* l) {
  __builtin_amdgcn_global_load_lds(
      (const __attribute__((address_space(1))) void*)g,
      (__attribute__((address_space(3))) void*)l, 16, 0, 0);
}

// ---------- x fp32 -> bf16 ----------
__global__ __launch_bounds__(256) void cvt_x_kernel(const float* __restrict__ x,
                                                    ushort_t* __restrict__ xb) {
  int i = blockIdx.x * 256 + threadIdx.x;  // each thread: 8 elems
  const f32x4v* xv = (const f32x4v*)x;
  f32x4v a = xv[2 * i], b = xv[2 * i + 1];
  bf16x8 o;
  o[0] = (short)f2bf(a[0]); o[1] = (short)f2bf(a[1]);
  o[2] = (short)f2bf(a[2]); o[3] = (short)f2bf(a[3]);
  o[4] = (short)f2bf(b[0]); o[5] = (short)f2bf(b[1]);
  o[6] = (short)f2bf(b[2]); o[7] = (short)f2bf(b[3]);
  ((bf16x8*)xb)[i] = o;
}

// ---------- weight fp32 [R][C] -> bf16 transposed [C][R], vectorized ----------
__global__ __launch_bounds__(256) void tr_cvt_kernel(const float* __restrict__ src,
                                                     ushort_t* __restrict__ dst,
                                                     int R, int C) {
  __shared__ float tile[64][65];
  int r0 = blockIdx.y * 64, c0 = blockIdx.x * 64;
  int t = threadIdx.x;
#pragma unroll
  for (int i = 0; i < 4; i++) {
    int idx = t + i * 256;          // 0..1023
    int r = idx >> 4, c4 = idx & 15;
    f32x4v v = *(const f32x4v*)&src[(size_t)(r0 + r) * C + c0 + c4 * 4];
#pragma unroll
    for (int j = 0; j < 4; j++) tile[r][c4 * 4 + j] = v[j];
  }
  __syncthreads();
#pragma unroll
  for (int i = 0; i < 4; i++) {
    int idx = t + i * 256;
    int cr = idx >> 4, cg = idx & 15;
    bf16x4 o;
#pragma unroll
    for (int j = 0; j < 4; j++) o[j] = (short)f2bf(tile[cg * 4 + j][cr]);
    *(bf16x4*)&dst[(size_t)(c0 + cr) * R + r0 + cg * 4] = o;
  }
}

// ---------- RoPE in-place (fallback path only) ----------
__global__ __launch_bounds__(256) void rope_kernel(ushort_t* __restrict__ C1,
                                                   const float* __restrict__ cosb,
                                                   const float* __restrict__ sinb) {
  int idx = blockIdx.x * 256 + threadIdx.x;  // 2048 * 640
  int s = idx / 640;
  int col0 = (idx % 640) * 8;
  int i0 = (col0 & 127) >> 1;
  const float qs = (col0 < 4096) ? 0.12753055296570565f : 1.0f;  // scale*log2e
  ushort_t* p = C1 + (size_t)s * 6144 + col0;
  bf16x8 v = *(const bf16x8*)p;
  bf16x8 o;
  const float* cr = cosb + s * 64 + i0;
  const float* sr = sinb + s * 64 + i0;
#pragma unroll
  for (int j = 0; j < 4; j++) {
    float tr = bf2f((ushort_t)v[2 * j]);
    float ti = bf2f((ushort_t)v[2 * j + 1]);
    float c = cr[j], sn = sr[j];
    o[2 * j] = (short)f2bf((tr * c - ti * sn) * qs);
    o[2 * j + 1] = (short)f2bf((tr * sn + ti * c) * qs);
  }
  *(bf16x8*)p = o;
}

// ---------- V part of C1 -> VT [1024][2048] (row = hk*128+d, col = s) ----------
__global__ __launch_bounds__(256) void trv_kernel(const ushort_t* __restrict__ C1,
                                                  ushort_t* __restrict__ VT) {
  __shared__ ushort_t tile[64][65];
  int c0 = blockIdx.x * 64;  // within 1024
  int r0 = blockIdx.y * 64;  // within 2048
  int t = threadIdx.x;
#pragma unroll
  for (int i = 0; i < 16; i++) {
    int idx = t + i * 256;
    int r = idx >> 6, c = idx & 63;
    tile[r][c] = C1[(size_t)(r0 + r) * 6144 + 5120 + c0 + c];
  }
  __syncthreads();
#pragma unroll
  for (int i = 0; i < 16; i++) {
    int idx = t + i * 256;
    int cr = idx >> 6, cc = idx & 63;
    VT[(size_t)(c0 + cr) * 2048 + r0 + cc] = tile[cc][cr];
  }
}

// ---------- 2D-chunked XCD block mapping ----------
__device__ __forceinline__ void xcd_chunk_map(int id, int nby, int nbx,
                                              int& browi, int& bcoli) {
  const int xcd = id & 7;
  const int j = id >> 3;
  const int rch = nby >> 1, cch = nbx >> 2;  // chunk dims
  const int cr = xcd >> 2, cc = xcd & 3;     // chunk grid is 2 x 4
  const int r = j / cch, c = j % cch;
  browi = cr * rch + r;
  bcoli = cc * cch + c;
}

// ---------- GEMM 256x192 p8 v2 + fused RoPE epilogue (gemm1/QKV only) ----------
// Schedule verified R14/R15. Epilogue applies RoPE on f32 accs before bf16:
// pair (2i,2i+1) lives in adjacent lanes (col parity == lr parity), so the
// partner value comes from __shfl_xor(v,1). Q cols (<4096) additionally
// scaled by 1/sqrt(128)*log2e; K cols [4096,5120) roped unscaled; V cols
// (>=5120) untouched.
__global__ __launch_bounds__(512) void gemmC_kernel(const ushort_t* __restrict__ A,
                                                    const ushort_t* __restrict__ BT,
                                                    ushort_t* __restrict__ C,
                                                    int M, int N, int K, int ldc,
                                                    const float* __restrict__ cosb,
                                                    const float* __restrict__ sinb) {
  __shared__ ushort_t As[2][256 * 64];  // 64KB
  __shared__ ushort_t Bs[3][192 * 64];  // 72KB
  const int nbx = N / 192, nby = M >> 8;
  int browi, bcoli;
  xcd_chunk_map((int)blockIdx.x, nby, nbx, browi, bcoli);
  const int brow = browi << 8, bcol = bcoli * 192;
  const int tid = threadIdx.x, w = tid >> 6, lane = tid & 63;
  const int wr = w >> 2, wc = w & 3;
  const int lr = lane & 15, lk = lane >> 4;

  const ushort_t* Ab = A + (size_t)brow * K;
  const ushort_t* Bb = BT + (size_t)bcol * K;

  auto stageQ = [&](const ushort_t* gbase, char* lds, int t, int q) {
    int L = q * 512 + tid;
    int r = L >> 3, sc = L & 7;
    load_lds16(gbase + (size_t)r * K + (t << 6) + ((sc ^ (r & 7)) << 3), lds + L * 16);
  };

  f32x4 acc[8][3] = {};
  const int NT = K >> 6;

  // prologue: B(0)x3, A(0)q0,q2,q1,q3, B(1)x3
#pragma unroll
  for (int q = 0; q < 3; ++q) stageQ(Bb, (char*)&Bs[0][0], 0, q);
  stageQ(Ab, (char*)&As[0][0], 0, 0);
  stageQ(Ab, (char*)&As[0][0], 0, 2);
  stageQ(Ab, (char*)&As[0][0], 0, 1);
  stageQ(Ab, (char*)&As[0][0], 0, 3);
#pragma unroll
  for (int q = 0; q < 3; ++q) stageQ(Bb, (char*)&Bs[1][0], 1, q);
  asm volatile("s_waitcnt vmcnt(5)" ::: "memory");
  __builtin_amdgcn_s_barrier();

  int bcur = 0;
  for (int t = 0; t < NT; ++t) {
    const int c = t & 1;
    const char* Ac = (const char*)&As[c][0];
    const char* Bc = (const char*)&Bs[bcur][0];
    char* An = (char*)&As[c ^ 1][0];
    const int bnxt = (bcur + 2 >= 3) ? bcur - 1 : bcur + 2;
    char* Bn = (char*)&Bs[bnxt][0];
    const bool pfA = (t + 1 < NT), pfB = (t + 2 < NT);

    bf16x8 af[4][2], bfr[3][2];
    // ===== phase 0 =====
#pragma unroll
    for (int mm = 0; mm < 4; ++mm)
#pragma unroll
      for (int ks = 0; ks < 2; ++ks) {
        int rA = wr * 128 + mm * 16 + lr;
        af[mm][ks] = *(const bf16x8*)(Ac + rA * 128 + (((ks * 4 + lk) ^ (rA & 7)) << 4));
      }
#pragma unroll
    for (int n = 0; n < 2; ++n)
#pragma unroll
      for (int ks = 0; ks < 2; ++ks) {
        int rB = wc * 48 + n * 16 + lr;
        bfr[n][ks] = *(const bf16x8*)(Bc + rB * 128 + (((ks * 4 + lk) ^ (rB & 7)) << 4));
      }
    if (pfA) { stageQ(Ab, An, t + 1, 0); stageQ(Ab, An, t + 1, 2); }
    __builtin_amdgcn_s_barrier();
    asm volatile("s_waitcnt lgkmcnt(0)" ::: "memory");
    __builtin_amdgcn_sched_barrier(0);
    __builtin_amdgcn_s_setprio(1);
#pragma unroll
    for (int mm = 0; mm < 4; ++mm)
#pragma unroll
      for (int n = 0; n < 2; ++n)
#pragma unroll
        for (int ks = 0; ks < 2; ++ks)
          acc[mm][n] = __builtin_amdgcn_mfma_f32_16x16x32_bf16(af[mm][ks], bfr[n][ks],
                                                               acc[mm][n], 0, 0, 0);
    __builtin_amdgcn_s_setprio(0);
    __builtin_amdgcn_s_barrier();

    // ===== phase 1 =====
#pragma unroll
    for (int ks = 0; ks < 2; ++ks) {
      int rB = wc * 48 + 32 + lr;
      bfr[2][ks] = *(const bf16x8*)(Bc + rB * 128 + (((ks * 4 + lk) ^ (rB & 7)) << 4));
    }
    if (pfA) { stageQ(Ab, An, t + 1, 1); stageQ(Ab, An, t + 1, 3); }
    __builtin_amdgcn_s_barrier();
    asm volatile("s_waitcnt lgkmcnt(0)" ::: "memory");
    __builtin_amdgcn_sched_barrier(0);
    __builtin_amdgcn_s_setprio(1);
#pragma unroll
    for (int mm = 0; mm < 4; ++mm)
#pragma unroll
      for (int ks = 0; ks < 2; ++ks)
        acc[mm][2] = __builtin_amdgcn_mfma_f32_16x16x32_bf16(af[mm][ks], bfr[2][ks],
                                                             acc[mm][2], 0, 0, 0);
    __builtin_amdgcn_s_setprio(0);
    asm volatile("s_waitcnt vmcnt(7)" ::: "memory");
    __builtin_amdgcn_s_barrier();

    // ===== phase 2 =====
#pragma unroll
    for (int mm = 0; mm < 4; ++mm)
#pragma unroll
      for (int ks = 0; ks < 2; ++ks) {
        int rA = wr * 128 + 64 + mm * 16 + lr;
        af[mm][ks] = *(const bf16x8*)(Ac + rA * 128 + (((ks * 4 + lk) ^ (rA & 7)) << 4));
      }
    if (pfB) { stageQ(Bb, Bn, t + 2, 0); stageQ(Bb, Bn, t + 2, 1); }
    __builtin_amdgcn_s_barrier();
    asm volatile("s_waitcnt lgkmcnt(0)" ::: "memory");
    __builtin_amdgcn_sched_barrier(0);
    __builtin_amdgcn_s_setprio(1);
#pragma unroll
    for (int mm = 0; mm < 4; ++mm)
#pragma unroll
      for (int n = 0; n < 2; ++n)
#pragma unroll
        for (int ks = 0; ks < 2; ++ks)
          acc[4 + mm][n] = __builtin_amdgcn_mfma_f32_16x16x32_bf16(af[mm][ks], bfr[n][ks],
                                                                   acc[4 + mm][n], 0, 0, 0);
    __builtin_amdgcn_s_setprio(0);
    __builtin_amdgcn_s_barrier();

    // ===== phase 3 =====
    if (pfB) stageQ(Bb, Bn, t + 2, 2);
    __builtin_amdgcn_s_setprio(1);
#pragma unroll
    for (int mm = 0; mm < 4; ++mm)
#pragma unroll
      for (int ks = 0; ks < 2; ++ks)
        acc[4 + mm][2] = __builtin_amdgcn_mfma_f32_16x16x32_bf16(af[mm][ks], bfr[2][ks],
                                                                 acc[4 + mm][2], 0, 0, 0);
    __builtin_amdgcn_s_setprio(0);
    if (pfB)
      asm volatile("s_waitcnt vmcnt(5)" ::: "memory");
    else
      asm volatile("s_waitcnt vmcnt(0)" ::: "memory");
    __builtin_amdgcn_s_barrier();
    bcur = (bcur + 1 == 3) ? 0 : bcur + 1;
  }
  // epilogue with fused RoPE (pairs via lane^1 shuffle)
  const float QS = 0.12753055296570565f;  // 1/sqrt(128)*log2e
#pragma unroll
  for (int m = 0; m < 8; ++m)
#pragma unroll
    for (int n = 0; n < 3; ++n) {
      int row = brow + wr * 128 + m * 16 + lk * 4;
      int col = bcol + wc * 48 + n * 16 + lr;
#pragma unroll
      for (int j = 0; j < 4; ++j) {
        float v = acc[m][n][j];
        float p = __shfl_xor(v, 1, 64);  // adjacent column, same row
        float outv;
        if (col < 5120) {
          int i0 = (col & 127) >> 1;
          int r = row + j;
          float cv = cosb[r * 64 + i0], sv = sinb[r * 64 + i0];
          float ro = v * cv + ((col & 1) ? p * sv : -p * sv);
          outv = (col < 4096) ? ro * QS : ro;
        } else {
          outv = v;
        }
        C[(size_t)(row + j) * ldc + col] = f2bf(outv);
      }
    }
}

// ---------- GEMM 256x128 2-phase p8 (gemm2): uniform 16-MFMA phases ----------
// C[M][ldc] = A[M][K]*BT[N][K]^T. M%256==0, N%128==0, K%64==0, K/64>=3,
// grid = (M/256)*(N/128), grid%8==0. 512 thr = 8 waves (2Mr x 4Nc), per-wave
// 128x32 out (acc[8][2]). LDS 144KB = 3 x (A 32KB + B 16KB), depth-2 staging
// (6 quarter-loads per tile: phA {Aq0,Aq2,Bq0}, phB {Aq1,Aq3,Bq1} -> t+2).
// FIFO: at end-of-tile boundary, outstanding = t+1(6)+t+2(6); vmcnt(6) drains
// t+1 -> tile t+1 fully resident before its phase A; NO mid-tile waits.
// Only 4 barriers + 1 counted vmcnt per K-tile (vs 8+2 in the 4-phase form).
template <typename OutT>
__global__ __launch_bounds__(512) void gemmD_kernel(const ushort_t* __restrict__ A,
                                                    const ushort_t* __restrict__ BT,
                                                    OutT* __restrict__ C,
                                                    int M, int N, int K, int ldc) {
  __shared__ ushort_t As[3][256 * 64];  // 96KB
  __shared__ ushort_t Bs[3][128 * 64];  // 48KB
  const int nbx = N >> 7, nby = M >> 8;
  int browi, bcoli;
  xcd_chunk_map((int)blockIdx.x, nby, nbx, browi, bcoli);
  const int brow = browi << 8, bcol = bcoli << 7;
  const int tid = threadIdx.x, w = tid >> 6, lane = tid & 63;
  const int wr = w >> 2, wc = w & 3;
  const int lr = lane & 15, lk = lane >> 4;

  const ushort_t* Ab = A + (size_t)brow * K;
  const ushort_t* Bb = BT + (size_t)bcol * K;

  auto stageQ = [&](const ushort_t* gbase, char* lds, int t, int q) {
    int L = q * 512 + tid;
    int r = L >> 3, sc = L & 7;
    load_lds16(gbase + (size_t)r * K + (t << 6) + ((sc ^ (r & 7)) << 3), lds + L * 16);
  };
  auto stageTile = [&](int t, int buf) {  // 6 loads: A q0..q3 + B q0,q1
#pragma unroll
    for (int q = 0; q < 4; ++q) stageQ(Ab, (char*)&As[buf][0], t, q);
#pragma unroll
    for (int q = 0; q < 2; ++q) stageQ(Bb, (char*)&Bs[buf][0], t, q);
  };

  f32x4 acc[8][2] = {};
  const int NT = K >> 6;

  stageTile(0, 0);
  stageTile(1, 1);
  asm volatile("s_waitcnt vmcnt(6)" ::: "memory");  // tile0 landed, tile1 in flight
  __builtin_amdgcn_s_barrier();

  int cur = 0;
  for (int t = 0; t < NT; ++t) {
    const char* Ac = (const char*)&As[cur][0];
    const char* Bc = (const char*)&Bs[cur][0];
    const int nxt = (cur + 2 >= 3) ? cur - 1 : cur + 2;  // (t+2)%3
    char* An = (char*)&As[nxt][0];
    char* Bn = (char*)&Bs[nxt][0];
    const bool pf = (t + 2 < NT);

    bf16x8 af[4][2], bfr[2][2];
    // ===== phase A: A mh0 (8 reads) + B n0,n1 (4 reads); stage Aq0,Aq2,Bq0 =====
#pragma unroll
    for (int mm = 0; mm < 4; ++mm)
#pragma unroll
      for (int ks = 0; ks < 2; ++ks) {
        int rA = wr * 128 + mm * 16 + lr;
        af[mm][ks] = *(const bf16x8*)(Ac + rA * 128 + (((ks * 4 + lk) ^ (rA & 7)) << 4));
      }
#pragma unroll
    for (int n = 0; n < 2; ++n)
#pragma unroll
      for (int ks = 0; ks < 2; ++ks) {
        int rB = wc * 32 + n * 16 + lr;
        bfr[n][ks] = *(const bf16x8*)(Bc + rB * 128 + (((ks * 4 + lk) ^ (rB & 7)) << 4));
      }
    if (pf) { stageQ(Ab, An, t + 2, 0); stageQ(Ab, An, t + 2, 2); stageQ(Bb, Bn, t + 2, 0); }
    __builtin_amdgcn_s_barrier();
    asm volatile("s_waitcnt lgkmcnt(0)" ::: "memory");
    __builtin_amdgcn_sched_barrier(0);
    __builtin_amdgcn_s_setprio(1);
#pragma unroll
    for (int mm = 0; mm < 4; ++mm)
#pragma unroll
      for (int n = 0; n < 2; ++n)
#pragma unroll
        for (int ks = 0; ks < 2; ++ks)
          acc[mm][n] = __builtin_amdgcn_mfma_f32_16x16x32_bf16(af[mm][ks], bfr[n][ks],
                                                               acc[mm][n], 0, 0, 0);
    __builtin_amdgcn_s_setprio(0);
    __builtin_amdgcn_s_barrier();

    // ===== phase B: A mh1 (8 reads); stage Aq1,Aq3,Bq1; counted boundary =====
#pragma unroll
    for (int mm = 0; mm < 4; ++mm)
#pragma unroll
      for (int ks = 0; ks < 2; ++ks) {
        int rA = wr * 128 + 64 + mm * 16 + lr;
        af[mm][ks] = *(const bf16x8*)(Ac + rA * 128 + (((ks * 4 + lk) ^ (rA & 7)) << 4));
      }
    if (pf) { stageQ(Ab, An, t + 2, 1); stageQ(Ab, An, t + 2, 3); stageQ(Bb, Bn, t + 2, 1); }
    __builtin_amdgcn_s_barrier();
    asm volatile("s_waitcnt lgkmcnt(0)" ::: "memory");
    __builtin_amdgcn_sched_barrier(0);
    __builtin_amdgcn_s_setprio(1);
#pragma unroll
    for (int mm = 0; mm < 4; ++mm)
#pragma unroll
      for (int n = 0; n < 2; ++n)
#pragma unroll
        for (int ks = 0; ks < 2; ++ks)
          acc[4 + mm][n] = __builtin_amdgcn_mfma_f32_16x16x32_bf16(af[mm][ks], bfr[n][ks],
                                                                   acc[4 + mm][n], 0, 0, 0);
    __builtin_amdgcn_s_setprio(0);
    if (pf)
      asm volatile("s_waitcnt vmcnt(6)" ::: "memory");  // t+1 landed; t+2 in flight
    else if (t + 1 < NT)
      asm volatile("s_waitcnt vmcnt(0)" ::: "memory");  // tail drain
    __builtin_amdgcn_s_barrier();
    cur = (cur == 2) ? 0 : cur + 1;
  }
  // epilogue
#pragma unroll
  for (int m = 0; m < 8; ++m)
#pragma unroll
    for (int n = 0; n < 2; ++n) {
      int row = brow + wr * 128 + m * 16 + lk * 4;
      int col = bcol + wc * 32 + n * 16 + lr;
#pragma unroll
      for (int j = 0; j < 4; ++j) {
        float v = acc[m][n][j];
        if constexpr (sizeof(OutT) == 2)
          C[(size_t)(row + j) * ldc + col] = (OutT)f2bf(v);
        else
          C[(size_t)(row + j) * ldc + col] = v;
      }
    }
}

// ---------- GEMM: C[M][ldc] = A[M][K] * BT[N][K]^T  (m97 structure, fallback) ----------
template <typename OutT>
__global__ __launch_bounds__(256) void gemm128_kernel(const ushort_t* __restrict__ A,
                                                      const ushort_t* __restrict__ BT,
                                                      OutT* __restrict__ C,
                                                      int M, int N, int K, int ldc) {
  __shared__ ushort_t As[128 * 32];
  __shared__ ushort_t Bs[128 * 32];
  int brow = blockIdx.y * 128, bcol = blockIdx.x * 128;
  int tid = threadIdx.x, w = tid >> 6, lane = tid & 63;
  int wr = w >> 1, wc = w & 1;
  int lr = lane & 15, lk = lane >> 4;
  f32x4 acc[4][4] = {};

  int srow = lane >> 2;
  int scol = (lane & 3) * 8;
  const ushort_t* Ab = A + (size_t)brow * K + scol;
  const ushort_t* Bb = BT + (size_t)bcol * K + scol;

  for (int kt = 0; kt < K; kt += 32) {
#pragma unroll
    for (int i = 0; i < 2; i++) {
      int seg = w * 2 + i;
      int row = seg * 16 + srow;
      load_lds16(Ab + (size_t)row * K + kt, (char*)As + seg * 1024);
      load_lds16(Bb + (size_t)row * K + kt, (char*)Bs + seg * 1024);
    }
    __syncthreads();
    bf16x8 af[4], bfr[4];
#pragma unroll
    for (int m = 0; m < 4; m++)
      af[m] = *(const bf16x8*)&As[(wr * 64 + m * 16 + lr) * 32 + lk * 8];
#pragma unroll
    for (int n = 0; n < 4; n++)
      bfr[n] = *(const bf16x8*)&Bs[(wc * 64 + n * 16 + lr) * 32 + lk * 8];
#pragma unroll
    for (int m = 0; m < 4; m++)
#pragma unroll
      for (int n = 0; n < 4; n++)
        acc[m][n] = __builtin_amdgcn_mfma_f32_16x16x32_bf16(af[m], bfr[n], acc[m][n], 0, 0, 0);
    __syncthreads();
  }
#pragma unroll
  for (int m = 0; m < 4; m++)
#pragma unroll
    for (int n = 0; n < 4; n++) {
      int row = brow + wr * 64 + m * 16 + lk * 4;
      int col = bcol + wc * 64 + n * 16 + lr;
#pragma unroll
      for (int j = 0; j < 4; j++) {
        float v = acc[m][n][j];
        if constexpr (sizeof(OutT) == 2)
          C[(size_t)(row + j) * ldc + col] = (OutT)f2bf(v);
        else
          C[(size_t)(row + j) * ldc + col] = v;
      }
    }
}

// ---------- gemmS: P[tile] = exp2(Q K^T) causal, materialized bf16 ----------
__global__ __launch_bounds__(256) void gemmS_kernel(const ushort_t* __restrict__ C1,
                                                    ushort_t* __restrict__ P) {
  int rem = blockIdx.x, rt = 0;
  while (rem > rt) { rem -= (rt + 1); rt++; }
  const int ct = rem;
  const int h = blockIdx.y, hk = h >> 2;

  __shared__ ushort_t As[128 * 32];
  __shared__ ushort_t Bs[128 * 32];
  int tid = threadIdx.x, w = tid >> 6, lane = tid & 63;
  int wr = w >> 1, wc = w & 1;
  int lr = lane & 15, lk = lane >> 4;
  f32x4 acc[4][4] = {};
  int srow = lane >> 2;
  int scol = (lane & 3) * 8;
  const ushort_t* Ab = C1 + (size_t)(rt * 128) * 6144 + h * 128 + scol;         // Q
  const ushort_t* Bb = C1 + (size_t)(ct * 128) * 6144 + 4096 + hk * 128 + scol; // K

  for (int kt = 0; kt < 128; kt += 32) {
#pragma unroll
    for (int i = 0; i < 2; i++) {
      int seg = w * 2 + i;
      int row = seg * 16 + srow;
      load_lds16(Ab + (size_t)row * 6144 + kt, (char*)As + seg * 1024);
      load_lds16(Bb + (size_t)row * 6144 + kt, (char*)Bs + seg * 1024);
    }
    __syncthreads();
    bf16x8 af[4], bfr[4];
#pragma unroll
    for (int m = 0; m < 4; m++)
      af[m] = *(const bf16x8*)&As[(wr * 64 + m * 16 + lr) * 32 + lk * 8];
#pragma unroll
    for (int n = 0; n < 4; n++)
      bfr[n] = *(const bf16x8*)&Bs[(wc * 64 + n * 16 + lr) * 32 + lk * 8];
#pragma unroll
    for (int m = 0; m < 4; m++)
#pragma unroll
      for (int n = 0; n < 4; n++)
        acc[m][n] = __builtin_amdgcn_mfma_f32_16x16x32_bf16(af[m], bfr[n], acc[m][n], 0, 0, 0);
    __syncthreads();
  }
  ushort_t* Pt = P + ((size_t)h * 136 + (size_t)(rt * (rt + 1) / 2) + ct) * 16384;
  const bool diag = (rt == ct);
#pragma unroll
  for (int m = 0; m < 4; m++)
#pragma unroll
    for (int n = 0; n < 4; n++) {
      int row = wr * 64 + m * 16 + lk * 4;
      int col = wc * 64 + n * 16 + lr;
#pragma unroll
      for (int j = 0; j < 4; j++) {
        float v = exp2_hw(acc[m][n][j]);
        if (diag && col > row + j) v = 0.f;
        Pt[(row + j) * 128 + col] = f2bf(v);
      }
    }
}

// ---------- gemmPV: AO[rt-tile] = (P * V) / rowsum(P), rowsum via ones-MFMA ----------
__global__ __launch_bounds__(256) void gemmPV_kernel(const ushort_t* __restrict__ P,
                                                     const ushort_t* __restrict__ VT,
                                                     ushort_t* __restrict__ AO) {
  const int h = blockIdx.x, hk = h >> 2;
  const int rt = 15 - (int)blockIdx.y;

  __shared__ ushort_t As[128 * 32];
  __shared__ ushort_t Bs[128 * 32];
  int tid = threadIdx.x, w = tid >> 6, lane = tid & 63;
  int wr = w >> 1, wc = w & 1;
  int lr = lane & 15, lk = lane >> 4;
  f32x4 acc[4][4] = {};
  f32x4 sacc[4] = {};
  bf16x8 ones;
#pragma unroll
  for (int j = 0; j < 8; j++) ones[j] = (short)0x3F80;  // bf16 1.0
  int srow = lane >> 2;
  int scol = (lane & 3) * 8;
  const ushort_t* Ph = P + ((size_t)h * 136 + (size_t)(rt * (rt + 1) / 2)) * 16384;
  const ushort_t* Vh = VT + (size_t)hk * 128 * 2048;

  const int nks = (rt + 1) * 4;
  for (int ks = 0; ks < nks; ks++) {
    int k0 = ks * 32;
    int ctk = k0 >> 7, kin = k0 & 127;
#pragma unroll
    for (int i = 0; i < 2; i++) {
      int seg = w * 2 + i;
      int row = seg * 16 + srow;
      load_lds16(Ph + (size_t)ctk * 16384 + (size_t)row * 128 + kin + scol,
                 (char*)As + seg * 1024);
      load_lds16(Vh + (size_t)row * 2048 + k0 + scol, (char*)Bs + seg * 1024);
    }
    __syncthreads();
    bf16x8 af[4], bfr[4];
#pragma unroll
    for (int m = 0; m < 4; m++)
      af[m] = *(const bf16x8*)&As[(wr * 64 + m * 16 + lr) * 32 + lk * 8];
#pragma unroll
    for (int n = 0; n < 4; n++)
      bfr[n] = *(const bf16x8*)&Bs[(wc * 64 + n * 16 + lr) * 32 + lk * 8];
#pragma unroll
    for (int m = 0; m < 4; m++) {
#pragma unroll
      for (int n = 0; n < 4; n++)
        acc[m][n] = __builtin_amdgcn_mfma_f32_16x16x32_bf16(af[m], bfr[n], acc[m][n], 0, 0, 0);
      sacc[m] = __builtin_amdgcn_mfma_f32_16x16x32_bf16(af[m], ones, sacc[m], 0, 0, 0);
    }
    __syncthreads();
  }
  const int q0 = rt * 128;
#pragma unroll
  for (int m = 0; m < 4; m++) {
    float invs[4];
#pragma unroll
    for (int j = 0; j < 4; j++) invs[j] = 1.0f / sacc[m][j];
#pragma unroll
    for (int n = 0; n < 4; n++) {
      int row = wr * 64 + m * 16 + lk * 4;
      int col = wc * 64 + n * 16 + lr;
#pragma unroll
      for (int j = 0; j < 4; j++) {
        float v = acc[m][n][j] * invs[j];
        AO[(size_t)(q0 + row + j) * 4096 + h * 128 + col] = f2bf(v);
      }
    }
  }
}

// ---------- flash attention (fallback when workspace too small) ----------
__global__ __launch_bounds__(256) void fattn_kernel(const ushort_t* __restrict__ C1,
                                                    const ushort_t* __restrict__ VT,
                                                    ushort_t* __restrict__ AO) {
  __shared__ ushort_t Pl[4][32][72];
  const int h = blockIdx.x, hk = h >> 2;
  const int qt = gridDim.y - 1 - blockIdx.y;
  const int tid = threadIdx.x, w = tid >> 6, lane = tid & 63;
  const int lq = lane & 31, hi = lane >> 5;
  const int qw0 = qt * 128 + w * 32;
  const int qabs = qw0 + lq;

  const ushort_t* Kb = C1 + 4096 + (size_t)hk * 128;
  const ushort_t* Vb = VT + (size_t)hk * 128 * 2048;

  bf16x8 qf[8];
  {
    const ushort_t* qrow = C1 + (size_t)qabs * 6144 + h * 128;
#pragma unroll
    for (int s = 0; s < 8; s++) qf[s] = *(const bf16x8*)(qrow + s * 16 + hi * 8);
  }
  f32x16 ot[4] = {};
  float mrow = -1e30f, ssum = 0.f;

  const int ktmax = (qw0 + 31) >> 6;
  for (int kt = 0; kt <= ktmax; kt++) {
    f32x16 sg[2] = {};
#pragma unroll
    for (int g = 0; g < 2; g++) {
      bf16x8 kfa[8];
      const ushort_t* krow = Kb + (size_t)(kt * 64 + g * 32 + lq) * 6144 + hi * 8;
#pragma unroll
      for (int s = 0; s < 8; s++) kfa[s] = *(const bf16x8*)(krow + s * 16);
#pragma unroll
      for (int s = 0; s < 8; s++)
        sg[g] = __builtin_amdgcn_mfma_f32_32x32x16_bf16(kfa[s], qf[s], sg[g], 0, 0, 0);
    }
    if (kt * 64 + 63 > qw0) {
#pragma unroll
      for (int g = 0; g < 2; g++)
#pragma unroll
        for (int r = 0; r < 16; r++) {
          int key = kt * 64 + g * 32 + (r & 3) + 8 * (r >> 2) + 4 * hi;
          if (key > qabs) sg[g][r] = -1e30f;
        }
    }
    float pm = -1e30f;
#pragma unroll
    for (int g = 0; g < 2; g++)
#pragma unroll
      for (int r = 0; r < 16; r++) pm = fmaxf(pm, sg[g][r]);
    pm = fmaxf(pm, __shfl_xor(pm, 32));
    float mnew = fmaxf(mrow, pm);
    float corr = exp2_hw(mrow - mnew);
    mrow = mnew;
    float ps = 0.f;
#pragma unroll
    for (int g = 0; g < 2; g++)
#pragma unroll
      for (int r = 0; r < 16; r++) {
        float e = exp2_hw(sg[g][r] - mnew);
        sg[g][r] = e;
        ps += e;
      }
    ps += __shfl_xor(ps, 32);
    ssum = ssum * corr + ps;
    if (!__all(corr == 1.f)) {
#pragma unroll
      for (int d = 0; d < 4; d++)
#pragma unroll
        for (int r = 0; r < 16; r++) ot[d][r] *= corr;
    }
#pragma unroll
    for (int g = 0; g < 2; g++)
#pragma unroll
      for (int rq = 0; rq < 4; rq++) {
        bf16x4 pk;
#pragma unroll
        for (int j = 0; j < 4; j++) pk[j] = (short)f2bf(sg[g][rq * 4 + j]);
        *(bf16x4*)&Pl[w][lq][g * 32 + rq * 8 + hi * 4] = pk;
      }
    asm volatile("s_waitcnt lgkmcnt(0)" ::: "memory");
    bf16x8 pf[4];
#pragma unroll
    for (int s = 0; s < 4; s++) pf[s] = *(const bf16x8*)&Pl[w][lq][s * 16 + hi * 8];
#pragma unroll
    for (int d = 0; d < 4; d++) {
      bf16x8 vfa[4];
      const ushort_t* vrow = Vb + (size_t)(d * 32 + lq) * 2048 + kt * 64 + hi * 8;
#pragma unroll
      for (int s = 0; s < 4; s++) vfa[s] = *(const bf16x8*)(vrow + s * 16);
#pragma unroll
      for (int s = 0; s < 4; s++)
        ot[d] = __builtin_amdgcn_mfma_f32_32x32x16_bf16(vfa[s], pf[s], ot[d], 0, 0, 0);
    }
  }
  const float inv = 1.0f / ssum;
  ushort_t* orow = AO + (size_t)qabs * 4096 + h * 128;
#pragma unroll
  for (int d = 0; d < 4; d++)
#pragma unroll
    for (int rq = 0; rq < 4; rq++) {
      bf16x4 ok;
#pragma unroll
      for (int j = 0; j < 4; j++) ok[j] = (short)f2bf(ot[d][rq * 4 + j] * inv);
      *(bf16x4*)(orow + d * 32 + rq * 8 + hi * 4) = ok;
    }
}

// ---------- launch ----------
extern "C" void kernel_launch(void* const* d_in, const int* in_sizes, int n_in,
                              void* d_out, int out_size, void* d_ws, size_t ws_size,
                              hipStream_t stream) {
  (void)in_sizes; (void)n_in; (void)out_size;
  const float* x    = (const float*)d_in[0];
  const float* wq   = (const float*)d_in[1];
  const float* wk   = (const float*)d_in[2];
  const float* wv   = (const float*)d_in[3];
  const float* wo   = (const float*)d_in[4];
  const float* cosb = (const float*)d_in[5];
  const float* sinb = (const float*)d_in[6];

  char* ws = (char*)d_ws;
  const bool fast = ws_size >= (215ull << 20);

  if (fast) {
    // layout (MiB): C1[0,24) VT[24,28) woT[28,60) xb[60,76) wT[76,124)
    //               P[60,196) (xb+wT dead after gemm1)  AO[196,212)
    ushort_t* C1  = (ushort_t*)(ws);
    ushort_t* VT  = (ushort_t*)(ws + ((size_t)24 << 20));
    ushort_t* woT = (ushort_t*)(ws + ((size_t)28 << 20));
    ushort_t* xb  = (ushort_t*)(ws + ((size_t)60 << 20));
    ushort_t* wT  = (ushort_t*)(ws + ((size_t)76 << 20));
    ushort_t* P   = (ushort_t*)(ws + ((size_t)60 << 20));
    ushort_t* AO  = (ushort_t*)(ws + ((size_t)196 << 20));

    cvt_x_kernel<<<4096, 256, 0, stream>>>(x, xb);
    tr_cvt_kernel<<<dim3(64, 64), 256, 0, stream>>>(wq, wT, 4096, 4096);
    tr_cvt_kernel<<<dim3(16, 64), 256, 0, stream>>>(wk, wT + (size_t)4096 * 4096, 4096, 1024);
    tr_cvt_kernel<<<dim3(16, 64), 256, 0, stream>>>(wv, wT + (size_t)5120 * 4096, 4096, 1024);
    tr_cvt_kernel<<<dim3(64, 64), 256, 0, stream>>>(wo, woT, 4096, 4096);

    // QKV projection + fused RoPE: 256x192 p8 v2, grid 256, 2D-chunked XCD map
    gemmC_kernel<<<256, 512, 0, stream>>>(xb, wT, C1, 2048, 6144, 4096, 6144, cosb, sinb);
    trv_kernel<<<dim3(16, 32), 256, 0, stream>>>(C1, VT);

    gemmS_kernel<<<dim3(136, 32), 256, 0, stream>>>(C1, P);
    gemmPV_kernel<<<dim3(32, 16), 256, 0, stream>>>(P, VT, AO);  // rowsum fused

    // output projection: 256x128 2-phase p8, grid 8x32 = 256, 2D-chunked XCD map
    gemmD_kernel<float><<<256, 512, 0, stream>>>(AO, woT, (float*)d_out, 2048, 4096, 4096, 4096);
  } else {
    // proven 92MiB layout + R7 fattn
    ushort_t* xb  = (ushort_t*)(ws);
    ushort_t* wT  = (ushort_t*)(ws + ((size_t)16 << 20));
    ushort_t* C1  = (ushort_t*)(ws + ((size_t)64 << 20));
    ushort_t* VT  = (ushort_t*)(ws + ((size_t)88 << 20));
    ushort_t* AO  = xb;
    ushort_t* woT = wT;

    cvt_x_kernel<<<4096, 256, 0, stream>>>(x, xb);
    tr_cvt_kernel<<<dim3(64, 64), 256, 0, stream>>>(wq, wT, 4096, 4096);
    tr_cvt_kernel<<<dim3(16, 64), 256, 0, stream>>>(wk, wT + (size_t)4096 * 4096, 4096, 1024);
    tr_cvt_kernel<<<dim3(16, 64), 256, 0, stream>>>(wv, wT + (size_t)5120 * 4096, 4096, 1024);
    gemm128_kernel<ushort_t><<<dim3(48, 16), 256, 0, stream>>>(xb, wT, C1, 2048, 6144, 4096, 6144);
    rope_kernel<<<5120, 256, 0, stream>>>(C1, cosb, sinb);
    trv_kernel<<<dim3(16, 32), 256, 0, stream>>>(C1, VT);
    tr_cvt_kernel<<<dim3(64, 64), 256, 0, stream>>>(wo, woT, 4096, 4096);
    fattn_kernel<<<dim3(32, 16), 256, 0, stream>>>(C1, VT, AO);
    gemm128_kernel<float><<<dim3(32, 16), 256, 0, stream>>>(AO, woT, (float*)d_out, 2048, 4096, 4096, 4096);
  }
}

// Round 17
// 355.318 us; speedup vs baseline: 1.1938x; 1.0469x over previous
//
#include <hip/hip_runtime.h>
#include <stdint.h>

typedef unsigned short ushort_t;
typedef short bf16x4 __attribute__((ext_vector_type(4)));
typedef short bf16x8 __attribute__((ext_vector_type(8)));
typedef float f32x4 __attribute__((ext_vector_type(4)));
typedef float f32x16 __attribute__((ext_vector_type(16)));
typedef float f32x4v __attribute__((ext_vector_type(4)));

// ---------- helpers ----------
__device__ __forceinline__ ushort_t f2bf(float f) {
  unsigned int u = __builtin_bit_cast(unsigned int, f);
  u += 0x7fffu + ((u >> 16) & 1u);
  return (ushort_t)(u >> 16);
}
__device__ __forceinline__ float bf2f(ushort_t h) {
  unsigned int u = ((unsigned int)h) << 16;
  return __builtin_bit_cast(float, u);
}
__device__ __forceinline__ float exp2_hw(float x) {
  return __builtin_amdgcn_exp2f(x);  // v_exp_f32: D = 2^S0
}
__device__ __forceinline__ void load_lds16(const void* g, void* l) {
  __builtin_amdgcn_global_load_lds(
      (const __attribute__((address_space(1))) void*)g,
      (__attribute__((address_space(3))) void*)l, 16, 0, 0);
}

// ---------- x fp32 -> bf16 ----------
__global__ __launch_bounds__(256) void cvt_x_kernel(const float* __restrict__ x,
                                                    ushort_t* __restrict__ xb) {
  int i = blockIdx.x * 256 + threadIdx.x;  // each thread: 8 elems
  const f32x4v* xv = (const f32x4v*)x;
  f32x4v a = xv[2 * i], b = xv[2 * i + 1];
  bf16x8 o;
  o[0] = (short)f2bf(a[0]); o[1] = (short)f2bf(a[1]);
  o[2] = (short)f2bf(a[2]); o[3] = (short)f2bf(a[3]);
  o[4] = (short)f2bf(b[0]); o[5] = (short)f2bf(b[1]);
  o[6] = (short)f2bf(b[2]); o[7] = (short)f2bf(b[3]);
  ((bf16x8*)xb)[i] = o;
}

// ---------- weight fp32 [R][C] -> bf16 transposed [C][R], vectorized ----------
__global__ __launch_bounds__(256) void tr_cvt_kernel(const float* __restrict__ src,
                                                     ushort_t* __restrict__ dst,
                                                     int R, int C) {
  __shared__ float tile[64][65];
  int r0 = blockIdx.y * 64, c0 = blockIdx.x * 64;
  int t = threadIdx.x;
#pragma unroll
  for (int i = 0; i < 4; i++) {
    int idx = t + i * 256;          // 0..1023
    int r = idx >> 4, c4 = idx & 15;
    f32x4v v = *(const f32x4v*)&src[(size_t)(r0 + r) * C + c0 + c4 * 4];
#pragma unroll
    for (int j = 0; j < 4; j++) tile[r][c4 * 4 + j] = v[j];
  }
  __syncthreads();
#pragma unroll
  for (int i = 0; i < 4; i++) {
    int idx = t + i * 256;
    int cr = idx >> 4, cg = idx & 15;
    bf16x4 o;
#pragma unroll
    for (int j = 0; j < 4; j++) o[j] = (short)f2bf(tile[cg * 4 + j][cr]);
    *(bf16x4*)&dst[(size_t)(c0 + cr) * R + r0 + cg * 4] = o;
  }
}

// ---------- RoPE in-place on C1 (Q cols 0..4095 pre-scaled by scale*log2e) ----------
__global__ __launch_bounds__(256) void rope_kernel(ushort_t* __restrict__ C1,
                                                   const float* __restrict__ cosb,
                                                   const float* __restrict__ sinb) {
  int idx = blockIdx.x * 256 + threadIdx.x;  // 2048 * 640
  int s = idx / 640;
  int col0 = (idx % 640) * 8;
  int i0 = (col0 & 127) >> 1;
  const float qs = (col0 < 4096) ? 0.12753055296570565f : 1.0f;  // scale*log2e
  ushort_t* p = C1 + (size_t)s * 6144 + col0;
  bf16x8 v = *(const bf16x8*)p;
  bf16x8 o;
  const float* cr = cosb + s * 64 + i0;
  const float* sr = sinb + s * 64 + i0;
#pragma unroll
  for (int j = 0; j < 4; j++) {
    float tr = bf2f((ushort_t)v[2 * j]);
    float ti = bf2f((ushort_t)v[2 * j + 1]);
    float c = cr[j], sn = sr[j];
    o[2 * j] = (short)f2bf((tr * c - ti * sn) * qs);
    o[2 * j + 1] = (short)f2bf((tr * sn + ti * c) * qs);
  }
  *(bf16x8*)p = o;
}

// ---------- V part of C1 -> VT [1024][2048] (row = hk*128+d, col = s) ----------
__global__ __launch_bounds__(256) void trv_kernel(const ushort_t* __restrict__ C1,
                                                  ushort_t* __restrict__ VT) {
  __shared__ ushort_t tile[64][65];
  int c0 = blockIdx.x * 64;  // within 1024
  int r0 = blockIdx.y * 64;  // within 2048
  int t = threadIdx.x;
#pragma unroll
  for (int i = 0; i < 16; i++) {
    int idx = t + i * 256;
    int r = idx >> 6, c = idx & 63;
    tile[r][c] = C1[(size_t)(r0 + r) * 6144 + 5120 + c0 + c];
  }
  __syncthreads();
#pragma unroll
  for (int i = 0; i < 16; i++) {
    int idx = t + i * 256;
    int cr = idx >> 6, cc = idx & 63;
    VT[(size_t)(c0 + cr) * 2048 + r0 + cc] = tile[cc][cr];
  }
}

// ---------- 2D-chunked XCD block mapping ----------
__device__ __forceinline__ void xcd_chunk_map(int id, int nby, int nbx,
                                              int& browi, int& bcoli) {
  const int xcd = id & 7;
  const int j = id >> 3;
  const int rch = nby >> 1, cch = nbx >> 2;  // chunk dims
  const int cr = xcd >> 2, cc = xcd & 3;     // chunk grid is 2 x 4
  const int r = j / cch, c = j % cch;
  browi = cr * rch + r;
  bcoli = cc * cch + c;
}

// ---------- GEMM 256x192 p8 v2 (gemm1/QKV; verified R14/R15, plain epilogue) ----------
template <typename OutT>
__global__ __launch_bounds__(512) void gemmC_kernel(const ushort_t* __restrict__ A,
                                                    const ushort_t* __restrict__ BT,
                                                    OutT* __restrict__ C,
                                                    int M, int N, int K, int ldc) {
  __shared__ ushort_t As[2][256 * 64];  // 64KB
  __shared__ ushort_t Bs[3][192 * 64];  // 72KB
  const int nbx = N / 192, nby = M >> 8;
  int browi, bcoli;
  xcd_chunk_map((int)blockIdx.x, nby, nbx, browi, bcoli);
  const int brow = browi << 8, bcol = bcoli * 192;
  const int tid = threadIdx.x, w = tid >> 6, lane = tid & 63;
  const int wr = w >> 2, wc = w & 3;
  const int lr = lane & 15, lk = lane >> 4;

  const ushort_t* Ab = A + (size_t)brow * K;
  const ushort_t* Bb = BT + (size_t)bcol * K;

  auto stageQ = [&](const ushort_t* gbase, char* lds, int t, int q) {
    int L = q * 512 + tid;
    int r = L >> 3, sc = L & 7;
    load_lds16(gbase + (size_t)r * K + (t << 6) + ((sc ^ (r & 7)) << 3), lds + L * 16);
  };

  f32x4 acc[8][3] = {};
  const int NT = K >> 6;

  // prologue: B(0)x3, A(0)q0,q2,q1,q3, B(1)x3
#pragma unroll
  for (int q = 0; q < 3; ++q) stageQ(Bb, (char*)&Bs[0][0], 0, q);
  stageQ(Ab, (char*)&As[0][0], 0, 0);
  stageQ(Ab, (char*)&As[0][0], 0, 2);
  stageQ(Ab, (char*)&As[0][0], 0, 1);
  stageQ(Ab, (char*)&As[0][0], 0, 3);
#pragma unroll
  for (int q = 0; q < 3; ++q) stageQ(Bb, (char*)&Bs[1][0], 1, q);
  asm volatile("s_waitcnt vmcnt(5)" ::: "memory");
  __builtin_amdgcn_s_barrier();

  int bcur = 0;
  for (int t = 0; t < NT; ++t) {
    const int c = t & 1;
    const char* Ac = (const char*)&As[c][0];
    const char* Bc = (const char*)&Bs[bcur][0];
    char* An = (char*)&As[c ^ 1][0];
    const int bnxt = (bcur + 2 >= 3) ? bcur - 1 : bcur + 2;
    char* Bn = (char*)&Bs[bnxt][0];
    const bool pfA = (t + 1 < NT), pfB = (t + 2 < NT);

    bf16x8 af[4][2], bfr[3][2];
    // ===== phase 0 =====
#pragma unroll
    for (int mm = 0; mm < 4; ++mm)
#pragma unroll
      for (int ks = 0; ks < 2; ++ks) {
        int rA = wr * 128 + mm * 16 + lr;
        af[mm][ks] = *(const bf16x8*)(Ac + rA * 128 + (((ks * 4 + lk) ^ (rA & 7)) << 4));
      }
#pragma unroll
    for (int n = 0; n < 2; ++n)
#pragma unroll
      for (int ks = 0; ks < 2; ++ks) {
        int rB = wc * 48 + n * 16 + lr;
        bfr[n][ks] = *(const bf16x8*)(Bc + rB * 128 + (((ks * 4 + lk) ^ (rB & 7)) << 4));
      }
    if (pfA) { stageQ(Ab, An, t + 1, 0); stageQ(Ab, An, t + 1, 2); }
    __builtin_amdgcn_s_barrier();
    asm volatile("s_waitcnt lgkmcnt(0)" ::: "memory");
    __builtin_amdgcn_sched_barrier(0);
    __builtin_amdgcn_s_setprio(1);
#pragma unroll
    for (int mm = 0; mm < 4; ++mm)
#pragma unroll
      for (int n = 0; n < 2; ++n)
#pragma unroll
        for (int ks = 0; ks < 2; ++ks)
          acc[mm][n] = __builtin_amdgcn_mfma_f32_16x16x32_bf16(af[mm][ks], bfr[n][ks],
                                                               acc[mm][n], 0, 0, 0);
    __builtin_amdgcn_s_setprio(0);
    __builtin_amdgcn_s_barrier();

    // ===== phase 1 =====
#pragma unroll
    for (int ks = 0; ks < 2; ++ks) {
      int rB = wc * 48 + 32 + lr;
      bfr[2][ks] = *(const bf16x8*)(Bc + rB * 128 + (((ks * 4 + lk) ^ (rB & 7)) << 4));
    }
    if (pfA) { stageQ(Ab, An, t + 1, 1); stageQ(Ab, An, t + 1, 3); }
    __builtin_amdgcn_s_barrier();
    asm volatile("s_waitcnt lgkmcnt(0)" ::: "memory");
    __builtin_amdgcn_sched_barrier(0);
    __builtin_amdgcn_s_setprio(1);
#pragma unroll
    for (int mm = 0; mm < 4; ++mm)
#pragma unroll
      for (int ks = 0; ks < 2; ++ks)
        acc[mm][2] = __builtin_amdgcn_mfma_f32_16x16x32_bf16(af[mm][ks], bfr[2][ks],
                                                             acc[mm][2], 0, 0, 0);
    __builtin_amdgcn_s_setprio(0);
    asm volatile("s_waitcnt vmcnt(7)" ::: "memory");  // A(t)q1,q3 landed
    __builtin_amdgcn_s_barrier();

    // ===== phase 2 =====
#pragma unroll
    for (int mm = 0; mm < 4; ++mm)
#pragma unroll
      for (int ks = 0; ks < 2; ++ks) {
        int rA = wr * 128 + 64 + mm * 16 + lr;
        af[mm][ks] = *(const bf16x8*)(Ac + rA * 128 + (((ks * 4 + lk) ^ (rA & 7)) << 4));
      }
    if (pfB) { stageQ(Bb, Bn, t + 2, 0); stageQ(Bb, Bn, t + 2, 1); }
    __builtin_amdgcn_s_barrier();
    asm volatile("s_waitcnt lgkmcnt(0)" ::: "memory");
    __builtin_amdgcn_sched_barrier(0);
    __builtin_amdgcn_s_setprio(1);
#pragma unroll
    for (int mm = 0; mm < 4; ++mm)
#pragma unroll
      for (int n = 0; n < 2; ++n)
#pragma unroll
        for (int ks = 0; ks < 2; ++ks)
          acc[4 + mm][n] = __builtin_amdgcn_mfma_f32_16x16x32_bf16(af[mm][ks], bfr[n][ks],
                                                                   acc[4 + mm][n], 0, 0, 0);
    __builtin_amdgcn_s_setprio(0);
    __builtin_amdgcn_s_barrier();

    // ===== phase 3 =====
    if (pfB) stageQ(Bb, Bn, t + 2, 2);
    __builtin_amdgcn_s_setprio(1);
#pragma unroll
    for (int mm = 0; mm < 4; ++mm)
#pragma unroll
      for (int ks = 0; ks < 2; ++ks)
        acc[4 + mm][2] = __builtin_amdgcn_mfma_f32_16x16x32_bf16(af[mm][ks], bfr[2][ks],
                                                                 acc[4 + mm][2], 0, 0, 0);
    __builtin_amdgcn_s_setprio(0);
    if (pfB)
      asm volatile("s_waitcnt vmcnt(5)" ::: "memory");
    else
      asm volatile("s_waitcnt vmcnt(0)" ::: "memory");
    __builtin_amdgcn_s_barrier();
    bcur = (bcur + 1 == 3) ? 0 : bcur + 1;
  }
  // epilogue
#pragma unroll
  for (int m = 0; m < 8; ++m)
#pragma unroll
    for (int n = 0; n < 3; ++n) {
      int row = brow + wr * 128 + m * 16 + lk * 4;
      int col = bcol + wc * 48 + n * 16 + lr;
#pragma unroll
      for (int j = 0; j < 4; ++j) {
        float v = acc[m][n][j];
        if constexpr (sizeof(OutT) == 2)
          C[(size_t)(row + j) * ldc + col] = (OutT)f2bf(v);
        else
          C[(size_t)(row + j) * ldc + col] = v;
      }
    }
}

// ---------- GEMM 256x128 2-phase p8 (gemm2; verified R16) ----------
template <typename OutT>
__global__ __launch_bounds__(512) void gemmD_kernel(const ushort_t* __restrict__ A,
                                                    const ushort_t* __restrict__ BT,
                                                    OutT* __restrict__ C,
                                                    int M, int N, int K, int ldc) {
  __shared__ ushort_t As[3][256 * 64];  // 96KB
  __shared__ ushort_t Bs[3][128 * 64];  // 48KB
  const int nbx = N >> 7, nby = M >> 8;
  int browi, bcoli;
  xcd_chunk_map((int)blockIdx.x, nby, nbx, browi, bcoli);
  const int brow = browi << 8, bcol = bcoli << 7;
  const int tid = threadIdx.x, w = tid >> 6, lane = tid & 63;
  const int wr = w >> 2, wc = w & 3;
  const int lr = lane & 15, lk = lane >> 4;

  const ushort_t* Ab = A + (size_t)brow * K;
  const ushort_t* Bb = BT + (size_t)bcol * K;

  auto stageQ = [&](const ushort_t* gbase, char* lds, int t, int q) {
    int L = q * 512 + tid;
    int r = L >> 3, sc = L & 7;
    load_lds16(gbase + (size_t)r * K + (t << 6) + ((sc ^ (r & 7)) << 3), lds + L * 16);
  };
  auto stageTile = [&](int t, int buf) {  // 6 loads: A q0..q3 + B q0,q1
#pragma unroll
    for (int q = 0; q < 4; ++q) stageQ(Ab, (char*)&As[buf][0], t, q);
#pragma unroll
    for (int q = 0; q < 2; ++q) stageQ(Bb, (char*)&Bs[buf][0], t, q);
  };

  f32x4 acc[8][2] = {};
  const int NT = K >> 6;

  stageTile(0, 0);
  stageTile(1, 1);
  asm volatile("s_waitcnt vmcnt(6)" ::: "memory");  // tile0 landed, tile1 in flight
  __builtin_amdgcn_s_barrier();

  int cur = 0;
  for (int t = 0; t < NT; ++t) {
    const char* Ac = (const char*)&As[cur][0];
    const char* Bc = (const char*)&Bs[cur][0];
    const int nxt = (cur + 2 >= 3) ? cur - 1 : cur + 2;  // (t+2)%3
    char* An = (char*)&As[nxt][0];
    char* Bn = (char*)&Bs[nxt][0];
    const bool pf = (t + 2 < NT);

    bf16x8 af[4][2], bfr[2][2];
    // ===== phase A: A mh0 (8 reads) + B n0,n1 (4 reads); stage Aq0,Aq2,Bq0 =====
#pragma unroll
    for (int mm = 0; mm < 4; ++mm)
#pragma unroll
      for (int ks = 0; ks < 2; ++ks) {
        int rA = wr * 128 + mm * 16 + lr;
        af[mm][ks] = *(const bf16x8*)(Ac + rA * 128 + (((ks * 4 + lk) ^ (rA & 7)) << 4));
      }
#pragma unroll
    for (int n = 0; n < 2; ++n)
#pragma unroll
      for (int ks = 0; ks < 2; ++ks) {
        int rB = wc * 32 + n * 16 + lr;
        bfr[n][ks] = *(const bf16x8*)(Bc + rB * 128 + (((ks * 4 + lk) ^ (rB & 7)) << 4));
      }
    if (pf) { stageQ(Ab, An, t + 2, 0); stageQ(Ab, An, t + 2, 2); stageQ(Bb, Bn, t + 2, 0); }
    __builtin_amdgcn_s_barrier();
    asm volatile("s_waitcnt lgkmcnt(0)" ::: "memory");
    __builtin_amdgcn_sched_barrier(0);
    __builtin_amdgcn_s_setprio(1);
#pragma unroll
    for (int mm = 0; mm < 4; ++mm)
#pragma unroll
      for (int n = 0; n < 2; ++n)
#pragma unroll
        for (int ks = 0; ks < 2; ++ks)
          acc[mm][n] = __builtin_amdgcn_mfma_f32_16x16x32_bf16(af[mm][ks], bfr[n][ks],
                                                               acc[mm][n], 0, 0, 0);
    __builtin_amdgcn_s_setprio(0);
    __builtin_amdgcn_s_barrier();

    // ===== phase B: A mh1 (8 reads); stage Aq1,Aq3,Bq1; counted boundary =====
#pragma unroll
    for (int mm = 0; mm < 4; ++mm)
#pragma unroll
      for (int ks = 0; ks < 2; ++ks) {
        int rA = wr * 128 + 64 + mm * 16 + lr;
        af[mm][ks] = *(const bf16x8*)(Ac + rA * 128 + (((ks * 4 + lk) ^ (rA & 7)) << 4));
      }
    if (pf) { stageQ(Ab, An, t + 2, 1); stageQ(Ab, An, t + 2, 3); stageQ(Bb, Bn, t + 2, 1); }
    __builtin_amdgcn_s_barrier();
    asm volatile("s_waitcnt lgkmcnt(0)" ::: "memory");
    __builtin_amdgcn_sched_barrier(0);
    __builtin_amdgcn_s_setprio(1);
#pragma unroll
    for (int mm = 0; mm < 4; ++mm)
#pragma unroll
      for (int n = 0; n < 2; ++n)
#pragma unroll
        for (int ks = 0; ks < 2; ++ks)
          acc[4 + mm][n] = __builtin_amdgcn_mfma_f32_16x16x32_bf16(af[mm][ks], bfr[n][ks],
                                                                   acc[4 + mm][n], 0, 0, 0);
    __builtin_amdgcn_s_setprio(0);
    if (pf)
      asm volatile("s_waitcnt vmcnt(6)" ::: "memory");  // t+1 landed; t+2 in flight
    else if (t + 1 < NT)
      asm volatile("s_waitcnt vmcnt(0)" ::: "memory");  // tail drain
    __builtin_amdgcn_s_barrier();
    cur = (cur == 2) ? 0 : cur + 1;
  }
  // epilogue
#pragma unroll
  for (int m = 0; m < 8; ++m)
#pragma unroll
    for (int n = 0; n < 2; ++n) {
      int row = brow + wr * 128 + m * 16 + lk * 4;
      int col = bcol + wc * 32 + n * 16 + lr;
#pragma unroll
      for (int j = 0; j < 4; ++j) {
        float v = acc[m][n][j];
        if constexpr (sizeof(OutT) == 2)
          C[(size_t)(row + j) * ldc + col] = (OutT)f2bf(v);
        else
          C[(size_t)(row + j) * ldc + col] = v;
      }
    }
}

// ---------- GEMM: C[M][ldc] = A[M][K] * BT[N][K]^T  (m97 structure, fallback) ----------
template <typename OutT>
__global__ __launch_bounds__(256) void gemm128_kernel(const ushort_t* __restrict__ A,
                                                      const ushort_t* __restrict__ BT,
                                                      OutT* __restrict__ C,
                                                      int M, int N, int K, int ldc) {
  __shared__ ushort_t As[128 * 32];
  __shared__ ushort_t Bs[128 * 32];
  int brow = blockIdx.y * 128, bcol = blockIdx.x * 128;
  int tid = threadIdx.x, w = tid >> 6, lane = tid & 63;
  int wr = w >> 1, wc = w & 1;
  int lr = lane & 15, lk = lane >> 4;
  f32x4 acc[4][4] = {};

  int srow = lane >> 2;
  int scol = (lane & 3) * 8;
  const ushort_t* Ab = A + (size_t)brow * K + scol;
  const ushort_t* Bb = BT + (size_t)bcol * K + scol;

  for (int kt = 0; kt < K; kt += 32) {
#pragma unroll
    for (int i = 0; i < 2; i++) {
      int seg = w * 2 + i;
      int row = seg * 16 + srow;
      load_lds16(Ab + (size_t)row * K + kt, (char*)As + seg * 1024);
      load_lds16(Bb + (size_t)row * K + kt, (char*)Bs + seg * 1024);
    }
    __syncthreads();
    bf16x8 af[4], bfr[4];
#pragma unroll
    for (int m = 0; m < 4; m++)
      af[m] = *(const bf16x8*)&As[(wr * 64 + m * 16 + lr) * 32 + lk * 8];
#pragma unroll
    for (int n = 0; n < 4; n++)
      bfr[n] = *(const bf16x8*)&Bs[(wc * 64 + n * 16 + lr) * 32 + lk * 8];
#pragma unroll
    for (int m = 0; m < 4; m++)
#pragma unroll
      for (int n = 0; n < 4; n++)
        acc[m][n] = __builtin_amdgcn_mfma_f32_16x16x32_bf16(af[m], bfr[n], acc[m][n], 0, 0, 0);
    __syncthreads();
  }
#pragma unroll
  for (int m = 0; m < 4; m++)
#pragma unroll
    for (int n = 0; n < 4; n++) {
      int row = brow + wr * 64 + m * 16 + lk * 4;
      int col = bcol + wc * 64 + n * 16 + lr;
#pragma unroll
      for (int j = 0; j < 4; j++) {
        float v = acc[m][n][j];
        if constexpr (sizeof(OutT) == 2)
          C[(size_t)(row + j) * ldc + col] = (OutT)f2bf(v);
        else
          C[(size_t)(row + j) * ldc + col] = v;
      }
    }
}

// ---------- gemmS: P[tile] = exp2(Q K^T) causal, materialized bf16 ----------
__global__ __launch_bounds__(256) void gemmS_kernel(const ushort_t* __restrict__ C1,
                                                    ushort_t* __restrict__ P) {
  int rem = blockIdx.x, rt = 0;
  while (rem > rt) { rem -= (rt + 1); rt++; }
  const int ct = rem;
  const int h = blockIdx.y, hk = h >> 2;

  __shared__ ushort_t As[128 * 32];
  __shared__ ushort_t Bs[128 * 32];
  int tid = threadIdx.x, w = tid >> 6, lane = tid & 63;
  int wr = w >> 1, wc = w & 1;
  int lr = lane & 15, lk = lane >> 4;
  f32x4 acc[4][4] = {};
  int srow = lane >> 2;
  int scol = (lane & 3) * 8;
  const ushort_t* Ab = C1 + (size_t)(rt * 128) * 6144 + h * 128 + scol;         // Q
  const ushort_t* Bb = C1 + (size_t)(ct * 128) * 6144 + 4096 + hk * 128 + scol; // K

  for (int kt = 0; kt < 128; kt += 32) {
#pragma unroll
    for (int i = 0; i < 2; i++) {
      int seg = w * 2 + i;
      int row = seg * 16 + srow;
      load_lds16(Ab + (size_t)row * 6144 + kt, (char*)As + seg * 1024);
      load_lds16(Bb + (size_t)row * 6144 + kt, (char*)Bs + seg * 1024);
    }
    __syncthreads();
    bf16x8 af[4], bfr[4];
#pragma unroll
    for (int m = 0; m < 4; m++)
      af[m] = *(const bf16x8*)&As[(wr * 64 + m * 16 + lr) * 32 + lk * 8];
#pragma unroll
    for (int n = 0; n < 4; n++)
      bfr[n] = *(const bf16x8*)&Bs[(wc * 64 + n * 16 + lr) * 32 + lk * 8];
#pragma unroll
    for (int m = 0; m < 4; m++)
#pragma unroll
      for (int n = 0; n < 4; n++)
        acc[m][n] = __builtin_amdgcn_mfma_f32_16x16x32_bf16(af[m], bfr[n], acc[m][n], 0, 0, 0);
    __syncthreads();
  }
  ushort_t* Pt = P + ((size_t)h * 136 + (size_t)(rt * (rt + 1) / 2) + ct) * 16384;
  const bool diag = (rt == ct);
#pragma unroll
  for (int m = 0; m < 4; m++)
#pragma unroll
    for (int n = 0; n < 4; n++) {
      int row = wr * 64 + m * 16 + lk * 4;
      int col = wc * 64 + n * 16 + lr;
#pragma unroll
      for (int j = 0; j < 4; j++) {
        float v = exp2_hw(acc[m][n][j]);
        if (diag && col > row + j) v = 0.f;
        Pt[(row + j) * 128 + col] = f2bf(v);
      }
    }
}

// ---------- gemmPV: AO[rt-tile] = (P * V) / rowsum(P), rowsum via ones-MFMA ----------
__global__ __launch_bounds__(256) void gemmPV_kernel(const ushort_t* __restrict__ P,
                                                     const ushort_t* __restrict__ VT,
                                                     ushort_t* __restrict__ AO) {
  const int h = blockIdx.x, hk = h >> 2;
  const int rt = 15 - (int)blockIdx.y;

  __shared__ ushort_t As[128 * 32];
  __shared__ ushort_t Bs[128 * 32];
  int tid = threadIdx.x, w = tid >> 6, lane = tid & 63;
  int wr = w >> 1, wc = w & 1;
  int lr = lane & 15, lk = lane >> 4;
  f32x4 acc[4][4] = {};
  f32x4 sacc[4] = {};
  bf16x8 ones;
#pragma unroll
  for (int j = 0; j < 8; j++) ones[j] = (short)0x3F80;  // bf16 1.0
  int srow = lane >> 2;
  int scol = (lane & 3) * 8;
  const ushort_t* Ph = P + ((size_t)h * 136 + (size_t)(rt * (rt + 1) / 2)) * 16384;
  const ushort_t* Vh = VT + (size_t)hk * 128 * 2048;

  const int nks = (rt + 1) * 4;
  for (int ks = 0; ks < nks; ks++) {
    int k0 = ks * 32;
    int ctk = k0 >> 7, kin = k0 & 127;
#pragma unroll
    for (int i = 0; i < 2; i++) {
      int seg = w * 2 + i;
      int row = seg * 16 + srow;
      load_lds16(Ph + (size_t)ctk * 16384 + (size_t)row * 128 + kin + scol,
                 (char*)As + seg * 1024);
      load_lds16(Vh + (size_t)row * 2048 + k0 + scol, (char*)Bs + seg * 1024);
    }
    __syncthreads();
    bf16x8 af[4], bfr[4];
#pragma unroll
    for (int m = 0; m < 4; m++)
      af[m] = *(const bf16x8*)&As[(wr * 64 + m * 16 + lr) * 32 + lk * 8];
#pragma unroll
    for (int n = 0; n < 4; n++)
      bfr[n] = *(const bf16x8*)&Bs[(wc * 64 + n * 16 + lr) * 32 + lk * 8];
#pragma unroll
    for (int m = 0; m < 4; m++) {
#pragma unroll
      for (int n = 0; n < 4; n++)
        acc[m][n] = __builtin_amdgcn_mfma_f32_16x16x32_bf16(af[m], bfr[n], acc[m][n], 0, 0, 0);
      sacc[m] = __builtin_amdgcn_mfma_f32_16x16x32_bf16(af[m], ones, sacc[m], 0, 0, 0);
    }
    __syncthreads();
  }
  const int q0 = rt * 128;
#pragma unroll
  for (int m = 0; m < 4; m++) {
    float invs[4];
#pragma unroll
    for (int j = 0; j < 4; j++) invs[j] = 1.0f / sacc[m][j];
#pragma unroll
    for (int n = 0; n < 4; n++) {
      int row = wr * 64 + m * 16 + lk * 4;
      int col = wc * 64 + n * 16 + lr;
#pragma unroll
      for (int j = 0; j < 4; j++) {
        float v = acc[m][n][j] * invs[j];
        AO[(size_t)(q0 + row + j) * 4096 + h * 128 + col] = f2bf(v);
      }
    }
  }
}

// ---------- flash attention (fallback when workspace too small) ----------
__global__ __launch_bounds__(256) void fattn_kernel(const ushort_t* __restrict__ C1,
                                                    const ushort_t* __restrict__ VT,
                                                    ushort_t* __restrict__ AO) {
  __shared__ ushort_t Pl[4][32][72];
  const int h = blockIdx.x, hk = h >> 2;
  const int qt = gridDim.y - 1 - blockIdx.y;
  const int tid = threadIdx.x, w = tid >> 6, lane = tid & 63;
  const int lq = lane & 31, hi = lane >> 5;
  const int qw0 = qt * 128 + w * 32;
  const int qabs = qw0 + lq;

  const ushort_t* Kb = C1 + 4096 + (size_t)hk * 128;
  const ushort_t* Vb = VT + (size_t)hk * 128 * 2048;

  bf16x8 qf[8];
  {
    const ushort_t* qrow = C1 + (size_t)qabs * 6144 + h * 128;
#pragma unroll
    for (int s = 0; s < 8; s++) qf[s] = *(const bf16x8*)(qrow + s * 16 + hi * 8);
  }
  f32x16 ot[4] = {};
  float mrow = -1e30f, ssum = 0.f;

  const int ktmax = (qw0 + 31) >> 6;
  for (int kt = 0; kt <= ktmax; kt++) {
    f32x16 sg[2] = {};
#pragma unroll
    for (int g = 0; g < 2; g++) {
      bf16x8 kfa[8];
      const ushort_t* krow = Kb + (size_t)(kt * 64 + g * 32 + lq) * 6144 + hi * 8;
#pragma unroll
      for (int s = 0; s < 8; s++) kfa[s] = *(const bf16x8*)(krow + s * 16);
#pragma unroll
      for (int s = 0; s < 8; s++)
        sg[g] = __builtin_amdgcn_mfma_f32_32x32x16_bf16(kfa[s], qf[s], sg[g], 0, 0, 0);
    }
    if (kt * 64 + 63 > qw0) {
#pragma unroll
      for (int g = 0; g < 2; g++)
#pragma unroll
        for (int r = 0; r < 16; r++) {
          int key = kt * 64 + g * 32 + (r & 3) + 8 * (r >> 2) + 4 * hi;
          if (key > qabs) sg[g][r] = -1e30f;
        }
    }
    float pm = -1e30f;
#pragma unroll
    for (int g = 0; g < 2; g++)
#pragma unroll
      for (int r = 0; r < 16; r++) pm = fmaxf(pm, sg[g][r]);
    pm = fmaxf(pm, __shfl_xor(pm, 32));
    float mnew = fmaxf(mrow, pm);
    float corr = exp2_hw(mrow - mnew);
    mrow = mnew;
    float ps = 0.f;
#pragma unroll
    for (int g = 0; g < 2; g++)
#pragma unroll
      for (int r = 0; r < 16; r++) {
        float e = exp2_hw(sg[g][r] - mnew);
        sg[g][r] = e;
        ps += e;
      }
    ps += __shfl_xor(ps, 32);
    ssum = ssum * corr + ps;
    if (!__all(corr == 1.f)) {
#pragma unroll
      for (int d = 0; d < 4; d++)
#pragma unroll
        for (int r = 0; r < 16; r++) ot[d][r] *= corr;
    }
#pragma unroll
    for (int g = 0; g < 2; g++)
#pragma unroll
      for (int rq = 0; rq < 4; rq++) {
        bf16x4 pk;
#pragma unroll
        for (int j = 0; j < 4; j++) pk[j] = (short)f2bf(sg[g][rq * 4 + j]);
        *(bf16x4*)&Pl[w][lq][g * 32 + rq * 8 + hi * 4] = pk;
      }
    asm volatile("s_waitcnt lgkmcnt(0)" ::: "memory");
    bf16x8 pf[4];
#pragma unroll
    for (int s = 0; s < 4; s++) pf[s] = *(const bf16x8*)&Pl[w][lq][s * 16 + hi * 8];
#pragma unroll
    for (int d = 0; d < 4; d++) {
      bf16x8 vfa[4];
      const ushort_t* vrow = Vb + (size_t)(d * 32 + lq) * 2048 + kt * 64 + hi * 8;
#pragma unroll
      for (int s = 0; s < 4; s++) vfa[s] = *(const bf16x8*)(vrow + s * 16);
#pragma unroll
      for (int s = 0; s < 4; s++)
        ot[d] = __builtin_amdgcn_mfma_f32_32x32x16_bf16(vfa[s], pf[s], ot[d], 0, 0, 0);
    }
  }
  const float inv = 1.0f / ssum;
  ushort_t* orow = AO + (size_t)qabs * 4096 + h * 128;
#pragma unroll
  for (int d = 0; d < 4; d++)
#pragma unroll
    for (int rq = 0; rq < 4; rq++) {
      bf16x4 ok;
#pragma unroll
      for (int j = 0; j < 4; j++) ok[j] = (short)f2bf(ot[d][rq * 4 + j] * inv);
      *(bf16x4*)(orow + d * 32 + rq * 8 + hi * 4) = ok;
    }
}

// ---------- launch ----------
extern "C" void kernel_launch(void* const* d_in, const int* in_sizes, int n_in,
                              void* d_out, int out_size, void* d_ws, size_t ws_size,
                              hipStream_t stream) {
  (void)in_sizes; (void)n_in; (void)out_size;
  const float* x    = (const float*)d_in[0];
  const float* wq   = (const float*)d_in[1];
  const float* wk   = (const float*)d_in[2];
  const float* wv   = (const float*)d_in[3];
  const float* wo   = (const float*)d_in[4];
  const float* cosb = (const float*)d_in[5];
  const float* sinb = (const float*)d_in[6];

  char* ws = (char*)d_ws;
  const bool fast = ws_size >= (215ull << 20);

  if (fast) {
    // layout (MiB): C1[0,24) VT[24,28) woT[28,60) xb[60,76) wT[76,124)
    //               P[60,196) (xb+wT dead after gemm1)  AO[196,212)
    ushort_t* C1  = (ushort_t*)(ws);
    ushort_t* VT  = (ushort_t*)(ws + ((size_t)24 << 20));
    ushort_t* woT = (ushort_t*)(ws + ((size_t)28 << 20));
    ushort_t* xb  = (ushort_t*)(ws + ((size_t)60 << 20));
    ushort_t* wT  = (ushort_t*)(ws + ((size_t)76 << 20));
    ushort_t* P   = (ushort_t*)(ws + ((size_t)60 << 20));
    ushort_t* AO  = (ushort_t*)(ws + ((size_t)196 << 20));

    cvt_x_kernel<<<4096, 256, 0, stream>>>(x, xb);
    tr_cvt_kernel<<<dim3(64, 64), 256, 0, stream>>>(wq, wT, 4096, 4096);
    tr_cvt_kernel<<<dim3(16, 64), 256, 0, stream>>>(wk, wT + (size_t)4096 * 4096, 4096, 1024);
    tr_cvt_kernel<<<dim3(16, 64), 256, 0, stream>>>(wv, wT + (size_t)5120 * 4096, 4096, 1024);
    tr_cvt_kernel<<<dim3(64, 64), 256, 0, stream>>>(wo, woT, 4096, 4096);

    // QKV projection: 256x192 p8 v2, grid 256, 2D-chunked XCD map
    gemmC_kernel<ushort_t><<<256, 512, 0, stream>>>(xb, wT, C1, 2048, 6144, 4096, 6144);
    rope_kernel<<<5120, 256, 0, stream>>>(C1, cosb, sinb);
    trv_kernel<<<dim3(16, 32), 256, 0, stream>>>(C1, VT);

    gemmS_kernel<<<dim3(136, 32), 256, 0, stream>>>(C1, P);
    gemmPV_kernel<<<dim3(32, 16), 256, 0, stream>>>(P, VT, AO);  // rowsum fused

    // output projection: 256x128 2-phase p8, grid 8x32 = 256, 2D-chunked XCD map
    gemmD_kernel<float><<<256, 512, 0, stream>>>(AO, woT, (float*)d_out, 2048, 4096, 4096, 4096);
  } else {
    // proven 92MiB layout + R7 fattn
    ushort_t* xb  = (ushort_t*)(ws);
    ushort_t* wT  = (ushort_t*)(ws + ((size_t)16 << 20));
    ushort_t* C1  = (ushort_t*)(ws + ((size_t)64 << 20));
    ushort_t* VT  = (ushort_t*)(ws + ((size_t)88 << 20));
    ushort_t* AO  = xb;
    ushort_t* woT = wT;

    cvt_x_kernel<<<4096, 256, 0, stream>>>(x, xb);
    tr_cvt_kernel<<<dim3(64, 64), 256, 0, stream>>>(wq, wT, 4096, 4096);
    tr_cvt_kernel<<<dim3(16, 64), 256, 0, stream>>>(wk, wT + (size_t)4096 * 4096, 4096, 1024);
    tr_cvt_kernel<<<dim3(16, 64), 256, 0, stream>>>(wv, wT + (size_t)5120 * 4096, 4096, 1024);
    gemm128_kernel<ushort_t><<<dim3(48, 16), 256, 0, stream>>>(xb, wT, C1, 2048, 6144, 4096, 6144);
    rope_kernel<<<5120, 256, 0, stream>>>(C1, cosb, sinb);
    trv_kernel<<<dim3(16, 32), 256, 0, stream>>>(C1, VT);
    tr_cvt_kernel<<<dim3(64, 64), 256, 0, stream>>>(wo, woT, 4096, 4096);
    fattn_kernel<<<dim3(32, 16), 256, 0, stream>>>(C1, VT, AO);
    gemm128_kernel<float><<<dim3(32, 16), 256, 0, stream>>>(AO, woT, (float*)d_out, 2048, 4096, 4096, 4096);
  }
}

// Round 18
// 346.889 us; speedup vs baseline: 1.2228x; 1.0243x over previous
//
#include <hip/hip_runtime.h>
#include <stdint.h>

typedef unsigned short ushort_t;
typedef short bf16x4 __attribute__((ext_vector_type(4)));
typedef short bf16x8 __attribute__((ext_vector_type(8)));
typedef float f32x4 __attribute__((ext_vector_type(4)));
typedef float f32x16 __attribute__((ext_vector_type(16)));
typedef float f32x4v __attribute__((ext_vector_type(4)));

// ---------- helpers ----------
__device__ __forceinline__ ushort_t f2bf(float f) {
  unsigned int u = __builtin_bit_cast(unsigned int, f);
  u += 0x7fffu + ((u >> 16) & 1u);
  return (ushort_t)(u >> 16);
}
__device__ __forceinline__ float bf2f(ushort_t h) {
  unsigned int u = ((unsigned int)h) << 16;
  return __builtin_bit_cast(float, u);
}
__device__ __forceinline__ float exp2_hw(float x) {
  return __builtin_amdgcn_exp2f(x);  // v_exp_f32: D = 2^S0
}
__device__ __forceinline__ void load_lds16(const void* g, void* l) {
  __builtin_amdgcn_global_load_lds(
      (const __attribute__((address_space(1))) void*)g,
      (__attribute__((address_space(3))) void*)l, 16, 0, 0);
}

// ---------- x fp32 -> bf16 ----------
__global__ __launch_bounds__(256) void cvt_x_kernel(const float* __restrict__ x,
                                                    ushort_t* __restrict__ xb) {
  int i = blockIdx.x * 256 + threadIdx.x;  // each thread: 8 elems
  const f32x4v* xv = (const f32x4v*)x;
  f32x4v a = xv[2 * i], b = xv[2 * i + 1];
  bf16x8 o;
  o[0] = (short)f2bf(a[0]); o[1] = (short)f2bf(a[1]);
  o[2] = (short)f2bf(a[2]); o[3] = (short)f2bf(a[3]);
  o[4] = (short)f2bf(b[0]); o[5] = (short)f2bf(b[1]);
  o[6] = (short)f2bf(b[2]); o[7] = (short)f2bf(b[3]);
  ((bf16x8*)xb)[i] = o;
}

// ---------- weight fp32 [R][C] -> bf16 transposed [C][R], vectorized ----------
__global__ __launch_bounds__(256) void tr_cvt_kernel(const float* __restrict__ src,
                                                     ushort_t* __restrict__ dst,
                                                     int R, int C) {
  __shared__ float tile[64][65];
  int r0 = blockIdx.y * 64, c0 = blockIdx.x * 64;
  int t = threadIdx.x;
#pragma unroll
  for (int i = 0; i < 4; i++) {
    int idx = t + i * 256;          // 0..1023
    int r = idx >> 4, c4 = idx & 15;
    f32x4v v = *(const f32x4v*)&src[(size_t)(r0 + r) * C + c0 + c4 * 4];
#pragma unroll
    for (int j = 0; j < 4; j++) tile[r][c4 * 4 + j] = v[j];
  }
  __syncthreads();
#pragma unroll
  for (int i = 0; i < 4; i++) {
    int idx = t + i * 256;
    int cr = idx >> 4, cg = idx & 15;
    bf16x4 o;
#pragma unroll
    for (int j = 0; j < 4; j++) o[j] = (short)f2bf(tile[cg * 4 + j][cr]);
    *(bf16x4*)&dst[(size_t)(c0 + cr) * R + r0 + cg * 4] = o;
  }
}

// ---------- RoPE in-place on C1 (Q cols 0..4095 pre-scaled by scale*log2e) ----------
__global__ __launch_bounds__(256) void rope_kernel(ushort_t* __restrict__ C1,
                                                   const float* __restrict__ cosb,
                                                   const float* __restrict__ sinb) {
  int idx = blockIdx.x * 256 + threadIdx.x;  // 2048 * 640
  int s = idx / 640;
  int col0 = (idx % 640) * 8;
  int i0 = (col0 & 127) >> 1;
  const float qs = (col0 < 4096) ? 0.12753055296570565f : 1.0f;  // scale*log2e
  ushort_t* p = C1 + (size_t)s * 6144 + col0;
  bf16x8 v = *(const bf16x8*)p;
  bf16x8 o;
  const float* cr = cosb + s * 64 + i0;
  const float* sr = sinb + s * 64 + i0;
#pragma unroll
  for (int j = 0; j < 4; j++) {
    float tr = bf2f((ushort_t)v[2 * j]);
    float ti = bf2f((ushort_t)v[2 * j + 1]);
    float c = cr[j], sn = sr[j];
    o[2 * j] = (short)f2bf((tr * c - ti * sn) * qs);
    o[2 * j + 1] = (short)f2bf((tr * sn + ti * c) * qs);
  }
  *(bf16x8*)p = o;
}

// ---------- V part of C1 -> VT [1024][2048] (row = hk*128+d, col = s) ----------
__global__ __launch_bounds__(256) void trv_kernel(const ushort_t* __restrict__ C1,
                                                  ushort_t* __restrict__ VT) {
  __shared__ ushort_t tile[64][65];
  int c0 = blockIdx.x * 64;  // within 1024
  int r0 = blockIdx.y * 64;  // within 2048
  int t = threadIdx.x;
#pragma unroll
  for (int i = 0; i < 16; i++) {
    int idx = t + i * 256;
    int r = idx >> 6, c = idx & 63;
    tile[r][c] = C1[(size_t)(r0 + r) * 6144 + 5120 + c0 + c];
  }
  __syncthreads();
#pragma unroll
  for (int i = 0; i < 16; i++) {
    int idx = t + i * 256;
    int cr = idx >> 6, cc = idx & 63;
    VT[(size_t)(c0 + cr) * 2048 + r0 + cc] = tile[cc][cr];
  }
}

// ---------- 2D-chunked XCD block mapping ----------
__device__ __forceinline__ void xcd_chunk_map(int id, int nby, int nbx,
                                              int& browi, int& bcoli) {
  const int xcd = id & 7;
  const int j = id >> 3;
  const int rch = nby >> 1, cch = nbx >> 2;  // chunk dims
  const int cr = xcd >> 2, cc = xcd & 3;     // chunk grid is 2 x 4
  const int r = j / cch, c = j % cch;
  browi = cr * rch + r;
  bcoli = cc * cch + c;
}

// ---------- GEMM 256x192, 2-phase (gemm1/QKV) ----------
// 2-phase conversion of the verified R15/R17 4-phase schedule (R16 evidence:
// 2-phase > 4-phase at equal tile volume — fewer all-wave barriers).
// A 2-buf depth-1, B 3-buf depth-2, 136KB LDS. Per tile:
//  phase A: read A-mh0 (8) + all B (6); stage A(t+1)q0,q2 + B(t+2)q0;
//           barrier; lgkmcnt(0); 24 MFMA.  end: W2.
//  phase B: read A-mh1 (8); stage A(t+1)q1,q3 + B(t+2)q1,q2;
//           barrier; lgkmcnt(0); 24 MFMA.  end: W1.
// FIFO (issue order per tile: [Aq0,Aq2,Bq0'][Aq1,Aq3,Bq1',Bq2']):
//  W2 needs A(t)q1,q3 (issued t-1 phB) landed; newer = B(t+1)q1,q2 + phA's 3
//    -> vmcnt(5).
//  W1 needs A(t+1)q0,q2 + B(t+1)x3 landed; newer than A(t+1)q2 = Bq0' +
//    phB's 4 -> vmcnt(5).
// Tail (t+2>=NT): vmcnt(0) at both (few loads left; exact drain).
template <typename OutT>
__global__ __launch_bounds__(512) void gemmC_kernel(const ushort_t* __restrict__ A,
                                                    const ushort_t* __restrict__ BT,
                                                    OutT* __restrict__ C,
                                                    int M, int N, int K, int ldc) {
  __shared__ ushort_t As[2][256 * 64];  // 64KB
  __shared__ ushort_t Bs[3][192 * 64];  // 72KB
  const int nbx = N / 192, nby = M >> 8;
  int browi, bcoli;
  xcd_chunk_map((int)blockIdx.x, nby, nbx, browi, bcoli);
  const int brow = browi << 8, bcol = bcoli * 192;
  const int tid = threadIdx.x, w = tid >> 6, lane = tid & 63;
  const int wr = w >> 2, wc = w & 3;
  const int lr = lane & 15, lk = lane >> 4;

  const ushort_t* Ab = A + (size_t)brow * K;
  const ushort_t* Bb = BT + (size_t)bcol * K;

  auto stageQ = [&](const ushort_t* gbase, char* lds, int t, int q) {
    int L = q * 512 + tid;
    int r = L >> 3, sc = L & 7;
    load_lds16(gbase + (size_t)r * K + (t << 6) + ((sc ^ (r & 7)) << 3), lds + L * 16);
  };

  f32x4 acc[8][3] = {};
  const int NT = K >> 6;  // requires NT >= 3

  // prologue: B(0)x3, A(0)x4, B(1)x3; wait B(0)+A(0) landed (B(1) in flight)
#pragma unroll
  for (int q = 0; q < 3; ++q) stageQ(Bb, (char*)&Bs[0][0], 0, q);
  stageQ(Ab, (char*)&As[0][0], 0, 0);
  stageQ(Ab, (char*)&As[0][0], 0, 2);
  stageQ(Ab, (char*)&As[0][0], 0, 1);
  stageQ(Ab, (char*)&As[0][0], 0, 3);
#pragma unroll
  for (int q = 0; q < 3; ++q) stageQ(Bb, (char*)&Bs[1][0], 1, q);
  asm volatile("s_waitcnt vmcnt(3)" ::: "memory");
  __builtin_amdgcn_s_barrier();

  int bcur = 0;
  for (int t = 0; t < NT; ++t) {
    const int c = t & 1;
    const char* Ac = (const char*)&As[c][0];
    const char* Bc = (const char*)&Bs[bcur][0];
    char* An = (char*)&As[c ^ 1][0];
    const int bnxt = (bcur + 2 >= 3) ? bcur - 1 : bcur + 2;  // (t+2)%3
    char* Bn = (char*)&Bs[bnxt][0];
    const bool pfA = (t + 1 < NT), pfB = (t + 2 < NT);

    bf16x8 af[4][2], bfr[3][2];
    // ===== phase A: A mh0 (8 reads) + B all (6 reads); stage Aq0,Aq2,B'q0 =====
#pragma unroll
    for (int mm = 0; mm < 4; ++mm)
#pragma unroll
      for (int ks = 0; ks < 2; ++ks) {
        int rA = wr * 128 + mm * 16 + lr;
        af[mm][ks] = *(const bf16x8*)(Ac + rA * 128 + (((ks * 4 + lk) ^ (rA & 7)) << 4));
      }
#pragma unroll
    for (int n = 0; n < 3; ++n)
#pragma unroll
      for (int ks = 0; ks < 2; ++ks) {
        int rB = wc * 48 + n * 16 + lr;
        bfr[n][ks] = *(const bf16x8*)(Bc + rB * 128 + (((ks * 4 + lk) ^ (rB & 7)) << 4));
      }
    if (pfA) { stageQ(Ab, An, t + 1, 0); stageQ(Ab, An, t + 1, 2); }
    if (pfB) stageQ(Bb, Bn, t + 2, 0);
    __builtin_amdgcn_s_barrier();
    asm volatile("s_waitcnt lgkmcnt(0)" ::: "memory");
    __builtin_amdgcn_sched_barrier(0);
    __builtin_amdgcn_s_setprio(1);
#pragma unroll
    for (int mm = 0; mm < 4; ++mm)
#pragma unroll
      for (int n = 0; n < 3; ++n)
#pragma unroll
        for (int ks = 0; ks < 2; ++ks)
          acc[mm][n] = __builtin_amdgcn_mfma_f32_16x16x32_bf16(af[mm][ks], bfr[n][ks],
                                                               acc[mm][n], 0, 0, 0);
    __builtin_amdgcn_s_setprio(0);
    // W2: A(t)q1,q3 landed (needed by phase B)
    if (pfB)
      asm volatile("s_waitcnt vmcnt(5)" ::: "memory");
    else
      asm volatile("s_waitcnt vmcnt(0)" ::: "memory");
    __builtin_amdgcn_s_barrier();

    // ===== phase B: A mh1 (8 reads); stage Aq1,Aq3,B'q1,B'q2 =====
#pragma unroll
    for (int mm = 0; mm < 4; ++mm)
#pragma unroll
      for (int ks = 0; ks < 2; ++ks) {
        int rA = wr * 128 + 64 + mm * 16 + lr;
        af[mm][ks] = *(const bf16x8*)(Ac + rA * 128 + (((ks * 4 + lk) ^ (rA & 7)) << 4));
      }
    if (pfA) { stageQ(Ab, An, t + 1, 1); stageQ(Ab, An, t + 1, 3); }
    if (pfB) { stageQ(Bb, Bn, t + 2, 1); stageQ(Bb, Bn, t + 2, 2); }
    __builtin_amdgcn_s_barrier();
    asm volatile("s_waitcnt lgkmcnt(0)" ::: "memory");
    __builtin_amdgcn_sched_barrier(0);
    __builtin_amdgcn_s_setprio(1);
#pragma unroll
    for (int mm = 0; mm < 4; ++mm)
#pragma unroll
      for (int n = 0; n < 3; ++n)
#pragma unroll
        for (int ks = 0; ks < 2; ++ks)
          acc[4 + mm][n] = __builtin_amdgcn_mfma_f32_16x16x32_bf16(af[mm][ks], bfr[n][ks],
                                                                   acc[4 + mm][n], 0, 0, 0);
    __builtin_amdgcn_s_setprio(0);
    // W1: A(t+1)q0,q2 + B(t+1)x3 landed (needed by next phase A)
    if (pfB)
      asm volatile("s_waitcnt vmcnt(5)" ::: "memory");
    else
      asm volatile("s_waitcnt vmcnt(0)" ::: "memory");
    __builtin_amdgcn_s_barrier();
    bcur = (bcur + 1 == 3) ? 0 : bcur + 1;
  }
  // epilogue
#pragma unroll
  for (int m = 0; m < 8; ++m)
#pragma unroll
    for (int n = 0; n < 3; ++n) {
      int row = brow + wr * 128 + m * 16 + lk * 4;
      int col = bcol + wc * 48 + n * 16 + lr;
#pragma unroll
      for (int j = 0; j < 4; ++j) {
        float v = acc[m][n][j];
        if constexpr (sizeof(OutT) == 2)
          C[(size_t)(row + j) * ldc + col] = (OutT)f2bf(v);
        else
          C[(size_t)(row + j) * ldc + col] = v;
      }
    }
}

// ---------- GEMM 256x128 2-phase p8 (gemm2; verified R16) ----------
template <typename OutT>
__global__ __launch_bounds__(512) void gemmD_kernel(const ushort_t* __restrict__ A,
                                                    const ushort_t* __restrict__ BT,
                                                    OutT* __restrict__ C,
                                                    int M, int N, int K, int ldc) {
  __shared__ ushort_t As[3][256 * 64];  // 96KB
  __shared__ ushort_t Bs[3][128 * 64];  // 48KB
  const int nbx = N >> 7, nby = M >> 8;
  int browi, bcoli;
  xcd_chunk_map((int)blockIdx.x, nby, nbx, browi, bcoli);
  const int brow = browi << 8, bcol = bcoli << 7;
  const int tid = threadIdx.x, w = tid >> 6, lane = tid & 63;
  const int wr = w >> 2, wc = w & 3;
  const int lr = lane & 15, lk = lane >> 4;

  const ushort_t* Ab = A + (size_t)brow * K;
  const ushort_t* Bb = BT + (size_t)bcol * K;

  auto stageQ = [&](const ushort_t* gbase, char* lds, int t, int q) {
    int L = q * 512 + tid;
    int r = L >> 3, sc = L & 7;
    load_lds16(gbase + (size_t)r * K + (t << 6) + ((sc ^ (r & 7)) << 3), lds + L * 16);
  };
  auto stageTile = [&](int t, int buf) {  // 6 loads: A q0..q3 + B q0,q1
#pragma unroll
    for (int q = 0; q < 4; ++q) stageQ(Ab, (char*)&As[buf][0], t, q);
#pragma unroll
    for (int q = 0; q < 2; ++q) stageQ(Bb, (char*)&Bs[buf][0], t, q);
  };

  f32x4 acc[8][2] = {};
  const int NT = K >> 6;

  stageTile(0, 0);
  stageTile(1, 1);
  asm volatile("s_waitcnt vmcnt(6)" ::: "memory");  // tile0 landed, tile1 in flight
  __builtin_amdgcn_s_barrier();

  int cur = 0;
  for (int t = 0; t < NT; ++t) {
    const char* Ac = (const char*)&As[cur][0];
    const char* Bc = (const char*)&Bs[cur][0];
    const int nxt = (cur + 2 >= 3) ? cur - 1 : cur + 2;  // (t+2)%3
    char* An = (char*)&As[nxt][0];
    char* Bn = (char*)&Bs[nxt][0];
    const bool pf = (t + 2 < NT);

    bf16x8 af[4][2], bfr[2][2];
    // ===== phase A: A mh0 (8 reads) + B n0,n1 (4 reads); stage Aq0,Aq2,Bq0 =====
#pragma unroll
    for (int mm = 0; mm < 4; ++mm)
#pragma unroll
      for (int ks = 0; ks < 2; ++ks) {
        int rA = wr * 128 + mm * 16 + lr;
        af[mm][ks] = *(const bf16x8*)(Ac + rA * 128 + (((ks * 4 + lk) ^ (rA & 7)) << 4));
      }
#pragma unroll
    for (int n = 0; n < 2; ++n)
#pragma unroll
      for (int ks = 0; ks < 2; ++ks) {
        int rB = wc * 32 + n * 16 + lr;
        bfr[n][ks] = *(const bf16x8*)(Bc + rB * 128 + (((ks * 4 + lk) ^ (rB & 7)) << 4));
      }
    if (pf) { stageQ(Ab, An, t + 2, 0); stageQ(Ab, An, t + 2, 2); stageQ(Bb, Bn, t + 2, 0); }
    __builtin_amdgcn_s_barrier();
    asm volatile("s_waitcnt lgkmcnt(0)" ::: "memory");
    __builtin_amdgcn_sched_barrier(0);
    __builtin_amdgcn_s_setprio(1);
#pragma unroll
    for (int mm = 0; mm < 4; ++mm)
#pragma unroll
      for (int n = 0; n < 2; ++n)
#pragma unroll
        for (int ks = 0; ks < 2; ++ks)
          acc[mm][n] = __builtin_amdgcn_mfma_f32_16x16x32_bf16(af[mm][ks], bfr[n][ks],
                                                               acc[mm][n], 0, 0, 0);
    __builtin_amdgcn_s_setprio(0);
    __builtin_amdgcn_s_barrier();

    // ===== phase B: A mh1 (8 reads); stage Aq1,Aq3,Bq1; counted boundary =====
#pragma unroll
    for (int mm = 0; mm < 4; ++mm)
#pragma unroll
      for (int ks = 0; ks < 2; ++ks) {
        int rA = wr * 128 + 64 + mm * 16 + lr;
        af[mm][ks] = *(const bf16x8*)(Ac + rA * 128 + (((ks * 4 + lk) ^ (rA & 7)) << 4));
      }
    if (pf) { stageQ(Ab, An, t + 2, 1); stageQ(Ab, An, t + 2, 3); stageQ(Bb, Bn, t + 2, 1); }
    __builtin_amdgcn_s_barrier();
    asm volatile("s_waitcnt lgkmcnt(0)" ::: "memory");
    __builtin_amdgcn_sched_barrier(0);
    __builtin_amdgcn_s_setprio(1);
#pragma unroll
    for (int mm = 0; mm < 4; ++mm)
#pragma unroll
      for (int n = 0; n < 2; ++n)
#pragma unroll
        for (int ks = 0; ks < 2; ++ks)
          acc[4 + mm][n] = __builtin_amdgcn_mfma_f32_16x16x32_bf16(af[mm][ks], bfr[n][ks],
                                                                   acc[4 + mm][n], 0, 0, 0);
    __builtin_amdgcn_s_setprio(0);
    if (pf)
      asm volatile("s_waitcnt vmcnt(6)" ::: "memory");  // t+1 landed; t+2 in flight
    else if (t + 1 < NT)
      asm volatile("s_waitcnt vmcnt(0)" ::: "memory");  // tail drain
    __builtin_amdgcn_s_barrier();
    cur = (cur == 2) ? 0 : cur + 1;
  }
  // epilogue
#pragma unroll
  for (int m = 0; m < 8; ++m)
#pragma unroll
    for (int n = 0; n < 2; ++n) {
      int row = brow + wr * 128 + m * 16 + lk * 4;
      int col = bcol + wc * 32 + n * 16 + lr;
#pragma unroll
      for (int j = 0; j < 4; ++j) {
        float v = acc[m][n][j];
        if constexpr (sizeof(OutT) == 2)
          C[(size_t)(row + j) * ldc + col] = (OutT)f2bf(v);
        else
          C[(size_t)(row + j) * ldc + col] = v;
      }
    }
}

// ---------- GEMM: C[M][ldc] = A[M][K] * BT[N][K]^T  (m97 structure, fallback) ----------
template <typename OutT>
__global__ __launch_bounds__(256) void gemm128_kernel(const ushort_t* __restrict__ A,
                                                      const ushort_t* __restrict__ BT,
                                                      OutT* __restrict__ C,
                                                      int M, int N, int K, int ldc) {
  __shared__ ushort_t As[128 * 32];
  __shared__ ushort_t Bs[128 * 32];
  int brow = blockIdx.y * 128, bcol = blockIdx.x * 128;
  int tid = threadIdx.x, w = tid >> 6, lane = tid & 63;
  int wr = w >> 1, wc = w & 1;
  int lr = lane & 15, lk = lane >> 4;
  f32x4 acc[4][4] = {};

  int srow = lane >> 2;
  int scol = (lane & 3) * 8;
  const ushort_t* Ab = A + (size_t)brow * K + scol;
  const ushort_t* Bb = BT + (size_t)bcol * K + scol;

  for (int kt = 0; kt < K; kt += 32) {
#pragma unroll
    for (int i = 0; i < 2; i++) {
      int seg = w * 2 + i;
      int row = seg * 16 + srow;
      load_lds16(Ab + (size_t)row * K + kt, (char*)As + seg * 1024);
      load_lds16(Bb + (size_t)row * K + kt, (char*)Bs + seg * 1024);
    }
    __syncthreads();
    bf16x8 af[4], bfr[4];
#pragma unroll
    for (int m = 0; m < 4; m++)
      af[m] = *(const bf16x8*)&As[(wr * 64 + m * 16 + lr) * 32 + lk * 8];
#pragma unroll
    for (int n = 0; n < 4; n++)
      bfr[n] = *(const bf16x8*)&Bs[(wc * 64 + n * 16 + lr) * 32 + lk * 8];
#pragma unroll
    for (int m = 0; m < 4; m++)
#pragma unroll
      for (int n = 0; n < 4; n++)
        acc[m][n] = __builtin_amdgcn_mfma_f32_16x16x32_bf16(af[m], bfr[n], acc[m][n], 0, 0, 0);
    __syncthreads();
  }
#pragma unroll
  for (int m = 0; m < 4; m++)
#pragma unroll
    for (int n = 0; n < 4; n++) {
      int row = brow + wr * 64 + m * 16 + lk * 4;
      int col = bcol + wc * 64 + n * 16 + lr;
#pragma unroll
      for (int j = 0; j < 4; j++) {
        float v = acc[m][n][j];
        if constexpr (sizeof(OutT) == 2)
          C[(size_t)(row + j) * ldc + col] = (OutT)f2bf(v);
        else
          C[(size_t)(row + j) * ldc + col] = v;
      }
    }
}

// ---------- gemmS: P[tile] = exp2(Q K^T) causal, materialized bf16 ----------
__global__ __launch_bounds__(256) void gemmS_kernel(const ushort_t* __restrict__ C1,
                                                    ushort_t* __restrict__ P) {
  int rem = blockIdx.x, rt = 0;
  while (rem > rt) { rem -= (rt + 1); rt++; }
  const int ct = rem;
  const int h = blockIdx.y, hk = h >> 2;

  __shared__ ushort_t As[128 * 32];
  __shared__ ushort_t Bs[128 * 32];
  int tid = threadIdx.x, w = tid >> 6, lane = tid & 63;
  int wr = w >> 1, wc = w & 1;
  int lr = lane & 15, lk = lane >> 4;
  f32x4 acc[4][4] = {};
  int srow = lane >> 2;
  int scol = (lane & 3) * 8;
  const ushort_t* Ab = C1 + (size_t)(rt * 128) * 6144 + h * 128 + scol;         // Q
  const ushort_t* Bb = C1 + (size_t)(ct * 128) * 6144 + 4096 + hk * 128 + scol; // K

  for (int kt = 0; kt < 128; kt += 32) {
#pragma unroll
    for (int i = 0; i < 2; i++) {
      int seg = w * 2 + i;
      int row = seg * 16 + srow;
      load_lds16(Ab + (size_t)row * 6144 + kt, (char*)As + seg * 1024);
      load_lds16(Bb + (size_t)row * 6144 + kt, (char*)Bs + seg * 1024);
    }
    __syncthreads();
    bf16x8 af[4], bfr[4];
#pragma unroll
    for (int m = 0; m < 4; m++)
      af[m] = *(const bf16x8*)&As[(wr * 64 + m * 16 + lr) * 32 + lk * 8];
#pragma unroll
    for (int n = 0; n < 4; n++)
      bfr[n] = *(const bf16x8*)&Bs[(wc * 64 + n * 16 + lr) * 32 + lk * 8];
#pragma unroll
    for (int m = 0; m < 4; m++)
#pragma unroll
      for (int n = 0; n < 4; n++)
        acc[m][n] = __builtin_amdgcn_mfma_f32_16x16x32_bf16(af[m], bfr[n], acc[m][n], 0, 0, 0);
    __syncthreads();
  }
  ushort_t* Pt = P + ((size_t)h * 136 + (size_t)(rt * (rt + 1) / 2) + ct) * 16384;
  const bool diag = (rt == ct);
#pragma unroll
  for (int m = 0; m < 4; m++)
#pragma unroll
    for (int n = 0; n < 4; n++) {
      int row = wr * 64 + m * 16 + lk * 4;
      int col = wc * 64 + n * 16 + lr;
#pragma unroll
      for (int j = 0; j < 4; j++) {
        float v = exp2_hw(acc[m][n][j]);
        if (diag && col > row + j) v = 0.f;
        Pt[(row + j) * 128 + col] = f2bf(v);
      }
    }
}

// ---------- gemmPV: AO[rt-tile] = (P * V) / rowsum(P), rowsum via ones-MFMA ----------
__global__ __launch_bounds__(256) void gemmPV_kernel(const ushort_t* __restrict__ P,
                                                     const ushort_t* __restrict__ VT,
                                                     ushort_t* __restrict__ AO) {
  const int h = blockIdx.x, hk = h >> 2;
  const int rt = 15 - (int)blockIdx.y;

  __shared__ ushort_t As[128 * 32];
  __shared__ ushort_t Bs[128 * 32];
  int tid = threadIdx.x, w = tid >> 6, lane = tid & 63;
  int wr = w >> 1, wc = w & 1;
  int lr = lane & 15, lk = lane >> 4;
  f32x4 acc[4][4] = {};
  f32x4 sacc[4] = {};
  bf16x8 ones;
#pragma unroll
  for (int j = 0; j < 8; j++) ones[j] = (short)0x3F80;  // bf16 1.0
  int srow = lane >> 2;
  int scol = (lane & 3) * 8;
  const ushort_t* Ph = P + ((size_t)h * 136 + (size_t)(rt * (rt + 1) / 2)) * 16384;
  const ushort_t* Vh = VT + (size_t)hk * 128 * 2048;

  const int nks = (rt + 1) * 4;
  for (int ks = 0; ks < nks; ks++) {
    int k0 = ks * 32;
    int ctk = k0 >> 7, kin = k0 & 127;
#pragma unroll
    for (int i = 0; i < 2; i++) {
      int seg = w * 2 + i;
      int row = seg * 16 + srow;
      load_lds16(Ph + (size_t)ctk * 16384 + (size_t)row * 128 + kin + scol,
                 (char*)As + seg * 1024);
      load_lds16(Vh + (size_t)row * 2048 + k0 + scol, (char*)Bs + seg * 1024);
    }
    __syncthreads();
    bf16x8 af[4], bfr[4];
#pragma unroll
    for (int m = 0; m < 4; m++)
      af[m] = *(const bf16x8*)&As[(wr * 64 + m * 16 + lr) * 32 + lk * 8];
#pragma unroll
    for (int n = 0; n < 4; n++)
      bfr[n] = *(const bf16x8*)&Bs[(wc * 64 + n * 16 + lr) * 32 + lk * 8];
#pragma unroll
    for (int m = 0; m < 4; m++) {
#pragma unroll
      for (int n = 0; n < 4; n++)
        acc[m][n] = __builtin_amdgcn_mfma_f32_16x16x32_bf16(af[m], bfr[n], acc[m][n], 0, 0, 0);
      sacc[m] = __builtin_amdgcn_mfma_f32_16x16x32_bf16(af[m], ones, sacc[m], 0, 0, 0);
    }
    __syncthreads();
  }
  const int q0 = rt * 128;
#pragma unroll
  for (int m = 0; m < 4; m++) {
    float invs[4];
#pragma unroll
    for (int j = 0; j < 4; j++) invs[j] = 1.0f / sacc[m][j];
#pragma unroll
    for (int n = 0; n < 4; n++) {
      int row = wr * 64 + m * 16 + lk * 4;
      int col = wc * 64 + n * 16 + lr;
#pragma unroll
      for (int j = 0; j < 4; j++) {
        float v = acc[m][n][j] * invs[j];
        AO[(size_t)(q0 + row + j) * 4096 + h * 128 + col] = f2bf(v);
      }
    }
  }
}

// ---------- flash attention (fallback when workspace too small) ----------
__global__ __launch_bounds__(256) void fattn_kernel(const ushort_t* __restrict__ C1,
                                                    const ushort_t* __restrict__ VT,
                                                    ushort_t* __restrict__ AO) {
  __shared__ ushort_t Pl[4][32][72];
  const int h = blockIdx.x, hk = h >> 2;
  const int qt = gridDim.y - 1 - blockIdx.y;
  const int tid = threadIdx.x, w = tid >> 6, lane = tid & 63;
  const int lq = lane & 31, hi = lane >> 5;
  const int qw0 = qt * 128 + w * 32;
  const int qabs = qw0 + lq;

  const ushort_t* Kb = C1 + 4096 + (size_t)hk * 128;
  const ushort_t* Vb = VT + (size_t)hk * 128 * 2048;

  bf16x8 qf[8];
  {
    const ushort_t* qrow = C1 + (size_t)qabs * 6144 + h * 128;
#pragma unroll
    for (int s = 0; s < 8; s++) qf[s] = *(const bf16x8*)(qrow + s * 16 + hi * 8);
  }
  f32x16 ot[4] = {};
  float mrow = -1e30f, ssum = 0.f;

  const int ktmax = (qw0 + 31) >> 6;
  for (int kt = 0; kt <= ktmax; kt++) {
    f32x16 sg[2] = {};
#pragma unroll
    for (int g = 0; g < 2; g++) {
      bf16x8 kfa[8];
      const ushort_t* krow = Kb + (size_t)(kt * 64 + g * 32 + lq) * 6144 + hi * 8;
#pragma unroll
      for (int s = 0; s < 8; s++) kfa[s] = *(const bf16x8*)(krow + s * 16);
#pragma unroll
      for (int s = 0; s < 8; s++)
        sg[g] = __builtin_amdgcn_mfma_f32_32x32x16_bf16(kfa[s], qf[s], sg[g], 0, 0, 0);
    }
    if (kt * 64 + 63 > qw0) {
#pragma unroll
      for (int g = 0; g < 2; g++)
#pragma unroll
        for (int r = 0; r < 16; r++) {
          int key = kt * 64 + g * 32 + (r & 3) + 8 * (r >> 2) + 4 * hi;
          if (key > qabs) sg[g][r] = -1e30f;
        }
    }
    float pm = -1e30f;
#pragma unroll
    for (int g = 0; g < 2; g++)
#pragma unroll
      for (int r = 0; r < 16; r++) pm = fmaxf(pm, sg[g][r]);
    pm = fmaxf(pm, __shfl_xor(pm, 32));
    float mnew = fmaxf(mrow, pm);
    float corr = exp2_hw(mrow - mnew);
    mrow = mnew;
    float ps = 0.f;
#pragma unroll
    for (int g = 0; g < 2; g++)
#pragma unroll
      for (int r = 0; r < 16; r++) {
        float e = exp2_hw(sg[g][r] - mnew);
        sg[g][r] = e;
        ps += e;
      }
    ps += __shfl_xor(ps, 32);
    ssum = ssum * corr + ps;
    if (!__all(corr == 1.f)) {
#pragma unroll
      for (int d = 0; d < 4; d++)
#pragma unroll
        for (int r = 0; r < 16; r++) ot[d][r] *= corr;
    }
#pragma unroll
    for (int g = 0; g < 2; g++)
#pragma unroll
      for (int rq = 0; rq < 4; rq++) {
        bf16x4 pk;
#pragma unroll
        for (int j = 0; j < 4; j++) pk[j] = (short)f2bf(sg[g][rq * 4 + j]);
        *(bf16x4*)&Pl[w][lq][g * 32 + rq * 8 + hi * 4] = pk;
      }
    asm volatile("s_waitcnt lgkmcnt(0)" ::: "memory");
    bf16x8 pf[4];
#pragma unroll
    for (int s = 0; s < 4; s++) pf[s] = *(const bf16x8*)&Pl[w][lq][s * 16 + hi * 8];
#pragma unroll
    for (int d = 0; d < 4; d++) {
      bf16x8 vfa[4];
      const ushort_t* vrow = Vb + (size_t)(d * 32 + lq) * 2048 + kt * 64 + hi * 8;
#pragma unroll
      for (int s = 0; s < 4; s++) vfa[s] = *(const bf16x8*)(vrow + s * 16);
#pragma unroll
      for (int s = 0; s < 4; s++)
        ot[d] = __builtin_amdgcn_mfma_f32_32x32x16_bf16(vfa[s], pf[s], ot[d], 0, 0, 0);
    }
  }
  const float inv = 1.0f / ssum;
  ushort_t* orow = AO + (size_t)qabs * 4096 + h * 128;
#pragma unroll
  for (int d = 0; d < 4; d++)
#pragma unroll
    for (int rq = 0; rq < 4; rq++) {
      bf16x4 ok;
#pragma unroll
      for (int j = 0; j < 4; j++) ok[j] = (short)f2bf(ot[d][rq * 4 + j] * inv);
      *(bf16x4*)(orow + d * 32 + rq * 8 + hi * 4) = ok;
    }
}

// ---------- launch ----------
extern "C" void kernel_launch(void* const* d_in, const int* in_sizes, int n_in,
                              void* d_out, int out_size, void* d_ws, size_t ws_size,
                              hipStream_t stream) {
  (void)in_sizes; (void)n_in; (void)out_size;
  const float* x    = (const float*)d_in[0];
  const float* wq   = (const float*)d_in[1];
  const float* wk   = (const float*)d_in[2];
  const float* wv   = (const float*)d_in[3];
  const float* wo   = (const float*)d_in[4];
  const float* cosb = (const float*)d_in[5];
  const float* sinb = (const float*)d_in[6];

  char* ws = (char*)d_ws;
  const bool fast = ws_size >= (215ull << 20);

  if (fast) {
    // layout (MiB): C1[0,24) VT[24,28) woT[28,60) xb[60,76) wT[76,124)
    //               P[60,196) (xb+wT dead after gemm1)  AO[196,212)
    ushort_t* C1  = (ushort_t*)(ws);
    ushort_t* VT  = (ushort_t*)(ws + ((size_t)24 << 20));
    ushort_t* woT = (ushort_t*)(ws + ((size_t)28 << 20));
    ushort_t* xb  = (ushort_t*)(ws + ((size_t)60 << 20));
    ushort_t* wT  = (ushort_t*)(ws + ((size_t)76 << 20));
    ushort_t* P   = (ushort_t*)(ws + ((size_t)60 << 20));
    ushort_t* AO  = (ushort_t*)(ws + ((size_t)196 << 20));

    cvt_x_kernel<<<4096, 256, 0, stream>>>(x, xb);
    tr_cvt_kernel<<<dim3(64, 64), 256, 0, stream>>>(wq, wT, 4096, 4096);
    tr_cvt_kernel<<<dim3(16, 64), 256, 0, stream>>>(wk, wT + (size_t)4096 * 4096, 4096, 1024);
    tr_cvt_kernel<<<dim3(16, 64), 256, 0, stream>>>(wv, wT + (size_t)5120 * 4096, 4096, 1024);
    tr_cvt_kernel<<<dim3(64, 64), 256, 0, stream>>>(wo, woT, 4096, 4096);

    // QKV projection: 256x192 2-phase, grid 256, 2D-chunked XCD map
    gemmC_kernel<ushort_t><<<256, 512, 0, stream>>>(xb, wT, C1, 2048, 6144, 4096, 6144);
    rope_kernel<<<5120, 256, 0, stream>>>(C1, cosb, sinb);
    trv_kernel<<<dim3(16, 32), 256, 0, stream>>>(C1, VT);

    gemmS_kernel<<<dim3(136, 32), 256, 0, stream>>>(C1, P);
    gemmPV_kernel<<<dim3(32, 16), 256, 0, stream>>>(P, VT, AO);  // rowsum fused

    // output projection: 256x128 2-phase p8, grid 8x32 = 256, 2D-chunked XCD map
    gemmD_kernel<float><<<256, 512, 0, stream>>>(AO, woT, (float*)d_out, 2048, 4096, 4096, 4096);
  } else {
    // proven 92MiB layout + R7 fattn
    ushort_t* xb  = (ushort_t*)(ws);
    ushort_t* wT  = (ushort_t*)(ws + ((size_t)16 << 20));
    ushort_t* C1  = (ushort_t*)(ws + ((size_t)64 << 20));
    ushort_t* VT  = (ushort_t*)(ws + ((size_t)88 << 20));
    ushort_t* AO  = xb;
    ushort_t* woT = wT;

    cvt_x_kernel<<<4096, 256, 0, stream>>>(x, xb);
    tr_cvt_kernel<<<dim3(64, 64), 256, 0, stream>>>(wq, wT, 4096, 4096);
    tr_cvt_kernel<<<dim3(16, 64), 256, 0, stream>>>(wk, wT + (size_t)4096 * 4096, 4096, 1024);
    tr_cvt_kernel<<<dim3(16, 64), 256, 0, stream>>>(wv, wT + (size_t)5120 * 4096, 4096, 1024);
    gemm128_kernel<ushort_t><<<dim3(48, 16), 256, 0, stream>>>(xb, wT, C1, 2048, 6144, 4096, 6144);
    rope_kernel<<<5120, 256, 0, stream>>>(C1, cosb, sinb);
    trv_kernel<<<dim3(16, 32), 256, 0, stream>>>(C1, VT);
    tr_cvt_kernel<<<dim3(64, 64), 256, 0, stream>>>(wo, woT, 4096, 4096);
    fattn_kernel<<<dim3(32, 16), 256, 0, stream>>>(C1, VT, AO);
    gemm128_kernel<float><<<dim3(32, 16), 256, 0, stream>>>(AO, woT, (float*)d_out, 2048, 4096, 4096, 4096);
  }
}